// Round 14
// baseline (732.319 us; speedup 1.0000x reference)
//
#include <hip/hip_runtime.h>
#include <stdint.h>

// Problem constants
#define B_   8
#define N_   32768
#define C_   32
#define K_   22
#define CAT_ 40

typedef unsigned short u16;
typedef unsigned int   u32;

typedef __attribute__((ext_vector_type(8))) short bf16x8;
typedef __attribute__((ext_vector_type(4))) float f32x4;

#define MFMA(a, b, c) __builtin_amdgcn_mfma_f32_16x16x32_bf16(a, b, c, 0, 0, 0)

// ---------- bf16 helpers (raw bits) ----------
__device__ __forceinline__ float b2f(u16 v) { return __uint_as_float(((u32)v) << 16); }
__device__ __forceinline__ u16 f2b(float f) {
    u32 x = __float_as_uint(f);
    return (u16)((x + 0x7fffu + ((x >> 16) & 1u)) >> 16);   // RNE
}
__device__ __forceinline__ u32 pk2(float a, float b) {
    return (u32)f2b(a) | ((u32)f2b(b) << 16);
}

// ---------- packed MFMA A-fragment weight offsets (u16 units) ----------
#define PK_WIN 0         // 256x32(pad), KB=1 : 8192
#define PK_W1  8192      // 2 x 64x256, KB=8  : 16384 each
#define PK_W2  40960     // 2 x 128x64, KB=2  : 8192 each
#define PK_W3  57344     // 2 x 128x128, KB=4 : 16384 each
#define PK_WC1 90112     // 2 x 128x128       : 16384 each
#define PK_WC2 122880    // 2 x 256x128, KB=4 : 32768 each
#define PK_WC3 188416    // 2 x 32x256, KB=8  : 8192 each
#define PK_WO1 204800    // 128x256, KB=8     : 32768
#define PK_WO2 237568    // 128x128, KB=4     : 16384

// ---------- fp32 bias block offsets (floats) ----------
#define OBIN 0
#define OB1  256
#define OB2  384
#define OB3  640
#define OBC1 896
#define OBC2 1152
#define OBC3 1664
#define OBO1 1728
#define OBO2 1856
#define ODB1 1984
#define ODB2 2240
#define ODB3 2496

// ---------- canonical bf16 dense-head weights (u16 offsets) ----------
#define ODW1 0
#define ODW2 32768
#define ODW3 98304

// ---------- workspace byte offsets ----------
#define OFS_WPK   0u
#define OFS_BIAS  524288u
#define OFS_DWC   540672u
#define OFS_MODE  786432u
#define OFS_FEATC 1048576u
#define OFS_GACC0 12582912u
#define OFS_GACC1 12746752u
#define OFS_GNET  12910592u
#define GACC_ZERO_BYTES 331776u
#define OFS_CF2B0 12914688u
#define OFS_CF2B1 12980224u
#define OFS_F0    16777216u     // fragment-major f: [b][nt(2048 of 16 pts)][kb(4)][lane(64)][8] bf16
#define OFS_F1    83886080u

// sSeg LDS layout (a-halves): stride 161 dwords (160%32==0 was a 16-way bank
// conflict on every seg-max atomic — round-6 lesson). bank=(cl+co)%32.
#define SEGSTR 161
#define SEGTOT (32 * SEGSTR)
// corr-only sSeg (b-halves): stride 33, bank=(cl+j)%32.
#define SEGCSTR 33
#define SEGCTOT (32 * SEGCSTR)

// ---------- dtype sniffer ----------
__global__ void kSniff(const u16* __restrict__ featAny, int* __restrict__ mode) {
    __shared__ int cnt;
    if (threadIdx.x == 0) cnt = 0;
    __syncthreads();
    int weird = 0;
    for (int j = 0; j < 4; ++j) {
        u16 v = featAny[threadIdx.x * 4 + j];
        float f = b2f(v);
        if (v == 0 || !(fabsf(f) < 1e10f)) weird++;
    }
    if (weird) atomicAdd(&cnt, weird);
    __syncthreads();
    if (threadIdx.x == 0) *mode = (cnt > 64) ? 1 : 0;
}

__device__ __forceinline__ float fetchF(const void* src, size_t i, int mode) {
    return mode ? ((const float*)src)[i] : b2f(((const u16*)src)[i]);
}

// ---------- weight pack: (COUT,CIN) -> MFMA A-fragment bf16 order ----------
__device__ void packA(const void* __restrict__ src, u16* __restrict__ dst,
                      int COUT, int CIN, int mode, int tid, int np) {
    int KB = (CIN + 31) / 32;
    int tiles = COUT / 16;
    int tot = tiles * KB * 64 * 8;
    for (int i = tid; i < tot; i += np) {
        int j = i & 7;
        int L = (i >> 3) & 63;
        int rest = i >> 9;
        int kb = rest % KB, tile = rest / KB;
        int co = tile * 16 + (L & 15);
        int ci = kb * 32 + (L >> 4) * 8 + j;
        float v = (ci < CIN) ? fetchF(src, (size_t)co * CIN + ci, mode) : 0.f;
        dst[i] = f2b(v);
    }
}

__device__ void cvtF(const void* __restrict__ src, float* __restrict__ dst,
                     int n, int mode, int tid, int np) {
    for (int i = tid; i < n; i += np) dst[i] = fetchF(src, i, mode);
}

__device__ void cvtB(const void* __restrict__ src, u16* __restrict__ dst,
                     int n, int mode, int tid, int np) {
    for (int i = tid; i < n; i += np)
        dst[i] = mode ? f2b(((const float*)src)[i]) : ((const u16*)src)[i];
}

__global__ void kPrep(const void* feat, const void* w_in, const void* b_in,
                      const void* w1, const void* b1, const void* w2, const void* b2,
                      const void* w3, const void* b3,
                      const void* wc1, const void* bc1, const void* wc2, const void* bc2,
                      const void* wc3, const void* bc3,
                      const void* wo1, const void* bo1, const void* wo2, const void* bo2,
                      const void* dw1, const void* db1, const void* dw2, const void* db2,
                      const void* dw3, const void* db3,
                      u16* WPK, float* BIAS, u16* DWC, u16* FEATC,
                      const int* __restrict__ modep) {
    const int mode = *modep;
    int tid = blockIdx.x * blockDim.x + threadIdx.x;
    int np  = gridDim.x * blockDim.x;
    cvtB(feat, FEATC, B_ * N_ * K_, mode, tid, np);
    packA(w_in, WPK + PK_WIN, 256, 22, mode, tid, np);
    packA(w1,                                 WPK + PK_W1,          64, 256, mode, tid, np);
    packA((const u16*)w1 + (mode?32768:16384), WPK + PK_W1 + 16384,  64, 256, mode, tid, np);
    packA(w2,                                 WPK + PK_W2,          128, 64, mode, tid, np);
    packA((const u16*)w2 + (mode?16384:8192),  WPK + PK_W2 + 8192,   128, 64, mode, tid, np);
    packA(w3,                                 WPK + PK_W3,          128, 128, mode, tid, np);
    packA((const u16*)w3 + (mode?32768:16384), WPK + PK_W3 + 16384,  128, 128, mode, tid, np);
    packA(wc1,                                WPK + PK_WC1,         128, 128, mode, tid, np);
    packA((const u16*)wc1 + (mode?32768:16384),WPK + PK_WC1 + 16384, 128, 128, mode, tid, np);
    packA(wc2,                                WPK + PK_WC2,         256, 128, mode, tid, np);
    packA((const u16*)wc2 + (mode?65536:32768),WPK + PK_WC2 + 32768, 256, 128, mode, tid, np);
    packA(wc3,                                WPK + PK_WC3,         32, 256, mode, tid, np);
    packA((const u16*)wc3 + (mode?16384:8192), WPK + PK_WC3 + 8192,  32, 256, mode, tid, np);
    packA(wo1, WPK + PK_WO1, 128, 256, mode, tid, np);
    packA(wo2, WPK + PK_WO2, 128, 128, mode, tid, np);
    cvtF(b_in, BIAS + OBIN, 256, mode, tid, np);
    cvtF(b1,   BIAS + OB1,  128, mode, tid, np);
    cvtF(b2,   BIAS + OB2,  256, mode, tid, np);
    cvtF(b3,   BIAS + OB3,  256, mode, tid, np);
    cvtF(bc1,  BIAS + OBC1, 256, mode, tid, np);
    cvtF(bc2,  BIAS + OBC2, 512, mode, tid, np);
    cvtF(bc3,  BIAS + OBC3, 64,  mode, tid, np);
    cvtF(bo1,  BIAS + OBO1, 128, mode, tid, np);
    cvtF(bo2,  BIAS + OBO2, 128, mode, tid, np);
    cvtF(db1,  BIAS + ODB1, 256, mode, tid, np);
    cvtF(db2,  BIAS + ODB2, 256, mode, tid, np);
    cvtF(db3,  BIAS + ODB3, 40,  mode, tid, np);
    cvtB(dw1, DWC + ODW1, 128 * 256, mode, tid, np);
    cvtB(dw2, DWC + ODW2, 256 * 256, mode, tid, np);
    cvtB(dw3, DWC + ODW3, 256 * 40,  mode, tid, np);
}

__device__ __forceinline__ void storeRow(u16* __restrict__ buf, int p, int col,
                                         float r0, float r1, float r2, float r3) {
    *(uint2*)(buf + p * 136 + col) = make_uint2(pk2(r0, r1), pk2(r2, r3));
}

// Load a wave's weight fragments into registers (R8 formulation, a-halves only).
template<int NF>
__device__ __forceinline__ void loadWF(const u16* __restrict__ wA, int lane, bf16x8 (&wf)[NF]) {
#pragma unroll
    for (int i = 0; i < NF; ++i)
        wf[i] = *(const bf16x8*)(wA + ((size_t)(i * 64 + lane)) * 8);
}

// ================= 8-wave / 128-pt building blocks (R12-verified, a-halves) ==========
template<int KB, int INS>
__device__ __forceinline__ void convP128w(const bf16x8 (&wf)[KB], const float* __restrict__ bias,
                                          const u16* __restrict__ sIn, u16* __restrict__ sOut) {
    const int t = threadIdx.x, lane = t & 63, w = t >> 6, lp = lane & 15, q = lane >> 4;
    f32x4 acc[8] = {};
#pragma unroll
    for (int kb = 0; kb < KB; ++kb) {
        bf16x8 bb[8];
#pragma unroll
        for (int pt = 0; pt < 8; ++pt)
            bb[pt] = *(const bf16x8*)(sIn + (pt * 16 + lp) * INS + kb * 32 + q * 8);
#pragma unroll
        for (int pt = 0; pt < 8; ++pt) acc[pt] = MFMA(wf[kb], bb[pt], acc[pt]);
    }
    const int co = w * 16 + q * 4;
    f32x4 bv = *(const f32x4*)(bias + co);
#pragma unroll
    for (int pt = 0; pt < 8; ++pt) {
        f32x4 v = acc[pt];
        storeRow(sOut, pt * 16 + lp, co,
                 fmaxf(v[0] + bv[0], 0.f), fmaxf(v[1] + bv[1], 0.f),
                 fmaxf(v[2] + bv[2], 0.f), fmaxf(v[3] + bv[3], 0.f));
    }
}

__device__ __forceinline__ void convW2_128w(const bf16x8 (&wf)[2], const float* __restrict__ bias,
                                            const u16* __restrict__ sIn, u16* __restrict__ sOut,
                                            const int* __restrict__ sCluSeg, int* __restrict__ sSeg) {
    const int t = threadIdx.x, lane = t & 63, w = t >> 6, lp = lane & 15, q = lane >> 4;
    f32x4 acc[8] = {};
#pragma unroll
    for (int kb = 0; kb < 2; ++kb) {
        bf16x8 bb[8];
#pragma unroll
        for (int pt = 0; pt < 8; ++pt)
            bb[pt] = *(const bf16x8*)(sIn + (pt * 16 + lp) * 136 + kb * 32 + q * 8);
#pragma unroll
        for (int pt = 0; pt < 8; ++pt) acc[pt] = MFMA(wf[kb], bb[pt], acc[pt]);
    }
    const int co = w * 16 + q * 4;
    f32x4 bv = *(const f32x4*)(bias + co);
#pragma unroll
    for (int pt = 0; pt < 8; ++pt) {
        f32x4 v = acc[pt];
        const int p = pt * 16 + lp;
        float r0 = fmaxf(v[0] + bv[0], 0.f), r1 = fmaxf(v[1] + bv[1], 0.f);
        float r2 = fmaxf(v[2] + bv[2], 0.f), r3 = fmaxf(v[3] + bv[3], 0.f);
        *(uint2*)(sOut + p * 136 + co) = make_uint2(pk2(r0, r1), pk2(r2, r3));
        const int sb = sCluSeg[p] * SEGSTR + co;
        atomicMax(&sSeg[sb + 0], __float_as_int(r0));
        atomicMax(&sSeg[sb + 1], __float_as_int(r1));
        atomicMax(&sSeg[sb + 2], __float_as_int(r2));
        atomicMax(&sSeg[sb + 3], __float_as_int(r3));
    }
}

__device__ __forceinline__ void convCat128w(const bf16x8 (&wf)[8], const float* __restrict__ bias,
                                            const u16* __restrict__ sLo, const u16* __restrict__ sHi,
                                            u16* __restrict__ sOut) {
    const int t = threadIdx.x, lane = t & 63, w = t >> 6, lp = lane & 15, q = lane >> 4;
    const int ct = w & 3, pp = (w >> 2) * 4;
    f32x4 acc[4] = {};
#pragma unroll
    for (int kb = 0; kb < 8; ++kb) {
        const u16* sIn = (kb < 4) ? sLo : sHi;
        const int col = (kb & 3) * 32 + q * 8;
        bf16x8 bb[4];
#pragma unroll
        for (int i = 0; i < 4; ++i)
            bb[i] = *(const bf16x8*)(sIn + ((pp + i) * 16 + lp) * 136 + col);
#pragma unroll
        for (int i = 0; i < 4; ++i) acc[i] = MFMA(wf[kb], bb[i], acc[i]);
    }
    const int co = ct * 16 + q * 4;
    f32x4 bv = *(const f32x4*)(bias + co);
#pragma unroll
    for (int i = 0; i < 4; ++i) {
        f32x4 v = acc[i];
        storeRow(sOut, (pp + i) * 16 + lp, co,
                 fmaxf(v[0] + bv[0], 0.f), fmaxf(v[1] + bv[1], 0.f),
                 fmaxf(v[2] + bv[2], 0.f), fmaxf(v[3] + bv[3], 0.f));
    }
}

__device__ __forceinline__ void convCatG128w(const bf16x8 (&wf)[8], const float* __restrict__ bias,
                                             const u16* __restrict__ sIn, const u16* __restrict__ cfb,
                                             const int* __restrict__ sClu, u16* __restrict__ sOut) {
    const int t = threadIdx.x, lane = t & 63, w = t >> 6, lp = lane & 15, q = lane >> 4;
    const int ct = w & 3, pp = (w >> 2) * 4;
    f32x4 acc[4] = {};
#pragma unroll
    for (int kb = 0; kb < 8; ++kb) {
        bf16x8 bb[4];
#pragma unroll
        for (int i = 0; i < 4; ++i) {
            const int p = (pp + i) * 16 + lp;
            if (kb < 4) bb[i] = *(const bf16x8*)(sIn + p * 136 + kb * 32 + q * 8);
            else        bb[i] = *(const bf16x8*)(cfb + sClu[p] * 128 + (kb - 4) * 32 + q * 8);
        }
#pragma unroll
        for (int i = 0; i < 4; ++i) acc[i] = MFMA(wf[kb], bb[i], acc[i]);
    }
    const int co = ct * 16 + q * 4;
    f32x4 bv = *(const f32x4*)(bias + co);
#pragma unroll
    for (int i = 0; i < 4; ++i) {
        f32x4 v = acc[i];
        storeRow(sOut, (pp + i) * 16 + lp, co,
                 fmaxf(v[0] + bv[0], 0.f), fmaxf(v[1] + bv[1], 0.f),
                 fmaxf(v[2] + bv[2], 0.f), fmaxf(v[3] + bv[3], 0.f));
    }
}

__device__ __forceinline__ void convG128w(const bf16x8 (&wf)[4], const float* __restrict__ bias,
                                          const u16* __restrict__ gB, u16* __restrict__ sOut) {
    const int t = threadIdx.x, lane = t & 63, w = t >> 6, lp = lane & 15, q = lane >> 4;
    f32x4 acc[8] = {};
#pragma unroll
    for (int kb = 0; kb < 4; ++kb) {
        bf16x8 bb[8];
#pragma unroll
        for (int pt = 0; pt < 8; ++pt)
            bb[pt] = *(const bf16x8*)(gB + pt * 2048 + kb * 512 + lane * 8);
#pragma unroll
        for (int pt = 0; pt < 8; ++pt) acc[pt] = MFMA(wf[kb], bb[pt], acc[pt]);
    }
    const int co = w * 16 + q * 4;
    f32x4 bv = *(const f32x4*)(bias + co);
#pragma unroll
    for (int pt = 0; pt < 8; ++pt) {
        f32x4 v = acc[pt];
        storeRow(sOut, pt * 16 + lp, co,
                 fmaxf(v[0] + bv[0], 0.f), fmaxf(v[1] + bv[1], 0.f),
                 fmaxf(v[2] + bv[2], 0.f), fmaxf(v[3] + bv[3], 0.f));
    }
}

// ================= 4-wave / 64-pt building blocks (R4/R8-verified) =================
__device__ __forceinline__ void convG64(const u16* __restrict__ wA, const float* __restrict__ bias,
                                        const u16* __restrict__ gB, u16* __restrict__ sOut) {
    const int t = threadIdx.x, lane = t & 63, w = t >> 6, lp = lane & 15, q = lane >> 4;
    bf16x8 bb[4][4];
#pragma unroll
    for (int pt = 0; pt < 4; ++pt)
#pragma unroll
        for (int kb = 0; kb < 4; ++kb)
            bb[pt][kb] = *(const bf16x8*)(gB + pt * 2048 + kb * 512 + lane * 8);
    f32x4 acc[2][4] = {};
#pragma unroll
    for (int kb = 0; kb < 4; ++kb)
#pragma unroll
        for (int ct = 0; ct < 2; ++ct) {
            bf16x8 a = *(const bf16x8*)(wA + (size_t)(((w * 2 + ct) * 4 + kb) * 64 + lane) * 8);
#pragma unroll
            for (int pt = 0; pt < 4; ++pt) acc[ct][pt] = MFMA(a, bb[pt][kb], acc[ct][pt]);
        }
#pragma unroll
    for (int ct = 0; ct < 2; ++ct) {
        const int co = (w * 2 + ct) * 16 + q * 4;
        f32x4 bv = *(const f32x4*)(bias + co);
#pragma unroll
        for (int pt = 0; pt < 4; ++pt) {
            f32x4 v = acc[ct][pt];
            storeRow(sOut, pt * 16 + lp, co,
                     fmaxf(v[0] + bv[0], 0.f), fmaxf(v[1] + bv[1], 0.f),
                     fmaxf(v[2] + bv[2], 0.f), fmaxf(v[3] + bv[3], 0.f));
        }
    }
}

template<int CT, int KB, int INS>
__device__ __forceinline__ void convL64(const u16* __restrict__ wA, const float* __restrict__ bias,
                                        const u16* __restrict__ sIn, u16* __restrict__ sOut) {
    const int t = threadIdx.x, lane = t & 63, w = t >> 6, lp = lane & 15, q = lane >> 4;
    f32x4 acc[CT][4] = {};
#pragma unroll
    for (int kb = 0; kb < KB; ++kb) {
        bf16x8 bb[4];
#pragma unroll
        for (int pt = 0; pt < 4; ++pt)
            bb[pt] = *(const bf16x8*)(sIn + (pt * 16 + lp) * INS + kb * 32 + q * 8);
#pragma unroll
        for (int ct = 0; ct < CT; ++ct) {
            bf16x8 a = *(const bf16x8*)(wA + (size_t)(((w * CT + ct) * KB + kb) * 64 + lane) * 8);
#pragma unroll
            for (int pt = 0; pt < 4; ++pt) acc[ct][pt] = MFMA(a, bb[pt], acc[ct][pt]);
        }
    }
#pragma unroll
    for (int ct = 0; ct < CT; ++ct) {
        const int co = (w * CT + ct) * 16 + q * 4;
        f32x4 bv = *(const f32x4*)(bias + co);
        const int col = co & 127;
#pragma unroll
        for (int pt = 0; pt < 4; ++pt) {
            f32x4 v = acc[ct][pt];
            storeRow(sOut, pt * 16 + lp, col,
                     fmaxf(v[0] + bv[0], 0.f), fmaxf(v[1] + bv[1], 0.f),
                     fmaxf(v[2] + bv[2], 0.f), fmaxf(v[3] + bv[3], 0.f));
        }
    }
}

__device__ __forceinline__ void convCatG64(const u16* __restrict__ wA, const float* __restrict__ bias,
                                           const u16* __restrict__ sIn, const u16* __restrict__ cfb,
                                           const int* __restrict__ sClu, u16* __restrict__ sOut) {
    const int t = threadIdx.x, lane = t & 63, w = t >> 6, lp = lane & 15, q = lane >> 4;
    bf16x8 pb[4][4];
#pragma unroll
    for (int pt = 0; pt < 4; ++pt) {
        const u16* src = cfb + sClu[pt * 16 + lp] * 128 + q * 8;
#pragma unroll
        for (int kb = 0; kb < 4; ++kb) pb[pt][kb] = *(const bf16x8*)(src + kb * 32);
    }
    f32x4 acc[2][4] = {};
#pragma unroll
    for (int kb = 0; kb < 8; ++kb) {
        bf16x8 bb[4];
#pragma unroll
        for (int pt = 0; pt < 4; ++pt) {
            if (kb < 4) bb[pt] = *(const bf16x8*)(sIn + (pt * 16 + lp) * 136 + kb * 32 + q * 8);
            else        bb[pt] = pb[pt][kb - 4];
        }
#pragma unroll
        for (int ct = 0; ct < 2; ++ct) {
            bf16x8 a = *(const bf16x8*)(wA + (size_t)(((w * 2 + ct) * 8 + kb) * 64 + lane) * 8);
#pragma unroll
            for (int pt = 0; pt < 4; ++pt) acc[ct][pt] = MFMA(a, bb[pt], acc[ct][pt]);
        }
    }
#pragma unroll
    for (int ct = 0; ct < 2; ++ct) {
        const int co = (w * 2 + ct) * 16 + q * 4;
        f32x4 bv = *(const f32x4*)(bias + co);
#pragma unroll
        for (int pt = 0; pt < 4; ++pt) {
            f32x4 v = acc[ct][pt];
            storeRow(sOut, pt * 16 + lp, co,
                     fmaxf(v[0] + bv[0], 0.f), fmaxf(v[1] + bv[1], 0.f),
                     fmaxf(v[2] + bv[2], 0.f), fmaxf(v[3] + bv[3], 0.f));
        }
    }
}

__device__ __forceinline__ void convNet64(const u16* __restrict__ wA, const float* __restrict__ bias,
                                          const u16* __restrict__ sIn, int* __restrict__ sNet) {
    const int t = threadIdx.x, lane = t & 63, w = t >> 6, lp = lane & 15, q = lane >> 4;
    f32x4 acc[2][4] = {};
#pragma unroll
    for (int kb = 0; kb < 4; ++kb) {
        bf16x8 bb[4];
#pragma unroll
        for (int pt = 0; pt < 4; ++pt)
            bb[pt] = *(const bf16x8*)(sIn + (pt * 16 + lp) * 136 + kb * 32 + q * 8);
#pragma unroll
        for (int ct = 0; ct < 2; ++ct) {
            bf16x8 a = *(const bf16x8*)(wA + (size_t)(((w * 2 + ct) * 4 + kb) * 64 + lane) * 8);
#pragma unroll
            for (int pt = 0; pt < 4; ++pt) acc[ct][pt] = MFMA(a, bb[pt], acc[ct][pt]);
        }
    }
#pragma unroll
    for (int ct = 0; ct < 2; ++ct) {
        const int co = (w * 2 + ct) * 16 + q * 4;
        f32x4 bv = *(const f32x4*)(bias + co);
        f32x4 m = acc[ct][0];
#pragma unroll
        for (int pt = 1; pt < 4; ++pt) {
            m[0] = fmaxf(m[0], acc[ct][pt][0]); m[1] = fmaxf(m[1], acc[ct][pt][1]);
            m[2] = fmaxf(m[2], acc[ct][pt][2]); m[3] = fmaxf(m[3], acc[ct][pt][3]);
        }
        atomicMax(&sNet[co + 0], __float_as_int(fmaxf(m[0] + bv[0], 0.f)));
        atomicMax(&sNet[co + 1], __float_as_int(fmaxf(m[1] + bv[1], 0.f)));
        atomicMax(&sNet[co + 2], __float_as_int(fmaxf(m[2] + bv[2], 0.f)));
        atomicMax(&sNet[co + 3], __float_as_int(fmaxf(m[3] + bv[3], 0.f)));
    }
}

// wc3 K-split accumulate (b-halves): kb range [K0,K1) from one LDS buffer,
// accumulator carried in registers across the wc2-hi barrier.
template<int K0, int K1>
__device__ __forceinline__ void wc3acc(const u16* __restrict__ wA, const u16* __restrict__ sIn,
                                       f32x4 (&acc)[2]) {
    const int t = threadIdx.x, lane = t & 63, w = t >> 6, lp = lane & 15, q = lane >> 4;
    const int ct = w & 1, pp = (w >> 1) * 2;
#pragma unroll
    for (int kb = K0; kb < K1; ++kb) {
        const int col = (kb & 3) * 32 + q * 8;
        bf16x8 a  = *(const bf16x8*)(wA + (size_t)((ct * 8 + kb) * 64 + lane) * 8);
        bf16x8 b0 = *(const bf16x8*)(sIn + ((pp + 0) * 16 + lp) * 136 + col);
        bf16x8 b1 = *(const bf16x8*)(sIn + ((pp + 1) * 16 + lp) * 136 + col);
        acc[0] = MFMA(a, b0, acc[0]);
        acc[1] = MFMA(a, b1, acc[1]);
    }
}

__device__ __forceinline__ void wc3fin(const float* __restrict__ bias, const f32x4 (&acc)[2],
                                       const int* __restrict__ sClu, int* __restrict__ sSegC) {
    const int t = threadIdx.x, lane = t & 63, w = t >> 6, lp = lane & 15, q = lane >> 4;
    const int ct = w & 1, pp = (w >> 1) * 2;
    const int col = ct * 16 + q * 4;
    f32x4 bv = *(const f32x4*)(bias + col);
#pragma unroll
    for (int i = 0; i < 2; ++i) {
        const int p = (pp + i) * 16 + lp;
        const int cl = sClu[p];
        f32x4 v = acc[i];
        atomicMax(&sSegC[cl * SEGCSTR + col + 0], __float_as_int(fmaxf(v[0] + bv[0], 0.f)));
        atomicMax(&sSegC[cl * SEGCSTR + col + 1], __float_as_int(fmaxf(v[1] + bv[1], 0.f)));
        atomicMax(&sSegC[cl * SEGCSTR + col + 2], __float_as_int(fmaxf(v[2] + bv[2], 0.f)));
        atomicMax(&sSegC[cl * SEGCSTR + col + 3], __float_as_int(fmaxf(v[3] + bv[3], 0.f)));
    }
}

// ---------- iteration-0, part A (R12-verified, unchanged) ----------
__global__ __launch_bounds__(512, 2)
void kA0a(const u16* __restrict__ featc, const int* __restrict__ clu0,
          const u16* __restrict__ WPK, const float* __restrict__ BIAS,
          u16* __restrict__ gF, int* __restrict__ gSeg) {
    __shared__ __attribute__((aligned(16))) u16 sA[128 * 136];
    __shared__ __attribute__((aligned(16))) u16 sB[128 * 136];
    __shared__ __attribute__((aligned(16))) u16 sC[128 * 136];
    __shared__ __attribute__((aligned(16))) u16 sFeat[128 * 40];
    __shared__ int sSeg[SEGTOT];
    __shared__ int sClu[128];
    const int t = threadIdx.x, lane = t & 63, w = t >> 6, lp = lane & 15, q = lane >> 4;
    const int b = blockIdx.y;
    const size_t bN = (size_t)b * N_;
    bf16x8 wf1a[1], wf1b[1], wf2[8], wf3[2];
    loadWF(WPK + PK_WIN + w * 512, lane, wf1a);
    loadWF(WPK + PK_WIN + 4096 + w * 512, lane, wf1b);
    loadWF(WPK + PK_W1 + (w & 3) * 4096, lane, wf2);
    loadWF(WPK + PK_W2 + w * 1024, lane, wf3);
    for (int i = t; i < SEGTOT; i += 512) sSeg[i] = 0;
    {
        const int n0 = blockIdx.x * 1024;
        for (int i = t; i < 5120; i += 512) {
            int p = i / 40, k = i - p * 40;
            sFeat[i] = (k < 22) ? featc[(bN + n0 + p) * 22 + k] : (u16)0;
        }
    }
    __syncthreads();
    for (int s = 0; s < 8; ++s) {
        const int n0 = (blockIdx.x * 8 + s) * 128;
        const size_t ntB = (size_t)b * 2048 + (size_t)(blockIdx.x * 8 + s) * 8;
        if (t < 128) sClu[t] = clu0[bN + n0 + t];
        convP128w<1, 40>(wf1a, BIAS + OBIN,       sFeat, sA);
        convP128w<1, 40>(wf1b, BIAS + OBIN + 128, sFeat, sB);
        __syncthreads();
        convCat128w(wf2, BIAS + OB1, sA, sB, sC);
        __syncthreads();
        convW2_128w(wf3, BIAS + OB2, sC, sA, sClu, sSeg);
        __syncthreads();
        {
#pragma unroll
            for (int r = 0; r < 4; ++r) {
                bf16x8 v = *(const bf16x8*)(sA + (w * 16 + lp) * 136 + r * 32 + q * 8);
                *(bf16x8*)(gF + ((ntB + w) * 4 + r) * 512 + lane * 8) = v;
            }
        }
        if (s < 7) {
            const int n1 = n0 + 128;
            for (int i = t; i < 5120; i += 512) {
                int p = i / 40, k = i - p * 40;
                sFeat[i] = (k < 22) ? featc[(bN + n1 + p) * 22 + k] : (u16)0;
            }
        }
        __syncthreads();
    }
    for (int i = t; i < 4096; i += 512) {
        int cl = i >> 7, ch = i & 127;
        atomicMax(&gSeg[b * 5120 + cl * 160 + ch], sSeg[cl * SEGSTR + ch]);
    }
}

// ---------- part B: 64-pt, 256 thr, 2 buffers, ~39KB LDS -> 4 blocks/CU ----------
template<int PKOFF, int BOFF>
__device__ __forceinline__ void kAbBody64(const u16* __restrict__ gFp, const int* __restrict__ clu,
                                          const u16* __restrict__ WPK, const float* __restrict__ BIAS,
                                          int* __restrict__ gSeg) {
    __shared__ __attribute__((aligned(16))) u16 sA[64 * 136];
    __shared__ __attribute__((aligned(16))) u16 sB[64 * 136];
    __shared__ int sSegC[SEGCTOT];
    __shared__ int sClu[64];
    const int t = threadIdx.x;
    const int b = blockIdx.y;
    const size_t bN = (size_t)b * N_;
    const u16* wc1 = WPK + PK_WC1 + PKOFF * 16384;
    const u16* wc2 = WPK + PK_WC2 + PKOFF * 32768;
    const u16* wc3 = WPK + PK_WC3 + PKOFF * 8192;
    for (int i = t; i < SEGCTOT; i += 256) sSegC[i] = 0;
    __syncthreads();
    for (int s = 0; s < 4; ++s) {
        const int n0 = (blockIdx.x * 4 + s) * 64;
        const size_t ntB = (size_t)b * 2048 + (size_t)(blockIdx.x * 4 + s) * 4;
        if (t < 64) sClu[t] = clu[bN + n0 + t];
        // P1: wc1 128->128, B direct from global f fragments (c1 -> sA)
        convG64(wc1, BIAS + OBC1 + BOFF * 128, gFp + ntB * 2048, sA);
        __syncthreads();
        // P2: wc2-lo 128->128 (sA -> sB)
        convL64<2, 4, 136>(wc2, BIAS + OBC2 + BOFF * 256, sA, sB);
        __syncthreads();
        // P3: wc3 partial (kb 0..3) — accumulator in registers
        f32x4 cacc[2] = {};
        wc3acc<0, 4>(wc3, sB, cacc);
        __syncthreads();
        // P4: wc2-hi 128->128 (sA -> sB, reuse buffer)
        convL64<2, 4, 136>(wc2 + 16384, BIAS + OBC2 + BOFF * 256 + 128, sA, sB);
        __syncthreads();
        // P5: wc3 finish (kb 4..7) + corr seg-max atomics
        wc3acc<4, 8>(wc3, sB, cacc);
        wc3fin(BIAS + OBC3 + BOFF * 32, cacc, sClu, sSegC);
        __syncthreads();   // guards sClu rewrite + sB rewrite next subtile
    }
    for (int i = t; i < 1024; i += 256) {
        int cl = i >> 5, ch = i & 31;
        atomicMax(&gSeg[b * 5120 + cl * 160 + 128 + ch], sSegC[cl * SEGCSTR + ch]);
    }
}

__global__ __launch_bounds__(256, 4)
void kA0b(const u16* __restrict__ gFp, const int* __restrict__ clu0,
          const u16* __restrict__ WPK, const float* __restrict__ BIAS,
          int* __restrict__ gSeg) {
    kAbBody64<0, 0>(gFp, clu0, WPK, BIAS, gSeg);
}

__global__ __launch_bounds__(256, 4)
void kA1b(const u16* __restrict__ gFp, const int* __restrict__ clu1,
          const u16* __restrict__ WPK, const float* __restrict__ BIAS,
          int* __restrict__ gSeg) {
    kAbBody64<1, 1>(gFp, clu1, WPK, BIAS, gSeg);
}

// ---------- per-batch cluster math -> bf16 cf2b ----------
__global__ __launch_bounds__(256)
void kB(const int* __restrict__ gSeg, u16* __restrict__ cf2b) {
    __shared__ float sA[5120];
    __shared__ float sR[1024];
    __shared__ float sI[32];
    const int t = threadIdx.x, b = blockIdx.x;
    for (int i = t; i < 5120; i += 256) sA[i] = __int_as_float(gSeg[b * 5120 + i]);
    __syncthreads();
    if (t < 32) {
        float s = 0.f;
        for (int j = 0; j < 32; ++j) { float v = sA[t * 160 + 128 + j]; s = fmaf(v, v, s); }
        sI[t] = 1.f / fmaxf(sqrtf(s), 1e-12f);
    }
    __syncthreads();
    for (int i = t; i < 1024; i += 256) {
        int ca = i >> 5, cb = i & 31;
        float s = 0.f;
        for (int j = 0; j < 32; ++j)
            s = fmaf(sA[ca * 160 + 128 + j], sA[cb * 160 + 128 + j], s);
        sR[i] = s * sI[ca] * sI[cb];
    }
    __syncthreads();
    for (int i = t; i < 4096; i += 256) {
        int c = i >> 7, ch = i & 127;
        float s = 0.f;
        for (int cp = 0; cp < 32; ++cp)
            s = fmaf(sA[cp * 160 + ch], sR[cp * 32 + c], s);
        cf2b[((size_t)b * 32 + c) * 128 + ch] = f2b(s);
    }
}

// ---------- iteration-1, part A (R12-verified, unchanged) ----------
__global__ __launch_bounds__(512, 2)
void kA1a(const u16* __restrict__ gFp, const int* __restrict__ clu_g,
          const int* __restrict__ clu_s, const u16* __restrict__ cf2b,
          const u16* __restrict__ WPK, const float* __restrict__ BIAS,
          u16* __restrict__ gFo, int* __restrict__ gSeg) {
    __shared__ __attribute__((aligned(16))) u16 sA[128 * 136];
    __shared__ __attribute__((aligned(16))) u16 sB[128 * 136];
    __shared__ __attribute__((aligned(16))) u16 sC[128 * 136];
    __shared__ int sSeg[SEGTOT];
    __shared__ int sClu0[128];
    __shared__ int sClu1[128];
    const int t = threadIdx.x, lane = t & 63, w = t >> 6, lp = lane & 15, q = lane >> 4;
    const int b = blockIdx.y;
    const size_t bN = (size_t)b * N_;
    bf16x8 wfG[4], wf2[8], wf3[2];
    loadWF(WPK + PK_W3 + w * 2048, lane, wfG);
    loadWF(WPK + PK_W1 + 16384 + (w & 3) * 4096, lane, wf2);
    loadWF(WPK + PK_W2 + 8192 + w * 1024, lane, wf3);
    for (int i = t; i < SEGTOT; i += 512) sSeg[i] = 0;
    const u16* cfb = cf2b + (size_t)b * 4096;
    __syncthreads();
    for (int s = 0; s < 8; ++s) {
        const int n0 = (blockIdx.x * 8 + s) * 128;
        const size_t ntB = (size_t)b * 2048 + (size_t)(blockIdx.x * 8 + s) * 8;
        if (t < 128) sClu0[t] = clu_g[bN + n0 + t];
        else if (t < 256) sClu1[t - 128] = clu_s[bN + n0 + (t - 128)];
        const u16* gB = gFp + ntB * 2048;
        convG128w(wfG, BIAS + OB3, gB, sA);
        __syncthreads();
        convCatG128w(wf2, BIAS + OB1 + 64, sA, cfb, sClu0, sB);
        __syncthreads();
        convW2_128w(wf3, BIAS + OB2 + 128, sB, sC, sClu1, sSeg);
        __syncthreads();
        {
#pragma unroll
            for (int r = 0; r < 4; ++r) {
                bf16x8 v = *(const bf16x8*)(sC + (w * 16 + lp) * 136 + r * 32 + q * 8);
                *(bf16x8*)(gFo + ((ntB + w) * 4 + r) * 512 + lane * 8) = v;
            }
        }
        __syncthreads();
    }
    for (int i = t; i < 4096; i += 512) {
        int cl = i >> 7, ch = i & 127;
        atomicMax(&gSeg[b * 5120 + cl * 160 + ch], sSeg[cl * SEGSTR + ch]);
    }
}

// ---------- final conv head: 64-pt, 256 thr, ~36KB LDS -> 4 blocks/CU ----------
__global__ __launch_bounds__(256, 4)
void kC(const u16* __restrict__ gFp, const int* __restrict__ clu_g,
        const u16* __restrict__ cf2b,
        const u16* __restrict__ WPK, const float* __restrict__ BIAS,
        int* __restrict__ gNet) {
    __shared__ __attribute__((aligned(16))) u16 sA[64 * 136];
    __shared__ __attribute__((aligned(16))) u16 sB[64 * 136];
    __shared__ int sNet[128];
    __shared__ int sClu[64];
    const int t = threadIdx.x;
    const int b = blockIdx.y;
    const size_t bN = (size_t)b * N_;
    if (t < 128) sNet[t] = 0;
    const u16* cfb = cf2b + (size_t)b * 4096;
    for (int s = 0; s < 4; ++s) {
        const int n0 = (blockIdx.x * 4 + s) * 64;
        const size_t ntB = (size_t)b * 2048 + (size_t)(blockIdx.x * 4 + s) * 4;
        if (t < 64) sClu[t] = clu_g[bN + n0 + t];
        // P1: w3[1] 128->128 from global fragments (-> sA)
        convG64(WPK + PK_W3 + 16384, BIAS + OB3 + 128, gFp + ntB * 2048, sA);
        __syncthreads();
        // P2: wo1 concat 256->128 (-> sB)
        convCatG64(WPK + PK_WO1, BIAS + OBO1, sA, cfb, sClu, sB);
        __syncthreads();
        // P3: wo2 128->128 + per-channel register-max then atomics
        convNet64(WPK + PK_WO2, BIAS + OBO2, sB, sNet);
        __syncthreads();
    }
    if (t < 128) atomicMax(&gNet[b * 128 + t], sNet[t]);
}

// ---------- tiny MLP head (dual-mode output) ----------
__global__ __launch_bounds__(256)
void kD(const int* __restrict__ gNet, const u16* __restrict__ DWC,
        const float* __restrict__ BIAS, void* __restrict__ outv,
        const int* __restrict__ modep) {
    __shared__ float sN[1024];
    __shared__ float sD1[2048];
    __shared__ float sD2[2048];
    const int mode = *modep;
    const int t = threadIdx.x;
    for (int i = t; i < 1024; i += 256) sN[i] = __int_as_float(gNet[i]);
    __syncthreads();
    for (int i = t; i < 2048; i += 256) {
        int bb = i >> 8, o = i & 255;
        float s = BIAS[ODB1 + o];
        for (int k = 0; k < 128; ++k)
            s = fmaf(sN[bb * 128 + k], b2f(DWC[ODW1 + k * 256 + o]), s);
        sD1[i] = (s >= 0.f) ? s : 0.2f * s;
    }
    __syncthreads();
    for (int i = t; i < 2048; i += 256) {
        int bb = i >> 8, o = i & 255;
        float s = BIAS[ODB2 + o];
        for (int k = 0; k < 256; ++k)
            s = fmaf(sD1[bb * 256 + k], b2f(DWC[ODW2 + k * 256 + o]), s);
        sD2[i] = (s >= 0.f) ? s : 0.2f * s;
    }
    __syncthreads();
    for (int i = t; i < 320; i += 256) {
        int bb = i / 40, o = i - bb * 40;
        float s = BIAS[ODB3 + o];
        for (int k = 0; k < 256; ++k)
            s = fmaf(sD2[bb * 256 + k], b2f(DWC[ODW3 + k * 40 + o]), s);
        if (mode) ((float*)outv)[i] = s;
        else      ((u16*)outv)[i]   = f2b(s);
    }
}

extern "C" void kernel_launch(void* const* d_in, const int* in_sizes, int n_in,
                              void* d_out, int out_size, void* d_ws, size_t ws_size,
                              hipStream_t stream) {
    const void* feat = d_in[0];
    const int* clus = (const int*)d_in[1];

    char* ws = (char*)d_ws;
    u16*   WPK   = (u16*)(ws + OFS_WPK);
    float* BIAS  = (float*)(ws + OFS_BIAS);
    u16*   DWC   = (u16*)(ws + OFS_DWC);
    int*   modep = (int*)(ws + OFS_MODE);
    u16*   FEATC = (u16*)(ws + OFS_FEATC);
    int*   seg0  = (int*)(ws + OFS_GACC0);
    int*   seg1  = (int*)(ws + OFS_GACC1);
    int*   gNet  = (int*)(ws + OFS_GNET);
    u16*   cf2b0 = (u16*)(ws + OFS_CF2B0);
    u16*   cf2b1 = (u16*)(ws + OFS_CF2B1);
    u16*   f0    = (u16*)(ws + OFS_F0);
    u16*   f1    = (u16*)(ws + OFS_F1);

    hipMemsetAsync(ws + OFS_GACC0, 0, GACC_ZERO_BYTES, stream);
    hipLaunchKernelGGL(kSniff, dim3(1), dim3(256), 0, stream, (const u16*)feat, modep);
    hipLaunchKernelGGL(kPrep, dim3(256), dim3(256), 0, stream,
                       feat, d_in[2], d_in[3], d_in[4], d_in[5], d_in[6], d_in[7],
                       d_in[8], d_in[9], d_in[10], d_in[11], d_in[12], d_in[13],
                       d_in[14], d_in[15], d_in[16], d_in[17], d_in[18], d_in[19],
                       d_in[20], d_in[21], d_in[22], d_in[23], d_in[24], d_in[25],
                       WPK, BIAS, DWC, FEATC, modep);

    const int* clu0 = clus;
    const int* clu1 = clus + (size_t)B_ * N_;

    hipLaunchKernelGGL(kA0a, dim3(32, 8), dim3(512), 0, stream,
                       FEATC, clu0, WPK, BIAS, f0, seg0);
    hipLaunchKernelGGL(kA0b, dim3(128, 8), dim3(256), 0, stream,
                       f0, clu0, WPK, BIAS, seg0);
    hipLaunchKernelGGL(kB, dim3(8), dim3(256), 0, stream, seg0, cf2b0);
    hipLaunchKernelGGL(kA1a, dim3(32, 8), dim3(512), 0, stream,
                       f0, clu0, clu1, cf2b0, WPK, BIAS, f1, seg1);
    hipLaunchKernelGGL(kA1b, dim3(128, 8), dim3(256), 0, stream,
                       f1, clu1, WPK, BIAS, seg1);
    hipLaunchKernelGGL(kB, dim3(8), dim3(256), 0, stream, seg1, cf2b1);
    hipLaunchKernelGGL(kC, dim3(128, 8), dim3(256), 0, stream,
                       f1, clu1, cf2b1, WPK, BIAS, gNet);
    hipLaunchKernelGGL(kD, dim3(1), dim3(256), 0, stream,
                       gNet, DWC, BIAS, d_out, modep);
}

// Round 15
// 601.664 us; speedup vs baseline: 1.2172x; 1.2172x over previous
//
#include <hip/hip_runtime.h>
#include <stdint.h>

// Problem constants
#define B_   8
#define N_   32768
#define C_   32
#define K_   22
#define CAT_ 40

typedef unsigned short u16;
typedef unsigned int   u32;

typedef __attribute__((ext_vector_type(8))) short bf16x8;
typedef __attribute__((ext_vector_type(4))) float f32x4;

#define MFMA(a, b, c) __builtin_amdgcn_mfma_f32_16x16x32_bf16(a, b, c, 0, 0, 0)

// ---------- bf16 helpers (raw bits) ----------
__device__ __forceinline__ float b2f(u16 v) { return __uint_as_float(((u32)v) << 16); }
__device__ __forceinline__ u16 f2b(float f) {
    u32 x = __float_as_uint(f);
    return (u16)((x + 0x7fffu + ((x >> 16) & 1u)) >> 16);   // RNE
}
__device__ __forceinline__ u32 pk2(float a, float b) {
    return (u32)f2b(a) | ((u32)f2b(b) << 16);
}

// ---------- packed MFMA A-fragment weight offsets (u16 units) ----------
#define PK_WIN 0         // 256x32(pad), KB=1 : 8192
#define PK_W1  8192      // 2 x 64x256, KB=8  : 16384 each
#define PK_W2  40960     // 2 x 128x64, KB=2  : 8192 each
#define PK_W3  57344     // 2 x 128x128, KB=4 : 16384 each
#define PK_WC1 90112     // 2 x 128x128       : 16384 each
#define PK_WC2 122880    // 2 x 256x128, KB=4 : 32768 each
#define PK_WC3 188416    // 2 x 32x256, KB=8  : 8192 each
#define PK_WO1 204800    // 128x256, KB=8     : 32768
#define PK_WO2 237568    // 128x128, KB=4     : 16384

// ---------- fp32 bias block offsets (floats) ----------
#define OBIN 0
#define OB1  256
#define OB2  384
#define OB3  640
#define OBC1 896
#define OBC2 1152
#define OBC3 1664
#define OBO1 1728
#define OBO2 1856
#define ODB1 1984
#define ODB2 2240
#define ODB3 2496

// ---------- canonical bf16 dense-head weights (u16 offsets) ----------
#define ODW1 0
#define ODW2 32768
#define ODW3 98304

// ---------- workspace byte offsets ----------
#define OFS_WPK   0u
#define OFS_BIAS  524288u
#define OFS_DWC   540672u
#define OFS_MODE  786432u
#define OFS_FEATC 1048576u
#define OFS_GACC0 12582912u
#define OFS_GACC1 12746752u
#define OFS_GNET  12910592u
#define GACC_ZERO_BYTES 331776u
#define OFS_CF2B0 12914688u
#define OFS_CF2B1 12980224u
#define OFS_F0    16777216u     // fragment-major f: [b][nt(2048 of 16 pts)][kb(4)][lane(64)][8] bf16
#define OFS_F1    83886080u

// sSeg LDS layout: stride 161 dwords (160%32==0 caused 16-way bank conflicts on
// every seg-max atomic — round-6 lesson). bank=(cl*161+co)%32=(cl+co)%32.
#define SEGSTR 161
#define SEGTOT (32 * SEGSTR)

// ---------- dtype sniffer ----------
__global__ void kSniff(const u16* __restrict__ featAny, int* __restrict__ mode) {
    __shared__ int cnt;
    if (threadIdx.x == 0) cnt = 0;
    __syncthreads();
    int weird = 0;
    for (int j = 0; j < 4; ++j) {
        u16 v = featAny[threadIdx.x * 4 + j];
        float f = b2f(v);
        if (v == 0 || !(fabsf(f) < 1e10f)) weird++;
    }
    if (weird) atomicAdd(&cnt, weird);
    __syncthreads();
    if (threadIdx.x == 0) *mode = (cnt > 64) ? 1 : 0;
}

__device__ __forceinline__ float fetchF(const void* src, size_t i, int mode) {
    return mode ? ((const float*)src)[i] : b2f(((const u16*)src)[i]);
}

// ---------- weight pack: (COUT,CIN) -> MFMA A-fragment bf16 order ----------
__device__ void packA(const void* __restrict__ src, u16* __restrict__ dst,
                      int COUT, int CIN, int mode, int tid, int np) {
    int KB = (CIN + 31) / 32;
    int tiles = COUT / 16;
    int tot = tiles * KB * 64 * 8;
    for (int i = tid; i < tot; i += np) {
        int j = i & 7;
        int L = (i >> 3) & 63;
        int rest = i >> 9;
        int kb = rest % KB, tile = rest / KB;
        int co = tile * 16 + (L & 15);
        int ci = kb * 32 + (L >> 4) * 8 + j;
        float v = (ci < CIN) ? fetchF(src, (size_t)co * CIN + ci, mode) : 0.f;
        dst[i] = f2b(v);
    }
}

__device__ void cvtF(const void* __restrict__ src, float* __restrict__ dst,
                     int n, int mode, int tid, int np) {
    for (int i = tid; i < n; i += np) dst[i] = fetchF(src, i, mode);
}

__device__ void cvtB(const void* __restrict__ src, u16* __restrict__ dst,
                     int n, int mode, int tid, int np) {
    for (int i = tid; i < n; i += np)
        dst[i] = mode ? f2b(((const float*)src)[i]) : ((const u16*)src)[i];
}

__global__ void kPrep(const void* feat, const void* w_in, const void* b_in,
                      const void* w1, const void* b1, const void* w2, const void* b2,
                      const void* w3, const void* b3,
                      const void* wc1, const void* bc1, const void* wc2, const void* bc2,
                      const void* wc3, const void* bc3,
                      const void* wo1, const void* bo1, const void* wo2, const void* bo2,
                      const void* dw1, const void* db1, const void* dw2, const void* db2,
                      const void* dw3, const void* db3,
                      u16* WPK, float* BIAS, u16* DWC, u16* FEATC,
                      const int* __restrict__ modep) {
    const int mode = *modep;
    int tid = blockIdx.x * blockDim.x + threadIdx.x;
    int np  = gridDim.x * blockDim.x;
    cvtB(feat, FEATC, B_ * N_ * K_, mode, tid, np);
    packA(w_in, WPK + PK_WIN, 256, 22, mode, tid, np);
    packA(w1,                                 WPK + PK_W1,          64, 256, mode, tid, np);
    packA((const u16*)w1 + (mode?32768:16384), WPK + PK_W1 + 16384,  64, 256, mode, tid, np);
    packA(w2,                                 WPK + PK_W2,          128, 64, mode, tid, np);
    packA((const u16*)w2 + (mode?16384:8192),  WPK + PK_W2 + 8192,   128, 64, mode, tid, np);
    packA(w3,                                 WPK + PK_W3,          128, 128, mode, tid, np);
    packA((const u16*)w3 + (mode?32768:16384), WPK + PK_W3 + 16384,  128, 128, mode, tid, np);
    packA(wc1,                                WPK + PK_WC1,         128, 128, mode, tid, np);
    packA((const u16*)wc1 + (mode?32768:16384),WPK + PK_WC1 + 16384, 128, 128, mode, tid, np);
    packA(wc2,                                WPK + PK_WC2,         256, 128, mode, tid, np);
    packA((const u16*)wc2 + (mode?65536:32768),WPK + PK_WC2 + 32768, 256, 128, mode, tid, np);
    packA(wc3,                                WPK + PK_WC3,         32, 256, mode, tid, np);
    packA((const u16*)wc3 + (mode?16384:8192), WPK + PK_WC3 + 8192,  32, 256, mode, tid, np);
    packA(wo1, WPK + PK_WO1, 128, 256, mode, tid, np);
    packA(wo2, WPK + PK_WO2, 128, 128, mode, tid, np);
    cvtF(b_in, BIAS + OBIN, 256, mode, tid, np);
    cvtF(b1,   BIAS + OB1,  128, mode, tid, np);
    cvtF(b2,   BIAS + OB2,  256, mode, tid, np);
    cvtF(b3,   BIAS + OB3,  256, mode, tid, np);
    cvtF(bc1,  BIAS + OBC1, 256, mode, tid, np);
    cvtF(bc2,  BIAS + OBC2, 512, mode, tid, np);
    cvtF(bc3,  BIAS + OBC3, 64,  mode, tid, np);
    cvtF(bo1,  BIAS + OBO1, 128, mode, tid, np);
    cvtF(bo2,  BIAS + OBO2, 128, mode, tid, np);
    cvtF(db1,  BIAS + ODB1, 256, mode, tid, np);
    cvtF(db2,  BIAS + ODB2, 256, mode, tid, np);
    cvtF(db3,  BIAS + ODB3, 40,  mode, tid, np);
    cvtB(dw1, DWC + ODW1, 128 * 256, mode, tid, np);
    cvtB(dw2, DWC + ODW2, 256 * 256, mode, tid, np);
    cvtB(dw3, DWC + ODW3, 256 * 40,  mode, tid, np);
}

__device__ __forceinline__ void storeRow(u16* __restrict__ buf, int p, int col,
                                         float r0, float r1, float r2, float r3) {
    *(uint2*)(buf + p * 136 + col) = make_uint2(pk2(r0, r1), pk2(r2, r3));
}

// Load a wave's weight fragments for one phase into registers (R8 formulation —
// measured ~9% faster than inline per-MFMA loads at identical structure).
template<int NF>
__device__ __forceinline__ void loadWF(const u16* __restrict__ wA, int lane, bf16x8 (&wf)[NF]) {
#pragma unroll
    for (int i = 0; i < NF; ++i)
        wf[i] = *(const bf16x8*)(wA + ((size_t)(i * 64 + lane)) * 8);
}

// ================= 8-wave / 128-pt building blocks (R12-verified, wf-array form) ==========
template<int KB, int INS>
__device__ __forceinline__ void convP128w(const bf16x8 (&wf)[KB], const float* __restrict__ bias,
                                          const u16* __restrict__ sIn, u16* __restrict__ sOut) {
    const int t = threadIdx.x, lane = t & 63, w = t >> 6, lp = lane & 15, q = lane >> 4;
    f32x4 acc[8] = {};
#pragma unroll
    for (int kb = 0; kb < KB; ++kb) {
        bf16x8 bb[8];
#pragma unroll
        for (int pt = 0; pt < 8; ++pt)
            bb[pt] = *(const bf16x8*)(sIn + (pt * 16 + lp) * INS + kb * 32 + q * 8);
#pragma unroll
        for (int pt = 0; pt < 8; ++pt) acc[pt] = MFMA(wf[kb], bb[pt], acc[pt]);
    }
    const int co = w * 16 + q * 4;
    f32x4 bv = *(const f32x4*)(bias + co);
#pragma unroll
    for (int pt = 0; pt < 8; ++pt) {
        f32x4 v = acc[pt];
        storeRow(sOut, pt * 16 + lp, co,
                 fmaxf(v[0] + bv[0], 0.f), fmaxf(v[1] + bv[1], 0.f),
                 fmaxf(v[2] + bv[2], 0.f), fmaxf(v[3] + bv[3], 0.f));
    }
}

// w2 64->128 fused: LDS store + f32 seg-max atomics from registers.
__device__ __forceinline__ void convW2_128w(const bf16x8 (&wf)[2], const float* __restrict__ bias,
                                            const u16* __restrict__ sIn, u16* __restrict__ sOut,
                                            const int* __restrict__ sCluSeg, int* __restrict__ sSeg) {
    const int t = threadIdx.x, lane = t & 63, w = t >> 6, lp = lane & 15, q = lane >> 4;
    f32x4 acc[8] = {};
#pragma unroll
    for (int kb = 0; kb < 2; ++kb) {
        bf16x8 bb[8];
#pragma unroll
        for (int pt = 0; pt < 8; ++pt)
            bb[pt] = *(const bf16x8*)(sIn + (pt * 16 + lp) * 136 + kb * 32 + q * 8);
#pragma unroll
        for (int pt = 0; pt < 8; ++pt) acc[pt] = MFMA(wf[kb], bb[pt], acc[pt]);
    }
    const int co = w * 16 + q * 4;
    f32x4 bv = *(const f32x4*)(bias + co);
#pragma unroll
    for (int pt = 0; pt < 8; ++pt) {
        f32x4 v = acc[pt];
        const int p = pt * 16 + lp;
        float r0 = fmaxf(v[0] + bv[0], 0.f), r1 = fmaxf(v[1] + bv[1], 0.f);
        float r2 = fmaxf(v[2] + bv[2], 0.f), r3 = fmaxf(v[3] + bv[3], 0.f);
        *(uint2*)(sOut + p * 136 + co) = make_uint2(pk2(r0, r1), pk2(r2, r3));
        const int sb = sCluSeg[p] * SEGSTR + co;
        atomicMax(&sSeg[sb + 0], __float_as_int(r0));
        atomicMax(&sSeg[sb + 1], __float_as_int(r1));
        atomicMax(&sSeg[sb + 2], __float_as_int(r2));
        atomicMax(&sSeg[sb + 3], __float_as_int(r3));
    }
}

// w1 256->64 concat (both halves in LDS): co-tile (w&3), p-group (w>>2)*4.
__device__ __forceinline__ void convCat128w(const bf16x8 (&wf)[8], const float* __restrict__ bias,
                                            const u16* __restrict__ sLo, const u16* __restrict__ sHi,
                                            u16* __restrict__ sOut) {
    const int t = threadIdx.x, lane = t & 63, w = t >> 6, lp = lane & 15, q = lane >> 4;
    const int ct = w & 3, pp = (w >> 2) * 4;
    f32x4 acc[4] = {};
#pragma unroll
    for (int kb = 0; kb < 8; ++kb) {
        const u16* sIn = (kb < 4) ? sLo : sHi;
        const int col = (kb & 3) * 32 + q * 8;
        bf16x8 bb[4];
#pragma unroll
        for (int i = 0; i < 4; ++i)
            bb[i] = *(const bf16x8*)(sIn + ((pp + i) * 16 + lp) * 136 + col);
#pragma unroll
        for (int i = 0; i < 4; ++i) acc[i] = MFMA(wf[kb], bb[i], acc[i]);
    }
    const int co = ct * 16 + q * 4;
    f32x4 bv = *(const f32x4*)(bias + co);
#pragma unroll
    for (int i = 0; i < 4; ++i) {
        f32x4 v = acc[i];
        storeRow(sOut, (pp + i) * 16 + lp, co,
                 fmaxf(v[0] + bv[0], 0.f), fmaxf(v[1] + bv[1], 0.f),
                 fmaxf(v[2] + bv[2], 0.f), fmaxf(v[3] + bv[3], 0.f));
    }
}

// w1 256->64 concat, upper half gathered per-lane from bf16 cf2b (L2-hot, 64 KB).
__device__ __forceinline__ void convCatG128w(const bf16x8 (&wf)[8], const float* __restrict__ bias,
                                             const u16* __restrict__ sIn, const u16* __restrict__ cfb,
                                             const int* __restrict__ sClu, u16* __restrict__ sOut) {
    const int t = threadIdx.x, lane = t & 63, w = t >> 6, lp = lane & 15, q = lane >> 4;
    const int ct = w & 3, pp = (w >> 2) * 4;
    f32x4 acc[4] = {};
#pragma unroll
    for (int kb = 0; kb < 8; ++kb) {
        bf16x8 bb[4];
#pragma unroll
        for (int i = 0; i < 4; ++i) {
            const int p = (pp + i) * 16 + lp;
            if (kb < 4) bb[i] = *(const bf16x8*)(sIn + p * 136 + kb * 32 + q * 8);
            else        bb[i] = *(const bf16x8*)(cfb + sClu[p] * 128 + (kb - 4) * 32 + q * 8);
        }
#pragma unroll
        for (int i = 0; i < 4; ++i) acc[i] = MFMA(wf[kb], bb[i], acc[i]);
    }
    const int co = ct * 16 + q * 4;
    f32x4 bv = *(const f32x4*)(bias + co);
#pragma unroll
    for (int i = 0; i < 4; ++i) {
        f32x4 v = acc[i];
        storeRow(sOut, (pp + i) * 16 + lp, co,
                 fmaxf(v[0] + bv[0], 0.f), fmaxf(v[1] + bv[1], 0.f),
                 fmaxf(v[2] + bv[2], 0.f), fmaxf(v[3] + bv[3], 0.f));
    }
}

// CIN=128 conv, B direct from global fragment-major f (128-pt group).
__device__ __forceinline__ void convG128w(const bf16x8 (&wf)[4], const float* __restrict__ bias,
                                          const u16* __restrict__ gB, u16* __restrict__ sOut) {
    const int t = threadIdx.x, lane = t & 63, w = t >> 6, lp = lane & 15, q = lane >> 4;
    f32x4 acc[8] = {};
#pragma unroll
    for (int kb = 0; kb < 4; ++kb) {
        bf16x8 bb[8];
#pragma unroll
        for (int pt = 0; pt < 8; ++pt)
            bb[pt] = *(const bf16x8*)(gB + pt * 2048 + kb * 512 + lane * 8);
#pragma unroll
        for (int pt = 0; pt < 8; ++pt) acc[pt] = MFMA(wf[kb], bb[pt], acc[pt]);
    }
    const int co = w * 16 + q * 4;
    f32x4 bv = *(const f32x4*)(bias + co);
#pragma unroll
    for (int pt = 0; pt < 8; ++pt) {
        f32x4 v = acc[pt];
        storeRow(sOut, pt * 16 + lp, co,
                 fmaxf(v[0] + bv[0], 0.f), fmaxf(v[1] + bv[1], 0.f),
                 fmaxf(v[2] + bv[2], 0.f), fmaxf(v[3] + bv[3], 0.f));
    }
}

// wc3 (32x256) + corr seg-max: co-tile (w&1), p-pair (w>>1)*2.
__device__ __forceinline__ void wc3seg128w(const bf16x8 (&wf)[8], const float* __restrict__ bias,
                                           const u16* __restrict__ sLo, const u16* __restrict__ sHi,
                                           const int* __restrict__ sClu, int* __restrict__ sSeg) {
    const int t = threadIdx.x, lane = t & 63, w = t >> 6, lp = lane & 15, q = lane >> 4;
    const int ct = w & 1, pp = (w >> 1) * 2;
    f32x4 acc[2] = {};
#pragma unroll
    for (int kb = 0; kb < 8; ++kb) {
        const u16* sIn = (kb < 4) ? sLo : sHi;
        const int col = (kb & 3) * 32 + q * 8;
        bf16x8 b0 = *(const bf16x8*)(sIn + ((pp + 0) * 16 + lp) * 136 + col);
        bf16x8 b1 = *(const bf16x8*)(sIn + ((pp + 1) * 16 + lp) * 136 + col);
        acc[0] = MFMA(wf[kb], b0, acc[0]);
        acc[1] = MFMA(wf[kb], b1, acc[1]);
    }
    const int col = ct * 16 + q * 4;
    f32x4 bv = *(const f32x4*)(bias + col);
#pragma unroll
    for (int i = 0; i < 2; ++i) {
        const int p = (pp + i) * 16 + lp;
        const int cl = sClu[p];
        f32x4 v = acc[i];
        atomicMax(&sSeg[cl * SEGSTR + 128 + col + 0], __float_as_int(fmaxf(v[0] + bv[0], 0.f)));
        atomicMax(&sSeg[cl * SEGSTR + 128 + col + 1], __float_as_int(fmaxf(v[1] + bv[1], 0.f)));
        atomicMax(&sSeg[cl * SEGSTR + 128 + col + 2], __float_as_int(fmaxf(v[2] + bv[2], 0.f)));
        atomicMax(&sSeg[cl * SEGSTR + 128 + col + 3], __float_as_int(fmaxf(v[3] + bv[3], 0.f)));
    }
}

// ---------- kC building blocks (wf-array form, R15 delta) ----------
// wo1 256->128 concat: wave w -> co-tile w, 8 p-tiles; kb<4 from sIn, kb>=4 cf2b gather.
__device__ __forceinline__ void convCatG128ow(const bf16x8 (&wf)[8], const float* __restrict__ bias,
                                              const u16* __restrict__ sIn, const u16* __restrict__ cfb,
                                              const int* __restrict__ sClu, u16* __restrict__ sOut) {
    const int t = threadIdx.x, lane = t & 63, w = t >> 6, lp = lane & 15, q = lane >> 4;
    f32x4 acc[8] = {};
#pragma unroll
    for (int kb = 0; kb < 8; ++kb) {
        bf16x8 bb[8];
#pragma unroll
        for (int pt = 0; pt < 8; ++pt) {
            const int p = pt * 16 + lp;
            if (kb < 4) bb[pt] = *(const bf16x8*)(sIn + p * 136 + kb * 32 + q * 8);
            else        bb[pt] = *(const bf16x8*)(cfb + sClu[p] * 128 + (kb - 4) * 32 + q * 8);
        }
#pragma unroll
        for (int pt = 0; pt < 8; ++pt) acc[pt] = MFMA(wf[kb], bb[pt], acc[pt]);
    }
    const int co = w * 16 + q * 4;
    f32x4 bv = *(const f32x4*)(bias + co);
#pragma unroll
    for (int pt = 0; pt < 8; ++pt) {
        f32x4 v = acc[pt];
        storeRow(sOut, pt * 16 + lp, co,
                 fmaxf(v[0] + bv[0], 0.f), fmaxf(v[1] + bv[1], 0.f),
                 fmaxf(v[2] + bv[2], 0.f), fmaxf(v[3] + bv[3], 0.f));
    }
}

// wo2 128->128 + per-channel max: register-max over 8 p-tiles FIRST, then one
// atomicMax per lane-channel.
__device__ __forceinline__ void convNet128w(const bf16x8 (&wf)[4], const float* __restrict__ bias,
                                            const u16* __restrict__ sIn, int* __restrict__ sNet) {
    const int t = threadIdx.x, lane = t & 63, w = t >> 6, lp = lane & 15, q = lane >> 4;
    f32x4 acc[8] = {};
#pragma unroll
    for (int kb = 0; kb < 4; ++kb) {
        bf16x8 bb[8];
#pragma unroll
        for (int pt = 0; pt < 8; ++pt)
            bb[pt] = *(const bf16x8*)(sIn + (pt * 16 + lp) * 136 + kb * 32 + q * 8);
#pragma unroll
        for (int pt = 0; pt < 8; ++pt) acc[pt] = MFMA(wf[kb], bb[pt], acc[pt]);
    }
    const int co = w * 16 + q * 4;
    f32x4 bv = *(const f32x4*)(bias + co);
    f32x4 m = acc[0];
#pragma unroll
    for (int pt = 1; pt < 8; ++pt) {
        m[0] = fmaxf(m[0], acc[pt][0]); m[1] = fmaxf(m[1], acc[pt][1]);
        m[2] = fmaxf(m[2], acc[pt][2]); m[3] = fmaxf(m[3], acc[pt][3]);
    }
    atomicMax(&sNet[co + 0], __float_as_int(fmaxf(m[0] + bv[0], 0.f)));
    atomicMax(&sNet[co + 1], __float_as_int(fmaxf(m[1] + bv[1], 0.f)));
    atomicMax(&sNet[co + 2], __float_as_int(fmaxf(m[2] + bv[2], 0.f)));
    atomicMax(&sNet[co + 3], __float_as_int(fmaxf(m[3] + bv[3], 0.f)));
}

// ---------- iteration-0, part A: w_in -> w1 -> w2 (+f seg, gF store). 64KB weights/block ----------
__global__ __launch_bounds__(512, 2)
void kA0a(const u16* __restrict__ featc, const int* __restrict__ clu0,
          const u16* __restrict__ WPK, const float* __restrict__ BIAS,
          u16* __restrict__ gF, int* __restrict__ gSeg) {
    __shared__ __attribute__((aligned(16))) u16 sA[128 * 136];
    __shared__ __attribute__((aligned(16))) u16 sB[128 * 136];
    __shared__ __attribute__((aligned(16))) u16 sC[128 * 136];
    __shared__ __attribute__((aligned(16))) u16 sFeat[128 * 40];
    __shared__ int sSeg[SEGTOT];
    __shared__ int sClu[128];
    const int t = threadIdx.x, lane = t & 63, w = t >> 6, lp = lane & 15, q = lane >> 4;
    const int b = blockIdx.y;
    const size_t bN = (size_t)b * N_;
    bf16x8 wf1a[1], wf1b[1], wf2[8], wf3[2];
    loadWF(WPK + PK_WIN + w * 512, lane, wf1a);
    loadWF(WPK + PK_WIN + 4096 + w * 512, lane, wf1b);
    loadWF(WPK + PK_W1 + (w & 3) * 4096, lane, wf2);
    loadWF(WPK + PK_W2 + w * 1024, lane, wf3);
    for (int i = t; i < SEGTOT; i += 512) sSeg[i] = 0;
    {
        const int n0 = blockIdx.x * 1024;
        for (int i = t; i < 5120; i += 512) {
            int p = i / 40, k = i - p * 40;
            sFeat[i] = (k < 22) ? featc[(bN + n0 + p) * 22 + k] : (u16)0;
        }
    }
    __syncthreads();
    for (int s = 0; s < 8; ++s) {
        const int n0 = (blockIdx.x * 8 + s) * 128;
        const size_t ntB = (size_t)b * 2048 + (size_t)(blockIdx.x * 8 + s) * 8;
        if (t < 128) sClu[t] = clu0[bN + n0 + t];
        // P1: w_in 22->256 (lo->sA, hi->sB)
        convP128w<1, 40>(wf1a, BIAS + OBIN,       sFeat, sA);
        convP128w<1, 40>(wf1b, BIAS + OBIN + 128, sFeat, sB);
        __syncthreads();
        // P2: w1 256->64 (h -> sC)
        convCat128w(wf2, BIAS + OB1, sA, sB, sC);
        __syncthreads();
        // P3: w2 64->128 fused (f -> sA + f32 seg-max from regs)
        convW2_128w(wf3, BIAS + OB2, sC, sA, sClu, sSeg);
        __syncthreads();
        // P4: fragment-major gF store + next-feat stage
        {
#pragma unroll
            for (int r = 0; r < 4; ++r) {
                bf16x8 v = *(const bf16x8*)(sA + (w * 16 + lp) * 136 + r * 32 + q * 8);
                *(bf16x8*)(gF + ((ntB + w) * 4 + r) * 512 + lane * 8) = v;
            }
        }
        if (s < 7) {
            const int n1 = n0 + 128;
            for (int i = t; i < 5120; i += 512) {
                int p = i / 40, k = i - p * 40;
                sFeat[i] = (k < 22) ? featc[(bN + n1 + p) * 22 + k] : (u16)0;
            }
        }
        __syncthreads();
    }
    for (int i = t; i < 4096; i += 512) {
        int cl = i >> 7, ch = i & 127;
        atomicMax(&gSeg[b * 5120 + cl * 160 + ch], sSeg[cl * SEGSTR + ch]);
    }
}

// ---------- part B: wc1 -> wc2 -> wc3 (+corr seg). f consumed from global fragments ----------
template<int PKOFF, int BOFF>
__device__ __forceinline__ void kAbBody(const u16* __restrict__ gFp, const int* __restrict__ clu,
                                        const u16* __restrict__ WPK, const float* __restrict__ BIAS,
                                        int* __restrict__ gSeg) {
    __shared__ __attribute__((aligned(16))) u16 sA[128 * 136];
    __shared__ __attribute__((aligned(16))) u16 sB[128 * 136];
    __shared__ __attribute__((aligned(16))) u16 sC[128 * 136];
    __shared__ int sSeg[SEGTOT];
    __shared__ int sClu[128];
    const int t = threadIdx.x, lane = t & 63, w = t >> 6;
    const int b = blockIdx.y;
    const size_t bN = (size_t)b * N_;
    bf16x8 wf4[4], wf5a[4], wf5b[4], wf6[8];
    loadWF(WPK + PK_WC1 + PKOFF * 16384 + w * 2048, lane, wf4);
    loadWF(WPK + PK_WC2 + PKOFF * 32768 + w * 2048, lane, wf5a);
    loadWF(WPK + PK_WC2 + PKOFF * 32768 + 16384 + w * 2048, lane, wf5b);
    loadWF(WPK + PK_WC3 + PKOFF * 8192 + (w & 1) * 4096, lane, wf6);
    for (int i = t; i < SEGTOT; i += 512) sSeg[i] = 0;
    __syncthreads();
    for (int s = 0; s < 8; ++s) {
        const int n0 = (blockIdx.x * 8 + s) * 128;
        const size_t ntB = (size_t)b * 2048 + (size_t)(blockIdx.x * 8 + s) * 8;
        if (t < 128) sClu[t] = clu[bN + n0 + t];
        const u16* gB = gFp + ntB * 2048;
        // P1: wc1 128->128, B direct from global f fragments (c1 -> sA)
        convG128w(wf4, BIAS + OBC1 + BOFF * 128, gB, sA);
        __syncthreads();
        // P2: wc2 128->256, two passes (corrLo -> sB, corrHi -> sC)
        convP128w<4, 136>(wf5a, BIAS + OBC2 + BOFF * 256,       sA, sB);
        convP128w<4, 136>(wf5b, BIAS + OBC2 + BOFF * 256 + 128, sA, sC);
        __syncthreads();
        // P3: wc3 + corr seg-max
        wc3seg128w(wf6, BIAS + OBC3 + BOFF * 32, sB, sC, sClu, sSeg);
        __syncthreads();
    }
    for (int i = t; i < 1024; i += 512) {
        int cl = i >> 5, ch = i & 31;
        atomicMax(&gSeg[b * 5120 + cl * 160 + 128 + ch], sSeg[cl * SEGSTR + 128 + ch]);
    }
}

__global__ __launch_bounds__(512, 2)
void kA0b(const u16* __restrict__ gFp, const int* __restrict__ clu0,
          const u16* __restrict__ WPK, const float* __restrict__ BIAS,
          int* __restrict__ gSeg) {
    kAbBody<0, 0>(gFp, clu0, WPK, BIAS, gSeg);
}

__global__ __launch_bounds__(512, 2)
void kA1b(const u16* __restrict__ gFp, const int* __restrict__ clu1,
          const u16* __restrict__ WPK, const float* __restrict__ BIAS,
          int* __restrict__ gSeg) {
    kAbBody<1, 1>(gFp, clu1, WPK, BIAS, gSeg);
}

// ---------- per-batch cluster math -> bf16 cf2b ----------
__global__ __launch_bounds__(256)
void kB(const int* __restrict__ gSeg, u16* __restrict__ cf2b) {
    __shared__ float sA[5120];
    __shared__ float sR[1024];
    __shared__ float sI[32];
    const int t = threadIdx.x, b = blockIdx.x;
    for (int i = t; i < 5120; i += 256) sA[i] = __int_as_float(gSeg[b * 5120 + i]);
    __syncthreads();
    if (t < 32) {
        float s = 0.f;
        for (int j = 0; j < 32; ++j) { float v = sA[t * 160 + 128 + j]; s = fmaf(v, v, s); }
        sI[t] = 1.f / fmaxf(sqrtf(s), 1e-12f);
    }
    __syncthreads();
    for (int i = t; i < 1024; i += 256) {
        int ca = i >> 5, cb = i & 31;
        float s = 0.f;
        for (int j = 0; j < 32; ++j)
            s = fmaf(sA[ca * 160 + 128 + j], sA[cb * 160 + 128 + j], s);
        sR[i] = s * sI[ca] * sI[cb];
    }
    __syncthreads();
    for (int i = t; i < 4096; i += 256) {
        int c = i >> 7, ch = i & 127;
        float s = 0.f;
        for (int cp = 0; cp < 32; ++cp)
            s = fmaf(sA[cp * 160 + ch], sR[cp * 32 + c], s);
        cf2b[((size_t)b * 32 + c) * 128 + ch] = f2b(s);
    }
}

// ---------- iteration-1, part A: w3 -> w1concat -> w2 (+f seg, gFo store) ----------
__global__ __launch_bounds__(512, 2)
void kA1a(const u16* __restrict__ gFp, const int* __restrict__ clu_g,
          const int* __restrict__ clu_s, const u16* __restrict__ cf2b,
          const u16* __restrict__ WPK, const float* __restrict__ BIAS,
          u16* __restrict__ gFo, int* __restrict__ gSeg) {
    __shared__ __attribute__((aligned(16))) u16 sA[128 * 136];
    __shared__ __attribute__((aligned(16))) u16 sB[128 * 136];
    __shared__ __attribute__((aligned(16))) u16 sC[128 * 136];
    __shared__ int sSeg[SEGTOT];
    __shared__ int sClu0[128];
    __shared__ int sClu1[128];
    const int t = threadIdx.x, lane = t & 63, w = t >> 6, lp = lane & 15, q = lane >> 4;
    const int b = blockIdx.y;
    const size_t bN = (size_t)b * N_;
    bf16x8 wfG[4], wf2[8], wf3[2];
    loadWF(WPK + PK_W3 + w * 2048, lane, wfG);
    loadWF(WPK + PK_W1 + 16384 + (w & 3) * 4096, lane, wf2);
    loadWF(WPK + PK_W2 + 8192 + w * 1024, lane, wf3);
    for (int i = t; i < SEGTOT; i += 512) sSeg[i] = 0;
    const u16* cfb = cf2b + (size_t)b * 4096;
    __syncthreads();
    for (int s = 0; s < 8; ++s) {
        const int n0 = (blockIdx.x * 8 + s) * 128;
        const size_t ntB = (size_t)b * 2048 + (size_t)(blockIdx.x * 8 + s) * 8;
        if (t < 128) sClu0[t] = clu_g[bN + n0 + t];
        else if (t < 256) sClu1[t - 128] = clu_s[bN + n0 + (t - 128)];
        const u16* gB = gFp + ntB * 2048;
        // P1: w3 128->128, B direct from global fragments (f3 -> sA)
        convG128w(wfG, BIAS + OB3, gB, sA);
        __syncthreads();
        // P2: w1 concat(w3out, pool-gather) 256->64 (h -> sB)
        convCatG128w(wf2, BIAS + OB1 + 64, sA, cfb, sClu0, sB);
        __syncthreads();
        // P3: w2 64->128 fused (f -> sC + f32 seg-max from regs)
        convW2_128w(wf3, BIAS + OB2 + 128, sB, sC, sClu1, sSeg);
        __syncthreads();
        // P4: fragment-major gFo store
        {
#pragma unroll
            for (int r = 0; r < 4; ++r) {
                bf16x8 v = *(const bf16x8*)(sC + (w * 16 + lp) * 136 + r * 32 + q * 8);
                *(bf16x8*)(gFo + ((ntB + w) * 4 + r) * 512 + lane * 8) = v;
            }
        }
        __syncthreads();
    }
    for (int i = t; i < 4096; i += 512) {
        int cl = i >> 7, ch = i & 127;
        atomicMax(&gSeg[b * 5120 + cl * 160 + ch], sSeg[cl * SEGSTR + ch]);
    }
}

// ---------- final conv head: 512 thr, 128-pt subtiles, wf-hoisted weights (R15 delta) ----------
__global__ __launch_bounds__(512, 2)
void kC(const u16* __restrict__ gFp, const int* __restrict__ clu_g,
        const u16* __restrict__ cf2b,
        const u16* __restrict__ WPK, const float* __restrict__ BIAS,
        int* __restrict__ gNet) {
    __shared__ __attribute__((aligned(16))) u16 sA[128 * 136];
    __shared__ __attribute__((aligned(16))) u16 sB[128 * 136];
    __shared__ int sNet[128];
    __shared__ int sClu[128];
    const int t = threadIdx.x, lane = t & 63, w = t >> 6;
    const int b = blockIdx.y;
    const size_t bN = (size_t)b * N_;
    bf16x8 wfG[4], wfO1[8], wfO2[4];
    loadWF(WPK + PK_W3 + 16384 + w * 2048, lane, wfG);
    loadWF(WPK + PK_WO1 + w * 4096, lane, wfO1);
    loadWF(WPK + PK_WO2 + w * 2048, lane, wfO2);
    if (t < 128) sNet[t] = 0;
    const u16* cfb = cf2b + (size_t)b * 4096;
    __syncthreads();
    for (int s = 0; s < 4; ++s) {
        const int n0 = (blockIdx.x * 4 + s) * 128;
        if (t < 128) sClu[t] = clu_g[bN + n0 + t];
        const u16* gB = gFp + ((size_t)b * 2048 + (size_t)(blockIdx.x * 4 + s) * 8) * 2048;
        // P1: w3[1] 128->128 from global fragments (-> sA)
        convG128w(wfG, BIAS + OB3 + 128, gB, sA);
        __syncthreads();
        // P2: wo1 concat 256->128 (-> sB)
        convCatG128ow(wfO1, BIAS + OBO1, sA, cfb, sClu, sB);
        __syncthreads();
        // P3: wo2 128->128 + per-channel max (register-max over p-tiles first)
        convNet128w(wfO2, BIAS + OBO2, sB, sNet);
        __syncthreads();
    }
    if (t < 128) atomicMax(&gNet[b * 128 + t], sNet[t]);
}

// ---------- tiny MLP head (dual-mode output) ----------
__global__ __launch_bounds__(256)
void kD(const int* __restrict__ gNet, const u16* __restrict__ DWC,
        const float* __restrict__ BIAS, void* __restrict__ outv,
        const int* __restrict__ modep) {
    __shared__ float sN[1024];
    __shared__ float sD1[2048];
    __shared__ float sD2[2048];
    const int mode = *modep;
    const int t = threadIdx.x;
    for (int i = t; i < 1024; i += 256) sN[i] = __int_as_float(gNet[i]);
    __syncthreads();
    for (int i = t; i < 2048; i += 256) {
        int bb = i >> 8, o = i & 255;
        float s = BIAS[ODB1 + o];
        for (int k = 0; k < 128; ++k)
            s = fmaf(sN[bb * 128 + k], b2f(DWC[ODW1 + k * 256 + o]), s);
        sD1[i] = (s >= 0.f) ? s : 0.2f * s;
    }
    __syncthreads();
    for (int i = t; i < 2048; i += 256) {
        int bb = i >> 8, o = i & 255;
        float s = BIAS[ODB2 + o];
        for (int k = 0; k < 256; ++k)
            s = fmaf(sD1[bb * 256 + k], b2f(DWC[ODW2 + k * 256 + o]), s);
        sD2[i] = (s >= 0.f) ? s : 0.2f * s;
    }
    __syncthreads();
    for (int i = t; i < 320; i += 256) {
        int bb = i / 40, o = i - bb * 40;
        float s = BIAS[ODB3 + o];
        for (int k = 0; k < 256; ++k)
            s = fmaf(sD2[bb * 256 + k], b2f(DWC[ODW3 + k * 40 + o]), s);
        if (mode) ((float*)outv)[i] = s;
        else      ((u16*)outv)[i]   = f2b(s);
    }
}

extern "C" void kernel_launch(void* const* d_in, const int* in_sizes, int n_in,
                              void* d_out, int out_size, void* d_ws, size_t ws_size,
                              hipStream_t stream) {
    const void* feat = d_in[0];
    const int* clus = (const int*)d_in[1];

    char* ws = (char*)d_ws;
    u16*   WPK   = (u16*)(ws + OFS_WPK);
    float* BIAS  = (float*)(ws + OFS_BIAS);
    u16*   DWC   = (u16*)(ws + OFS_DWC);
    int*   modep = (int*)(ws + OFS_MODE);
    u16*   FEATC = (u16*)(ws + OFS_FEATC);
    int*   seg0  = (int*)(ws + OFS_GACC0);
    int*   seg1  = (int*)(ws + OFS_GACC1);
    int*   gNet  = (int*)(ws + OFS_GNET);
    u16*   cf2b0 = (u16*)(ws + OFS_CF2B0);
    u16*   cf2b1 = (u16*)(ws + OFS_CF2B1);
    u16*   f0    = (u16*)(ws + OFS_F0);
    u16*   f1    = (u16*)(ws + OFS_F1);

    hipMemsetAsync(ws + OFS_GACC0, 0, GACC_ZERO_BYTES, stream);
    hipLaunchKernelGGL(kSniff, dim3(1), dim3(256), 0, stream, (const u16*)feat, modep);
    hipLaunchKernelGGL(kPrep, dim3(256), dim3(256), 0, stream,
                       feat, d_in[2], d_in[3], d_in[4], d_in[5], d_in[6], d_in[7],
                       d_in[8], d_in[9], d_in[10], d_in[11], d_in[12], d_in[13],
                       d_in[14], d_in[15], d_in[16], d_in[17], d_in[18], d_in[19],
                       d_in[20], d_in[21], d_in[22], d_in[23], d_in[24], d_in[25],
                       WPK, BIAS, DWC, FEATC, modep);

    const int* clu0 = clus;
    const int* clu1 = clus + (size_t)B_ * N_;

    hipLaunchKernelGGL(kA0a, dim3(32, 8), dim3(512), 0, stream,
                       FEATC, clu0, WPK, BIAS, f0, seg0);
    hipLaunchKernelGGL(kA0b, dim3(32, 8), dim3(512), 0, stream,
                       f0, clu0, WPK, BIAS, seg0);
    hipLaunchKernelGGL(kB, dim3(8), dim3(256), 0, stream, seg0, cf2b0);
    hipLaunchKernelGGL(kA1a, dim3(32, 8), dim3(512), 0, stream,
                       f0, clu0, clu1, cf2b0, WPK, BIAS, f1, seg1);
    hipLaunchKernelGGL(kA1b, dim3(32, 8), dim3(512), 0, stream,
                       f1, clu1, WPK, BIAS, seg1);
    hipLaunchKernelGGL(kB, dim3(8), dim3(256), 0, stream, seg1, cf2b1);
    hipLaunchKernelGGL(kC, dim3(64, 8), dim3(512), 0, stream,
                       f1, clu1, cf2b1, WPK, BIAS, gNet);
    hipLaunchKernelGGL(kD, dim3(1), dim3(256), 0, stream,
                       gNet, DWC, BIAS, d_out, modep);
}

// Round 16
// 537.950 us; speedup vs baseline: 1.3613x; 1.1184x over previous
//
#include <hip/hip_runtime.h>
#include <stdint.h>

// Problem constants
#define B_   8
#define N_   32768
#define C_   32
#define K_   22
#define CAT_ 40

typedef unsigned short u16;
typedef unsigned int   u32;

typedef __attribute__((ext_vector_type(8))) short bf16x8;
typedef __attribute__((ext_vector_type(4))) float f32x4;

#define MFMA(a, b, c) __builtin_amdgcn_mfma_f32_16x16x32_bf16(a, b, c, 0, 0, 0)

// ---------- bf16 helpers (raw bits) ----------
__device__ __forceinline__ float b2f(u16 v) { return __uint_as_float(((u32)v) << 16); }
__device__ __forceinline__ u16 f2b(float f) {
    u32 x = __float_as_uint(f);
    return (u16)((x + 0x7fffu + ((x >> 16) & 1u)) >> 16);   // RNE
}
__device__ __forceinline__ u32 pk2(float a, float b) {
    return (u32)f2b(a) | ((u32)f2b(b) << 16);
}

// ---------- packed MFMA A-fragment weight offsets (u16 units) ----------
#define PK_WIN 0         // 256x32(pad), KB=1 : 8192
#define PK_W1  8192      // 2 x 64x256, KB=8  : 16384 each
#define PK_W2  40960     // 2 x 128x64, KB=2  : 8192 each
#define PK_W3  57344     // 2 x 128x128, KB=4 : 16384 each
#define PK_WC1 90112     // 2 x 128x128       : 16384 each
#define PK_WC2 122880    // 2 x 256x128, KB=4 : 32768 each
#define PK_WC3 188416    // 2 x 32x256, KB=8  : 8192 each
#define PK_WO1 204800    // 128x256, KB=8     : 32768
#define PK_WO2 237568    // 128x128, KB=4     : 16384

// ---------- fp32 bias block offsets (floats) ----------
#define OBIN 0
#define OB1  256
#define OB2  384
#define OB3  640
#define OBC1 896
#define OBC2 1152
#define OBC3 1664
#define OBO1 1728
#define OBO2 1856
#define ODB1 1984
#define ODB2 2240
#define ODB3 2496

// ---------- canonical bf16 dense-head weights (u16 offsets) ----------
#define ODW1 0
#define ODW2 32768
#define ODW3 98304

// ---------- workspace byte offsets ----------
#define OFS_WPK   0u
#define OFS_BIAS  524288u
#define OFS_DWC   540672u
#define OFS_MODE  786432u
#define OFS_FEATC 1048576u
#define OFS_GACC0 12582912u
#define OFS_GACC1 12746752u
#define OFS_GNET  12910592u
#define GACC_ZERO_BYTES 331776u
#define OFS_CF2B0 12914688u
#define OFS_CF2B1 12980224u
#define OFS_F0    16777216u     // fragment-major f: [b][nt(2048 of 16 pts)][kb(4)][lane(64)][8] bf16
#define OFS_F1    83886080u

// sSeg LDS layout: stride 161 dwords (160%32==0 caused 16-way bank conflicts on
// every seg-max atomic — round-6 lesson). bank=(cl*161+co)%32=(cl+co)%32.
#define SEGSTR 161
#define SEGTOT (32 * SEGSTR)
// cf2b LDS staging stride: 136 u16 (cluster base -> 8 bank groups, 16B aligned).
#define CFSTR 136

// ---------- dtype sniffer ----------
__global__ void kSniff(const u16* __restrict__ featAny, int* __restrict__ mode) {
    __shared__ int cnt;
    if (threadIdx.x == 0) cnt = 0;
    __syncthreads();
    int weird = 0;
    for (int j = 0; j < 4; ++j) {
        u16 v = featAny[threadIdx.x * 4 + j];
        float f = b2f(v);
        if (v == 0 || !(fabsf(f) < 1e10f)) weird++;
    }
    if (weird) atomicAdd(&cnt, weird);
    __syncthreads();
    if (threadIdx.x == 0) *mode = (cnt > 64) ? 1 : 0;
}

__device__ __forceinline__ float fetchF(const void* src, size_t i, int mode) {
    return mode ? ((const float*)src)[i] : b2f(((const u16*)src)[i]);
}

// ---------- weight pack: (COUT,CIN) -> MFMA A-fragment bf16 order ----------
__device__ void packA(const void* __restrict__ src, u16* __restrict__ dst,
                      int COUT, int CIN, int mode, int tid, int np) {
    int KB = (CIN + 31) / 32;
    int tiles = COUT / 16;
    int tot = tiles * KB * 64 * 8;
    for (int i = tid; i < tot; i += np) {
        int j = i & 7;
        int L = (i >> 3) & 63;
        int rest = i >> 9;
        int kb = rest % KB, tile = rest / KB;
        int co = tile * 16 + (L & 15);
        int ci = kb * 32 + (L >> 4) * 8 + j;
        float v = (ci < CIN) ? fetchF(src, (size_t)co * CIN + ci, mode) : 0.f;
        dst[i] = f2b(v);
    }
}

__device__ void cvtF(const void* __restrict__ src, float* __restrict__ dst,
                     int n, int mode, int tid, int np) {
    for (int i = tid; i < n; i += np) dst[i] = fetchF(src, i, mode);
}

__device__ void cvtB(const void* __restrict__ src, u16* __restrict__ dst,
                     int n, int mode, int tid, int np) {
    for (int i = tid; i < n; i += np)
        dst[i] = mode ? f2b(((const float*)src)[i]) : ((const u16*)src)[i];
}

__global__ void kPrep(const void* feat, const void* w_in, const void* b_in,
                      const void* w1, const void* b1, const void* w2, const void* b2,
                      const void* w3, const void* b3,
                      const void* wc1, const void* bc1, const void* wc2, const void* bc2,
                      const void* wc3, const void* bc3,
                      const void* wo1, const void* bo1, const void* wo2, const void* bo2,
                      const void* dw1, const void* db1, const void* dw2, const void* db2,
                      const void* dw3, const void* db3,
                      u16* WPK, float* BIAS, u16* DWC, u16* FEATC,
                      const int* __restrict__ modep) {
    const int mode = *modep;
    int tid = blockIdx.x * blockDim.x + threadIdx.x;
    int np  = gridDim.x * blockDim.x;
    cvtB(feat, FEATC, B_ * N_ * K_, mode, tid, np);
    packA(w_in, WPK + PK_WIN, 256, 22, mode, tid, np);
    packA(w1,                                 WPK + PK_W1,          64, 256, mode, tid, np);
    packA((const u16*)w1 + (mode?32768:16384), WPK + PK_W1 + 16384,  64, 256, mode, tid, np);
    packA(w2,                                 WPK + PK_W2,          128, 64, mode, tid, np);
    packA((const u16*)w2 + (mode?16384:8192),  WPK + PK_W2 + 8192,   128, 64, mode, tid, np);
    packA(w3,                                 WPK + PK_W3,          128, 128, mode, tid, np);
    packA((const u16*)w3 + (mode?32768:16384), WPK + PK_W3 + 16384,  128, 128, mode, tid, np);
    packA(wc1,                                WPK + PK_WC1,         128, 128, mode, tid, np);
    packA((const u16*)wc1 + (mode?32768:16384),WPK + PK_WC1 + 16384, 128, 128, mode, tid, np);
    packA(wc2,                                WPK + PK_WC2,         256, 128, mode, tid, np);
    packA((const u16*)wc2 + (mode?65536:32768),WPK + PK_WC2 + 32768, 256, 128, mode, tid, np);
    packA(wc3,                                WPK + PK_WC3,         32, 256, mode, tid, np);
    packA((const u16*)wc3 + (mode?16384:8192), WPK + PK_WC3 + 8192,  32, 256, mode, tid, np);
    packA(wo1, WPK + PK_WO1, 128, 256, mode, tid, np);
    packA(wo2, WPK + PK_WO2, 128, 128, mode, tid, np);
    cvtF(b_in, BIAS + OBIN, 256, mode, tid, np);
    cvtF(b1,   BIAS + OB1,  128, mode, tid, np);
    cvtF(b2,   BIAS + OB2,  256, mode, tid, np);
    cvtF(b3,   BIAS + OB3,  256, mode, tid, np);
    cvtF(bc1,  BIAS + OBC1, 256, mode, tid, np);
    cvtF(bc2,  BIAS + OBC2, 512, mode, tid, np);
    cvtF(bc3,  BIAS + OBC3, 64,  mode, tid, np);
    cvtF(bo1,  BIAS + OBO1, 128, mode, tid, np);
    cvtF(bo2,  BIAS + OBO2, 128, mode, tid, np);
    cvtF(db1,  BIAS + ODB1, 256, mode, tid, np);
    cvtF(db2,  BIAS + ODB2, 256, mode, tid, np);
    cvtF(db3,  BIAS + ODB3, 40,  mode, tid, np);
    cvtB(dw1, DWC + ODW1, 128 * 256, mode, tid, np);
    cvtB(dw2, DWC + ODW2, 256 * 256, mode, tid, np);
    cvtB(dw3, DWC + ODW3, 256 * 40,  mode, tid, np);
}

__device__ __forceinline__ void storeRow(u16* __restrict__ buf, int p, int col,
                                         float r0, float r1, float r2, float r3) {
    *(uint2*)(buf + p * 136 + col) = make_uint2(pk2(r0, r1), pk2(r2, r3));
}

// Load a wave's weight fragments for one phase into registers.
template<int NF>
__device__ __forceinline__ void loadWF(const u16* __restrict__ wA, int lane, bf16x8 (&wf)[NF]) {
#pragma unroll
    for (int i = 0; i < NF; ++i)
        wf[i] = *(const bf16x8*)(wA + ((size_t)(i * 64 + lane)) * 8);
}

// ================= 8-wave / 128-pt building blocks (R12-verified) ==========
template<int KB, int INS>
__device__ __forceinline__ void convP128w(const bf16x8 (&wf)[KB], const float* __restrict__ bias,
                                          const u16* __restrict__ sIn, u16* __restrict__ sOut) {
    const int t = threadIdx.x, lane = t & 63, w = t >> 6, lp = lane & 15, q = lane >> 4;
    f32x4 acc[8] = {};
#pragma unroll
    for (int kb = 0; kb < KB; ++kb) {
        bf16x8 bb[8];
#pragma unroll
        for (int pt = 0; pt < 8; ++pt)
            bb[pt] = *(const bf16x8*)(sIn + (pt * 16 + lp) * INS + kb * 32 + q * 8);
#pragma unroll
        for (int pt = 0; pt < 8; ++pt) acc[pt] = MFMA(wf[kb], bb[pt], acc[pt]);
    }
    const int co = w * 16 + q * 4;
    f32x4 bv = *(const f32x4*)(bias + co);
#pragma unroll
    for (int pt = 0; pt < 8; ++pt) {
        f32x4 v = acc[pt];
        storeRow(sOut, pt * 16 + lp, co,
                 fmaxf(v[0] + bv[0], 0.f), fmaxf(v[1] + bv[1], 0.f),
                 fmaxf(v[2] + bv[2], 0.f), fmaxf(v[3] + bv[3], 0.f));
    }
}

// w2 64->128 fused: LDS store + f32 seg-max atomics from registers.
__device__ __forceinline__ void convW2_128w(const bf16x8 (&wf)[2], const float* __restrict__ bias,
                                            const u16* __restrict__ sIn, u16* __restrict__ sOut,
                                            const int* __restrict__ sCluSeg, int* __restrict__ sSeg) {
    const int t = threadIdx.x, lane = t & 63, w = t >> 6, lp = lane & 15, q = lane >> 4;
    f32x4 acc[8] = {};
#pragma unroll
    for (int kb = 0; kb < 2; ++kb) {
        bf16x8 bb[8];
#pragma unroll
        for (int pt = 0; pt < 8; ++pt)
            bb[pt] = *(const bf16x8*)(sIn + (pt * 16 + lp) * 136 + kb * 32 + q * 8);
#pragma unroll
        for (int pt = 0; pt < 8; ++pt) acc[pt] = MFMA(wf[kb], bb[pt], acc[pt]);
    }
    const int co = w * 16 + q * 4;
    f32x4 bv = *(const f32x4*)(bias + co);
#pragma unroll
    for (int pt = 0; pt < 8; ++pt) {
        f32x4 v = acc[pt];
        const int p = pt * 16 + lp;
        float r0 = fmaxf(v[0] + bv[0], 0.f), r1 = fmaxf(v[1] + bv[1], 0.f);
        float r2 = fmaxf(v[2] + bv[2], 0.f), r3 = fmaxf(v[3] + bv[3], 0.f);
        *(uint2*)(sOut + p * 136 + co) = make_uint2(pk2(r0, r1), pk2(r2, r3));
        const int sb = sCluSeg[p] * SEGSTR + co;
        atomicMax(&sSeg[sb + 0], __float_as_int(r0));
        atomicMax(&sSeg[sb + 1], __float_as_int(r1));
        atomicMax(&sSeg[sb + 2], __float_as_int(r2));
        atomicMax(&sSeg[sb + 3], __float_as_int(r3));
    }
}

// w1 256->64 concat (both halves in LDS): co-tile (w&3), p-group (w>>2)*4.
__device__ __forceinline__ void convCat128w(const bf16x8 (&wf)[8], const float* __restrict__ bias,
                                            const u16* __restrict__ sLo, const u16* __restrict__ sHi,
                                            u16* __restrict__ sOut) {
    const int t = threadIdx.x, lane = t & 63, w = t >> 6, lp = lane & 15, q = lane >> 4;
    const int ct = w & 3, pp = (w >> 2) * 4;
    f32x4 acc[4] = {};
#pragma unroll
    for (int kb = 0; kb < 8; ++kb) {
        const u16* sIn = (kb < 4) ? sLo : sHi;
        const int col = (kb & 3) * 32 + q * 8;
        bf16x8 bb[4];
#pragma unroll
        for (int i = 0; i < 4; ++i)
            bb[i] = *(const bf16x8*)(sIn + ((pp + i) * 16 + lp) * 136 + col);
#pragma unroll
        for (int i = 0; i < 4; ++i) acc[i] = MFMA(wf[kb], bb[i], acc[i]);
    }
    const int co = ct * 16 + q * 4;
    f32x4 bv = *(const f32x4*)(bias + co);
#pragma unroll
    for (int i = 0; i < 4; ++i) {
        f32x4 v = acc[i];
        storeRow(sOut, (pp + i) * 16 + lp, co,
                 fmaxf(v[0] + bv[0], 0.f), fmaxf(v[1] + bv[1], 0.f),
                 fmaxf(v[2] + bv[2], 0.f), fmaxf(v[3] + bv[3], 0.f));
    }
}

// w1 256->64 concat, upper half gathered per-lane from LDS-staged cf2b (stride 136).
__device__ __forceinline__ void convCatG128s(const bf16x8 (&wf)[8], const float* __restrict__ bias,
                                             const u16* __restrict__ sIn, const u16* __restrict__ sCf,
                                             const int* __restrict__ sClu, u16* __restrict__ sOut) {
    const int t = threadIdx.x, lane = t & 63, w = t >> 6, lp = lane & 15, q = lane >> 4;
    const int ct = w & 3, pp = (w >> 2) * 4;
    f32x4 acc[4] = {};
#pragma unroll
    for (int kb = 0; kb < 8; ++kb) {
        bf16x8 bb[4];
#pragma unroll
        for (int i = 0; i < 4; ++i) {
            const int p = (pp + i) * 16 + lp;
            if (kb < 4) bb[i] = *(const bf16x8*)(sIn + p * 136 + kb * 32 + q * 8);
            else        bb[i] = *(const bf16x8*)(sCf + sClu[p] * CFSTR + (kb - 4) * 32 + q * 8);
        }
#pragma unroll
        for (int i = 0; i < 4; ++i) acc[i] = MFMA(wf[kb], bb[i], acc[i]);
    }
    const int co = ct * 16 + q * 4;
    f32x4 bv = *(const f32x4*)(bias + co);
#pragma unroll
    for (int i = 0; i < 4; ++i) {
        f32x4 v = acc[i];
        storeRow(sOut, (pp + i) * 16 + lp, co,
                 fmaxf(v[0] + bv[0], 0.f), fmaxf(v[1] + bv[1], 0.f),
                 fmaxf(v[2] + bv[2], 0.f), fmaxf(v[3] + bv[3], 0.f));
    }
}

// CIN=128 conv, B direct from global fragment-major f (128-pt group).
__device__ __forceinline__ void convG128w(const bf16x8 (&wf)[4], const float* __restrict__ bias,
                                          const u16* __restrict__ gB, u16* __restrict__ sOut) {
    const int t = threadIdx.x, lane = t & 63, w = t >> 6, lp = lane & 15, q = lane >> 4;
    f32x4 acc[8] = {};
#pragma unroll
    for (int kb = 0; kb < 4; ++kb) {
        bf16x8 bb[8];
#pragma unroll
        for (int pt = 0; pt < 8; ++pt)
            bb[pt] = *(const bf16x8*)(gB + pt * 2048 + kb * 512 + lane * 8);
#pragma unroll
        for (int pt = 0; pt < 8; ++pt) acc[pt] = MFMA(wf[kb], bb[pt], acc[pt]);
    }
    const int co = w * 16 + q * 4;
    f32x4 bv = *(const f32x4*)(bias + co);
#pragma unroll
    for (int pt = 0; pt < 8; ++pt) {
        f32x4 v = acc[pt];
        storeRow(sOut, pt * 16 + lp, co,
                 fmaxf(v[0] + bv[0], 0.f), fmaxf(v[1] + bv[1], 0.f),
                 fmaxf(v[2] + bv[2], 0.f), fmaxf(v[3] + bv[3], 0.f));
    }
}

// wc3 (32x256) + corr seg-max: co-tile (w&1), p-pair (w>>1)*2.
__device__ __forceinline__ void wc3seg128w(const bf16x8 (&wf)[8], const float* __restrict__ bias,
                                           const u16* __restrict__ sLo, const u16* __restrict__ sHi,
                                           const int* __restrict__ sClu, int* __restrict__ sSeg) {
    const int t = threadIdx.x, lane = t & 63, w = t >> 6, lp = lane & 15, q = lane >> 4;
    const int ct = w & 1, pp = (w >> 1) * 2;
    f32x4 acc[2] = {};
#pragma unroll
    for (int kb = 0; kb < 8; ++kb) {
        const u16* sIn = (kb < 4) ? sLo : sHi;
        const int col = (kb & 3) * 32 + q * 8;
        bf16x8 b0 = *(const bf16x8*)(sIn + ((pp + 0) * 16 + lp) * 136 + col);
        bf16x8 b1 = *(const bf16x8*)(sIn + ((pp + 1) * 16 + lp) * 136 + col);
        acc[0] = MFMA(wf[kb], b0, acc[0]);
        acc[1] = MFMA(wf[kb], b1, acc[1]);
    }
    const int col = ct * 16 + q * 4;
    f32x4 bv = *(const f32x4*)(bias + col);
#pragma unroll
    for (int i = 0; i < 2; ++i) {
        const int p = (pp + i) * 16 + lp;
        const int cl = sClu[p];
        f32x4 v = acc[i];
        atomicMax(&sSeg[cl * SEGSTR + 128 + col + 0], __float_as_int(fmaxf(v[0] + bv[0], 0.f)));
        atomicMax(&sSeg[cl * SEGSTR + 128 + col + 1], __float_as_int(fmaxf(v[1] + bv[1], 0.f)));
        atomicMax(&sSeg[cl * SEGSTR + 128 + col + 2], __float_as_int(fmaxf(v[2] + bv[2], 0.f)));
        atomicMax(&sSeg[cl * SEGSTR + 128 + col + 3], __float_as_int(fmaxf(v[3] + bv[3], 0.f)));
    }
}

// ---------- kC building blocks ----------
// wo1 256->128 concat: wave w -> co-tile w, 8 p-tiles; kb<4 from sIn, kb>=4 LDS-staged cf2b.
__device__ __forceinline__ void convCatG128os(const bf16x8 (&wf)[8], const float* __restrict__ bias,
                                              const u16* __restrict__ sIn, const u16* __restrict__ sCf,
                                              const int* __restrict__ sClu, u16* __restrict__ sOut) {
    const int t = threadIdx.x, lane = t & 63, w = t >> 6, lp = lane & 15, q = lane >> 4;
    f32x4 acc[8] = {};
#pragma unroll
    for (int kb = 0; kb < 8; ++kb) {
        bf16x8 bb[8];
#pragma unroll
        for (int pt = 0; pt < 8; ++pt) {
            const int p = pt * 16 + lp;
            if (kb < 4) bb[pt] = *(const bf16x8*)(sIn + p * 136 + kb * 32 + q * 8);
            else        bb[pt] = *(const bf16x8*)(sCf + sClu[p] * CFSTR + (kb - 4) * 32 + q * 8);
        }
#pragma unroll
        for (int pt = 0; pt < 8; ++pt) acc[pt] = MFMA(wf[kb], bb[pt], acc[pt]);
    }
    const int co = w * 16 + q * 4;
    f32x4 bv = *(const f32x4*)(bias + co);
#pragma unroll
    for (int pt = 0; pt < 8; ++pt) {
        f32x4 v = acc[pt];
        storeRow(sOut, pt * 16 + lp, co,
                 fmaxf(v[0] + bv[0], 0.f), fmaxf(v[1] + bv[1], 0.f),
                 fmaxf(v[2] + bv[2], 0.f), fmaxf(v[3] + bv[3], 0.f));
    }
}

// wo2 128->128 + per-channel max: register-max over 8 p-tiles FIRST, then one
// atomicMax per lane-channel.
__device__ __forceinline__ void convNet128w(const bf16x8 (&wf)[4], const float* __restrict__ bias,
                                            const u16* __restrict__ sIn, int* __restrict__ sNet) {
    const int t = threadIdx.x, lane = t & 63, w = t >> 6, lp = lane & 15, q = lane >> 4;
    f32x4 acc[8] = {};
#pragma unroll
    for (int kb = 0; kb < 4; ++kb) {
        bf16x8 bb[8];
#pragma unroll
        for (int pt = 0; pt < 8; ++pt)
            bb[pt] = *(const bf16x8*)(sIn + (pt * 16 + lp) * 136 + kb * 32 + q * 8);
#pragma unroll
        for (int pt = 0; pt < 8; ++pt) acc[pt] = MFMA(wf[kb], bb[pt], acc[pt]);
    }
    const int co = w * 16 + q * 4;
    f32x4 bv = *(const f32x4*)(bias + co);
    f32x4 m = acc[0];
#pragma unroll
    for (int pt = 1; pt < 8; ++pt) {
        m[0] = fmaxf(m[0], acc[pt][0]); m[1] = fmaxf(m[1], acc[pt][1]);
        m[2] = fmaxf(m[2], acc[pt][2]); m[3] = fmaxf(m[3], acc[pt][3]);
    }
    atomicMax(&sNet[co + 0], __float_as_int(fmaxf(m[0] + bv[0], 0.f)));
    atomicMax(&sNet[co + 1], __float_as_int(fmaxf(m[1] + bv[1], 0.f)));
    atomicMax(&sNet[co + 2], __float_as_int(fmaxf(m[2] + bv[2], 0.f)));
    atomicMax(&sNet[co + 3], __float_as_int(fmaxf(m[3] + bv[3], 0.f)));
}

// ---------- iteration-0, part A: w_in -> w1 -> w2 (+f seg, gF store) ----------
__global__ __launch_bounds__(512, 2)
void kA0a(const u16* __restrict__ featc, const int* __restrict__ clu0,
          const u16* __restrict__ WPK, const float* __restrict__ BIAS,
          u16* __restrict__ gF, int* __restrict__ gSeg) {
    __shared__ __attribute__((aligned(16))) u16 sA[128 * 136];
    __shared__ __attribute__((aligned(16))) u16 sB[128 * 136];
    __shared__ __attribute__((aligned(16))) u16 sC[128 * 136];
    __shared__ __attribute__((aligned(16))) u16 sFeat[128 * 40];
    __shared__ int sSeg[SEGTOT];
    __shared__ int sClu[128];
    const int t = threadIdx.x, lane = t & 63, w = t >> 6, lp = lane & 15, q = lane >> 4;
    const int b = blockIdx.y;
    const size_t bN = (size_t)b * N_;
    bf16x8 wf1a[1], wf1b[1], wf2[8], wf3[2];
    loadWF(WPK + PK_WIN + w * 512, lane, wf1a);
    loadWF(WPK + PK_WIN + 4096 + w * 512, lane, wf1b);
    loadWF(WPK + PK_W1 + (w & 3) * 4096, lane, wf2);
    loadWF(WPK + PK_W2 + w * 1024, lane, wf3);
    for (int i = t; i < SEGTOT; i += 512) sSeg[i] = 0;
    {
        const int n0 = blockIdx.x * 1024;
        for (int i = t; i < 5120; i += 512) {
            int p = i / 40, k = i - p * 40;
            sFeat[i] = (k < 22) ? featc[(bN + n0 + p) * 22 + k] : (u16)0;
        }
    }
    __syncthreads();
    for (int s = 0; s < 8; ++s) {
        const int n0 = (blockIdx.x * 8 + s) * 128;
        const size_t ntB = (size_t)b * 2048 + (size_t)(blockIdx.x * 8 + s) * 8;
        if (t < 128) sClu[t] = clu0[bN + n0 + t];
        convP128w<1, 40>(wf1a, BIAS + OBIN,       sFeat, sA);
        convP128w<1, 40>(wf1b, BIAS + OBIN + 128, sFeat, sB);
        __syncthreads();
        convCat128w(wf2, BIAS + OB1, sA, sB, sC);
        __syncthreads();
        convW2_128w(wf3, BIAS + OB2, sC, sA, sClu, sSeg);
        __syncthreads();
        {
#pragma unroll
            for (int r = 0; r < 4; ++r) {
                bf16x8 v = *(const bf16x8*)(sA + (w * 16 + lp) * 136 + r * 32 + q * 8);
                *(bf16x8*)(gF + ((ntB + w) * 4 + r) * 512 + lane * 8) = v;
            }
        }
        if (s < 7) {
            const int n1 = n0 + 128;
            for (int i = t; i < 5120; i += 512) {
                int p = i / 40, k = i - p * 40;
                sFeat[i] = (k < 22) ? featc[(bN + n1 + p) * 22 + k] : (u16)0;
            }
        }
        __syncthreads();
    }
    for (int i = t; i < 4096; i += 512) {
        int cl = i >> 7, ch = i & 127;
        atomicMax(&gSeg[b * 5120 + cl * 160 + ch], sSeg[cl * SEGSTR + ch]);
    }
}

// ---------- part B: wc1 -> wc2 -> wc3 (+corr seg). f consumed from global fragments ----------
template<int PKOFF, int BOFF>
__device__ __forceinline__ void kAbBody(const u16* __restrict__ gFp, const int* __restrict__ clu,
                                        const u16* __restrict__ WPK, const float* __restrict__ BIAS,
                                        int* __restrict__ gSeg) {
    __shared__ __attribute__((aligned(16))) u16 sA[128 * 136];
    __shared__ __attribute__((aligned(16))) u16 sB[128 * 136];
    __shared__ __attribute__((aligned(16))) u16 sC[128 * 136];
    __shared__ int sSeg[SEGTOT];
    __shared__ int sClu[128];
    const int t = threadIdx.x, lane = t & 63, w = t >> 6;
    const int b = blockIdx.y;
    const size_t bN = (size_t)b * N_;
    bf16x8 wf4[4], wf5a[4], wf5b[4], wf6[8];
    loadWF(WPK + PK_WC1 + PKOFF * 16384 + w * 2048, lane, wf4);
    loadWF(WPK + PK_WC2 + PKOFF * 32768 + w * 2048, lane, wf5a);
    loadWF(WPK + PK_WC2 + PKOFF * 32768 + 16384 + w * 2048, lane, wf5b);
    loadWF(WPK + PK_WC3 + PKOFF * 8192 + (w & 1) * 4096, lane, wf6);
    for (int i = t; i < SEGTOT; i += 512) sSeg[i] = 0;
    __syncthreads();
    for (int s = 0; s < 8; ++s) {
        const int n0 = (blockIdx.x * 8 + s) * 128;
        const size_t ntB = (size_t)b * 2048 + (size_t)(blockIdx.x * 8 + s) * 8;
        if (t < 128) sClu[t] = clu[bN + n0 + t];
        const u16* gB = gFp + ntB * 2048;
        convG128w(wf4, BIAS + OBC1 + BOFF * 128, gB, sA);
        __syncthreads();
        convP128w<4, 136>(wf5a, BIAS + OBC2 + BOFF * 256,       sA, sB);
        convP128w<4, 136>(wf5b, BIAS + OBC2 + BOFF * 256 + 128, sA, sC);
        __syncthreads();
        wc3seg128w(wf6, BIAS + OBC3 + BOFF * 32, sB, sC, sClu, sSeg);
        __syncthreads();
    }
    for (int i = t; i < 1024; i += 512) {
        int cl = i >> 5, ch = i & 31;
        atomicMax(&gSeg[b * 5120 + cl * 160 + 128 + ch], sSeg[cl * SEGSTR + 128 + ch]);
    }
}

__global__ __launch_bounds__(512, 2)
void kA0b(const u16* __restrict__ gFp, const int* __restrict__ clu0,
          const u16* __restrict__ WPK, const float* __restrict__ BIAS,
          int* __restrict__ gSeg) {
    kAbBody<0, 0>(gFp, clu0, WPK, BIAS, gSeg);
}

__global__ __launch_bounds__(512, 2)
void kA1b(const u16* __restrict__ gFp, const int* __restrict__ clu1,
          const u16* __restrict__ WPK, const float* __restrict__ BIAS,
          int* __restrict__ gSeg) {
    kAbBody<1, 1>(gFp, clu1, WPK, BIAS, gSeg);
}

// ---------- per-batch cluster math -> bf16 cf2b ----------
__global__ __launch_bounds__(256)
void kB(const int* __restrict__ gSeg, u16* __restrict__ cf2b) {
    __shared__ float sA[5120];
    __shared__ float sR[1024];
    __shared__ float sI[32];
    const int t = threadIdx.x, b = blockIdx.x;
    for (int i = t; i < 5120; i += 256) sA[i] = __int_as_float(gSeg[b * 5120 + i]);
    __syncthreads();
    if (t < 32) {
        float s = 0.f;
        for (int j = 0; j < 32; ++j) { float v = sA[t * 160 + 128 + j]; s = fmaf(v, v, s); }
        sI[t] = 1.f / fmaxf(sqrtf(s), 1e-12f);
    }
    __syncthreads();
    for (int i = t; i < 1024; i += 256) {
        int ca = i >> 5, cb = i & 31;
        float s = 0.f;
        for (int j = 0; j < 32; ++j)
            s = fmaf(sA[ca * 160 + 128 + j], sA[cb * 160 + 128 + j], s);
        sR[i] = s * sI[ca] * sI[cb];
    }
    __syncthreads();
    for (int i = t; i < 4096; i += 256) {
        int c = i >> 7, ch = i & 127;
        float s = 0.f;
        for (int cp = 0; cp < 32; ++cp)
            s = fmaf(sA[cp * 160 + ch], sR[cp * 32 + c], s);
        cf2b[((size_t)b * 32 + c) * 128 + ch] = f2b(s);
    }
}

// ---------- iteration-1, part A: w3 -> w1concat -> w2 (+f seg, gFo store) ----------
// cf2b staged in LDS (R16: kills the per-lane divergent global gather in P2).
__global__ __launch_bounds__(512, 2)
void kA1a(const u16* __restrict__ gFp, const int* __restrict__ clu_g,
          const int* __restrict__ clu_s, const u16* __restrict__ cf2b,
          const u16* __restrict__ WPK, const float* __restrict__ BIAS,
          u16* __restrict__ gFo, int* __restrict__ gSeg) {
    __shared__ __attribute__((aligned(16))) u16 sA[128 * 136];
    __shared__ __attribute__((aligned(16))) u16 sB[128 * 136];
    __shared__ __attribute__((aligned(16))) u16 sC[128 * 136];
    __shared__ __attribute__((aligned(16))) u16 sCf[32 * CFSTR];
    __shared__ int sSeg[SEGTOT];
    __shared__ int sClu0[128];
    __shared__ int sClu1[128];
    const int t = threadIdx.x, lane = t & 63, w = t >> 6, lp = lane & 15, q = lane >> 4;
    const int b = blockIdx.y;
    const size_t bN = (size_t)b * N_;
    bf16x8 wfG[4], wf2[8], wf3[2];
    loadWF(WPK + PK_W3 + w * 2048, lane, wfG);
    loadWF(WPK + PK_W1 + 16384 + (w & 3) * 4096, lane, wf2);
    loadWF(WPK + PK_W2 + 8192 + w * 1024, lane, wf3);
    for (int i = t; i < SEGTOT; i += 512) sSeg[i] = 0;
    const u16* cfb = cf2b + (size_t)b * 4096;
    for (int i = t; i < 4096; i += 512) {
        int cl = i >> 7, ch = i & 127;
        sCf[cl * CFSTR + ch] = cfb[i];
    }
    __syncthreads();
    for (int s = 0; s < 8; ++s) {
        const int n0 = (blockIdx.x * 8 + s) * 128;
        const size_t ntB = (size_t)b * 2048 + (size_t)(blockIdx.x * 8 + s) * 8;
        if (t < 128) sClu0[t] = clu_g[bN + n0 + t];
        else if (t < 256) sClu1[t - 128] = clu_s[bN + n0 + (t - 128)];
        const u16* gB = gFp + ntB * 2048;
        // P1: w3 128->128, B direct from global fragments (f3 -> sA)
        convG128w(wfG, BIAS + OB3, gB, sA);
        __syncthreads();
        // P2: w1 concat(w3out, LDS pool-gather) 256->64 (h -> sB)
        convCatG128s(wf2, BIAS + OB1 + 64, sA, sCf, sClu0, sB);
        __syncthreads();
        // P3: w2 64->128 fused (f -> sC + f32 seg-max from regs)
        convW2_128w(wf3, BIAS + OB2 + 128, sB, sC, sClu1, sSeg);
        __syncthreads();
        // P4: fragment-major gFo store
        {
#pragma unroll
            for (int r = 0; r < 4; ++r) {
                bf16x8 v = *(const bf16x8*)(sC + (w * 16 + lp) * 136 + r * 32 + q * 8);
                *(bf16x8*)(gFo + ((ntB + w) * 4 + r) * 512 + lane * 8) = v;
            }
        }
        __syncthreads();
    }
    for (int i = t; i < 4096; i += 512) {
        int cl = i >> 7, ch = i & 127;
        atomicMax(&gSeg[b * 5120 + cl * 160 + ch], sSeg[cl * SEGSTR + ch]);
    }
}

// ---------- final conv head: 512 thr, 128-pt subtiles, LDS-staged cf2b (R16) ----------
__global__ __launch_bounds__(512, 2)
void kC(const u16* __restrict__ gFp, const int* __restrict__ clu_g,
        const u16* __restrict__ cf2b,
        const u16* __restrict__ WPK, const float* __restrict__ BIAS,
        int* __restrict__ gNet) {
    __shared__ __attribute__((aligned(16))) u16 sA[128 * 136];
    __shared__ __attribute__((aligned(16))) u16 sB[128 * 136];
    __shared__ __attribute__((aligned(16))) u16 sCf[32 * CFSTR];
    __shared__ int sNet[128];
    __shared__ int sClu[128];
    const int t = threadIdx.x, lane = t & 63, w = t >> 6;
    const int b = blockIdx.y;
    const size_t bN = (size_t)b * N_;
    bf16x8 wfG[4], wfO1[8], wfO2[4];
    loadWF(WPK + PK_W3 + 16384 + w * 2048, lane, wfG);
    loadWF(WPK + PK_WO1 + w * 4096, lane, wfO1);
    loadWF(WPK + PK_WO2 + w * 2048, lane, wfO2);
    if (t < 128) sNet[t] = 0;
    const u16* cfb = cf2b + (size_t)b * 4096;
    for (int i = t; i < 4096; i += 512) {
        int cl = i >> 7, ch = i & 127;
        sCf[cl * CFSTR + ch] = cfb[i];
    }
    __syncthreads();
    for (int s = 0; s < 4; ++s) {
        const int n0 = (blockIdx.x * 4 + s) * 128;
        if (t < 128) sClu[t] = clu_g[bN + n0 + t];
        const u16* gB = gFp + ((size_t)b * 2048 + (size_t)(blockIdx.x * 4 + s) * 8) * 2048;
        // P1: w3[1] 128->128 from global fragments (-> sA)
        convG128w(wfG, BIAS + OB3 + 128, gB, sA);
        __syncthreads();
        // P2: wo1 concat 256->128, pool-gather from LDS (-> sB)
        convCatG128os(wfO1, BIAS + OBO1, sA, sCf, sClu, sB);
        __syncthreads();
        // P3: wo2 128->128 + per-channel max (register-max over p-tiles first)
        convNet128w(wfO2, BIAS + OBO2, sB, sNet);
        __syncthreads();
    }
    if (t < 128) atomicMax(&gNet[b * 128 + t], sNet[t]);
}

// ---------- tiny MLP head (dual-mode output) ----------
__global__ __launch_bounds__(256)
void kD(const int* __restrict__ gNet, const u16* __restrict__ DWC,
        const float* __restrict__ BIAS, void* __restrict__ outv,
        const int* __restrict__ modep) {
    __shared__ float sN[1024];
    __shared__ float sD1[2048];
    __shared__ float sD2[2048];
    const int mode = *modep;
    const int t = threadIdx.x;
    for (int i = t; i < 1024; i += 256) sN[i] = __int_as_float(gNet[i]);
    __syncthreads();
    for (int i = t; i < 2048; i += 256) {
        int bb = i >> 8, o = i & 255;
        float s = BIAS[ODB1 + o];
        for (int k = 0; k < 128; ++k)
            s = fmaf(sN[bb * 128 + k], b2f(DWC[ODW1 + k * 256 + o]), s);
        sD1[i] = (s >= 0.f) ? s : 0.2f * s;
    }
    __syncthreads();
    for (int i = t; i < 2048; i += 256) {
        int bb = i >> 8, o = i & 255;
        float s = BIAS[ODB2 + o];
        for (int k = 0; k < 256; ++k)
            s = fmaf(sD1[bb * 256 + k], b2f(DWC[ODW2 + k * 256 + o]), s);
        sD2[i] = (s >= 0.f) ? s : 0.2f * s;
    }
    __syncthreads();
    for (int i = t; i < 320; i += 256) {
        int bb = i / 40, o = i - bb * 40;
        float s = BIAS[ODB3 + o];
        for (int k = 0; k < 256; ++k)
            s = fmaf(sD2[bb * 256 + k], b2f(DWC[ODW3 + k * 40 + o]), s);
        if (mode) ((float*)outv)[i] = s;
        else      ((u16*)outv)[i]   = f2b(s);
    }
}

extern "C" void kernel_launch(void* const* d_in, const int* in_sizes, int n_in,
                              void* d_out, int out_size, void* d_ws, size_t ws_size,
                              hipStream_t stream) {
    const void* feat = d_in[0];
    const int* clus = (const int*)d_in[1];

    char* ws = (char*)d_ws;
    u16*   WPK   = (u16*)(ws + OFS_WPK);
    float* BIAS  = (float*)(ws + OFS_BIAS);
    u16*   DWC   = (u16*)(ws + OFS_DWC);
    int*   modep = (int*)(ws + OFS_MODE);
    u16*   FEATC = (u16*)(ws + OFS_FEATC);
    int*   seg0  = (int*)(ws + OFS_GACC0);
    int*   seg1  = (int*)(ws + OFS_GACC1);
    int*   gNet  = (int*)(ws + OFS_GNET);
    u16*   cf2b0 = (u16*)(ws + OFS_CF2B0);
    u16*   cf2b1 = (u16*)(ws + OFS_CF2B1);
    u16*   f0    = (u16*)(ws + OFS_F0);
    u16*   f1    = (u16*)(ws + OFS_F1);

    hipMemsetAsync(ws + OFS_GACC0, 0, GACC_ZERO_BYTES, stream);
    hipLaunchKernelGGL(kSniff, dim3(1), dim3(256), 0, stream, (const u16*)feat, modep);
    hipLaunchKernelGGL(kPrep, dim3(256), dim3(256), 0, stream,
                       feat, d_in[2], d_in[3], d_in[4], d_in[5], d_in[6], d_in[7],
                       d_in[8], d_in[9], d_in[10], d_in[11], d_in[12], d_in[13],
                       d_in[14], d_in[15], d_in[16], d_in[17], d_in[18], d_in[19],
                       d_in[20], d_in[21], d_in[22], d_in[23], d_in[24], d_in[25],
                       WPK, BIAS, DWC, FEATC, modep);

    const int* clu0 = clus;
    const int* clu1 = clus + (size_t)B_ * N_;

    hipLaunchKernelGGL(kA0a, dim3(32, 8), dim3(512), 0, stream,
                       FEATC, clu0, WPK, BIAS, f0, seg0);
    hipLaunchKernelGGL(kA0b, dim3(32, 8), dim3(512), 0, stream,
                       f0, clu0, WPK, BIAS, seg0);
    hipLaunchKernelGGL(kB, dim3(8), dim3(256), 0, stream, seg0, cf2b0);
    hipLaunchKernelGGL(kA1a, dim3(32, 8), dim3(512), 0, stream,
                       f0, clu0, clu1, cf2b0, WPK, BIAS, f1, seg1);
    hipLaunchKernelGGL(kA1b, dim3(32, 8), dim3(512), 0, stream,
                       f1, clu1, WPK, BIAS, seg1);
    hipLaunchKernelGGL(kB, dim3(8), dim3(256), 0, stream, seg1, cf2b1);
    hipLaunchKernelGGL(kC, dim3(64, 8), dim3(512), 0, stream,
                       f1, clu1, cf2b1, WPK, BIAS, gNet);
    hipLaunchKernelGGL(kD, dim3(1), dim3(256), 0, stream,
                       gNet, DWC, BIAS, d_out, modep);
}

// Round 17
// 481.267 us; speedup vs baseline: 1.5216x; 1.1178x over previous
//
#include <hip/hip_runtime.h>
#include <stdint.h>

// Problem constants
#define B_   8
#define N_   32768
#define C_   32
#define K_   22
#define CAT_ 40

typedef unsigned short u16;
typedef unsigned int   u32;

typedef __attribute__((ext_vector_type(8))) short bf16x8;
typedef __attribute__((ext_vector_type(4))) float f32x4;

#define MFMA(a, b, c) __builtin_amdgcn_mfma_f32_16x16x32_bf16(a, b, c, 0, 0, 0)

// ---------- bf16 helpers (raw bits) ----------
__device__ __forceinline__ float b2f(u16 v) { return __uint_as_float(((u32)v) << 16); }
__device__ __forceinline__ u16 f2b(float f) {
    u32 x = __float_as_uint(f);
    return (u16)((x + 0x7fffu + ((x >> 16) & 1u)) >> 16);   // RNE
}
__device__ __forceinline__ u32 pk2(float a, float b) {
    return (u32)f2b(a) | ((u32)f2b(b) << 16);
}

// ---------- packed MFMA A-fragment weight offsets (u16 units) ----------
#define PK_WIN 0         // 256x32(pad), KB=1 : 8192
#define PK_W1  8192      // 2 x 64x256, KB=8  : 16384 each
#define PK_W2  40960     // 2 x 128x64, KB=2  : 8192 each
#define PK_W3  57344     // 2 x 128x128, KB=4 : 16384 each
#define PK_WC1 90112     // 2 x 128x128       : 16384 each
#define PK_WC2 122880    // 2 x 256x128, KB=4 : 32768 each
#define PK_WC3 188416    // 2 x 32x256, KB=8  : 8192 each
#define PK_WO1 204800    // 128x256, KB=8     : 32768
#define PK_WO2 237568    // 128x128, KB=4     : 16384

// ---------- fp32 bias block offsets (floats) ----------
#define OBIN 0
#define OB1  256
#define OB2  384
#define OB3  640
#define OBC1 896
#define OBC2 1152
#define OBC3 1664
#define OBO1 1728
#define OBO2 1856
#define ODB1 1984
#define ODB2 2240
#define ODB3 2496

// ---------- canonical bf16 dense-head weights (u16 offsets) ----------
#define ODW1 0
#define ODW2 32768
#define ODW3 98304

// ---------- workspace byte offsets ----------
#define OFS_WPK   0u
#define OFS_BIAS  524288u
#define OFS_DWC   540672u
#define OFS_MODE  786432u
#define OFS_FEATC 1048576u
#define OFS_GACC0 12582912u
#define OFS_GACC1 12746752u
#define OFS_GNET  12910592u
#define GACC_ZERO_BYTES 331776u
#define OFS_CF2B0 12914688u
#define OFS_CF2B1 12980224u
#define OFS_F0    16777216u     // fragment-major f: [b][nt(2048 of 16 pts)][kb(4)][lane(64)][8] bf16
#define OFS_F1    83886080u

// sSeg LDS layout: stride 161 dwords (160%32==0 caused 16-way bank conflicts on
// every seg-max atomic — round-6 lesson). bank=(cl*161+co)%32=(cl+co)%32.
#define SEGSTR 161
#define SEGTOT (32 * SEGSTR)
// cf2b LDS staging stride: 136 u16 (cluster base -> 8 bank groups, 16B aligned).
#define CFSTR 136

// ---------- dtype sniffer ----------
__global__ void kSniff(const u16* __restrict__ featAny, int* __restrict__ mode) {
    __shared__ int cnt;
    if (threadIdx.x == 0) cnt = 0;
    __syncthreads();
    int weird = 0;
    for (int j = 0; j < 4; ++j) {
        u16 v = featAny[threadIdx.x * 4 + j];
        float f = b2f(v);
        if (v == 0 || !(fabsf(f) < 1e10f)) weird++;
    }
    if (weird) atomicAdd(&cnt, weird);
    __syncthreads();
    if (threadIdx.x == 0) *mode = (cnt > 64) ? 1 : 0;
}

__device__ __forceinline__ float fetchF(const void* src, size_t i, int mode) {
    return mode ? ((const float*)src)[i] : b2f(((const u16*)src)[i]);
}

// ---------- weight pack: (COUT,CIN) -> MFMA A-fragment bf16 order ----------
__device__ void packA(const void* __restrict__ src, u16* __restrict__ dst,
                      int COUT, int CIN, int mode, int tid, int np) {
    int KB = (CIN + 31) / 32;
    int tiles = COUT / 16;
    int tot = tiles * KB * 64 * 8;
    for (int i = tid; i < tot; i += np) {
        int j = i & 7;
        int L = (i >> 3) & 63;
        int rest = i >> 9;
        int kb = rest % KB, tile = rest / KB;
        int co = tile * 16 + (L & 15);
        int ci = kb * 32 + (L >> 4) * 8 + j;
        float v = (ci < CIN) ? fetchF(src, (size_t)co * CIN + ci, mode) : 0.f;
        dst[i] = f2b(v);
    }
}

__device__ void cvtF(const void* __restrict__ src, float* __restrict__ dst,
                     int n, int mode, int tid, int np) {
    for (int i = tid; i < n; i += np) dst[i] = fetchF(src, i, mode);
}

__device__ void cvtB(const void* __restrict__ src, u16* __restrict__ dst,
                     int n, int mode, int tid, int np) {
    for (int i = tid; i < n; i += np)
        dst[i] = mode ? f2b(((const float*)src)[i]) : ((const u16*)src)[i];
}

__global__ void kPrep(const void* feat, const void* w_in, const void* b_in,
                      const void* w1, const void* b1, const void* w2, const void* b2,
                      const void* w3, const void* b3,
                      const void* wc1, const void* bc1, const void* wc2, const void* bc2,
                      const void* wc3, const void* bc3,
                      const void* wo1, const void* bo1, const void* wo2, const void* bo2,
                      const void* dw1, const void* db1, const void* dw2, const void* db2,
                      const void* dw3, const void* db3,
                      u16* WPK, float* BIAS, u16* DWC, u16* FEATC,
                      const int* __restrict__ modep) {
    const int mode = *modep;
    int tid = blockIdx.x * blockDim.x + threadIdx.x;
    int np  = gridDim.x * blockDim.x;
    cvtB(feat, FEATC, B_ * N_ * K_, mode, tid, np);
    packA(w_in, WPK + PK_WIN, 256, 22, mode, tid, np);
    packA(w1,                                 WPK + PK_W1,          64, 256, mode, tid, np);
    packA((const u16*)w1 + (mode?32768:16384), WPK + PK_W1 + 16384,  64, 256, mode, tid, np);
    packA(w2,                                 WPK + PK_W2,          128, 64, mode, tid, np);
    packA((const u16*)w2 + (mode?16384:8192),  WPK + PK_W2 + 8192,   128, 64, mode, tid, np);
    packA(w3,                                 WPK + PK_W3,          128, 128, mode, tid, np);
    packA((const u16*)w3 + (mode?32768:16384), WPK + PK_W3 + 16384,  128, 128, mode, tid, np);
    packA(wc1,                                WPK + PK_WC1,         128, 128, mode, tid, np);
    packA((const u16*)wc1 + (mode?32768:16384),WPK + PK_WC1 + 16384, 128, 128, mode, tid, np);
    packA(wc2,                                WPK + PK_WC2,         256, 128, mode, tid, np);
    packA((const u16*)wc2 + (mode?65536:32768),WPK + PK_WC2 + 32768, 256, 128, mode, tid, np);
    packA(wc3,                                WPK + PK_WC3,         32, 256, mode, tid, np);
    packA((const u16*)wc3 + (mode?16384:8192), WPK + PK_WC3 + 8192,  32, 256, mode, tid, np);
    packA(wo1, WPK + PK_WO1, 128, 256, mode, tid, np);
    packA(wo2, WPK + PK_WO2, 128, 128, mode, tid, np);
    cvtF(b_in, BIAS + OBIN, 256, mode, tid, np);
    cvtF(b1,   BIAS + OB1,  128, mode, tid, np);
    cvtF(b2,   BIAS + OB2,  256, mode, tid, np);
    cvtF(b3,   BIAS + OB3,  256, mode, tid, np);
    cvtF(bc1,  BIAS + OBC1, 256, mode, tid, np);
    cvtF(bc2,  BIAS + OBC2, 512, mode, tid, np);
    cvtF(bc3,  BIAS + OBC3, 64,  mode, tid, np);
    cvtF(bo1,  BIAS + OBO1, 128, mode, tid, np);
    cvtF(bo2,  BIAS + OBO2, 128, mode, tid, np);
    cvtF(db1,  BIAS + ODB1, 256, mode, tid, np);
    cvtF(db2,  BIAS + ODB2, 256, mode, tid, np);
    cvtF(db3,  BIAS + ODB3, 40,  mode, tid, np);
    cvtB(dw1, DWC + ODW1, 128 * 256, mode, tid, np);
    cvtB(dw2, DWC + ODW2, 256 * 256, mode, tid, np);
    cvtB(dw3, DWC + ODW3, 256 * 40,  mode, tid, np);
}

__device__ __forceinline__ void storeRow(u16* __restrict__ buf, int p, int col,
                                         float r0, float r1, float r2, float r3) {
    *(uint2*)(buf + p * 136 + col) = make_uint2(pk2(r0, r1), pk2(r2, r3));
}

// Load a wave's weight fragments for one phase into registers.
template<int NF>
__device__ __forceinline__ void loadWF(const u16* __restrict__ wA, int lane, bf16x8 (&wf)[NF]) {
#pragma unroll
    for (int i = 0; i < NF; ++i)
        wf[i] = *(const bf16x8*)(wA + ((size_t)(i * 64 + lane)) * 8);
}

// ================= 8-wave / 128-pt building blocks (R12-verified) ==========
template<int KB, int INS>
__device__ __forceinline__ void convP128w(const bf16x8 (&wf)[KB], const float* __restrict__ bias,
                                          const u16* __restrict__ sIn, u16* __restrict__ sOut) {
    const int t = threadIdx.x, lane = t & 63, w = t >> 6, lp = lane & 15, q = lane >> 4;
    f32x4 acc[8] = {};
#pragma unroll
    for (int kb = 0; kb < KB; ++kb) {
        bf16x8 bb[8];
#pragma unroll
        for (int pt = 0; pt < 8; ++pt)
            bb[pt] = *(const bf16x8*)(sIn + (pt * 16 + lp) * INS + kb * 32 + q * 8);
#pragma unroll
        for (int pt = 0; pt < 8; ++pt) acc[pt] = MFMA(wf[kb], bb[pt], acc[pt]);
    }
    const int co = w * 16 + q * 4;
    f32x4 bv = *(const f32x4*)(bias + co);
#pragma unroll
    for (int pt = 0; pt < 8; ++pt) {
        f32x4 v = acc[pt];
        storeRow(sOut, pt * 16 + lp, co,
                 fmaxf(v[0] + bv[0], 0.f), fmaxf(v[1] + bv[1], 0.f),
                 fmaxf(v[2] + bv[2], 0.f), fmaxf(v[3] + bv[3], 0.f));
    }
}

// w2 64->128 fused: LDS store + f32 seg-max atomics from registers.
__device__ __forceinline__ void convW2_128w(const bf16x8 (&wf)[2], const float* __restrict__ bias,
                                            const u16* __restrict__ sIn, u16* __restrict__ sOut,
                                            const int* __restrict__ sCluSeg, int* __restrict__ sSeg) {
    const int t = threadIdx.x, lane = t & 63, w = t >> 6, lp = lane & 15, q = lane >> 4;
    f32x4 acc[8] = {};
#pragma unroll
    for (int kb = 0; kb < 2; ++kb) {
        bf16x8 bb[8];
#pragma unroll
        for (int pt = 0; pt < 8; ++pt)
            bb[pt] = *(const bf16x8*)(sIn + (pt * 16 + lp) * 136 + kb * 32 + q * 8);
#pragma unroll
        for (int pt = 0; pt < 8; ++pt) acc[pt] = MFMA(wf[kb], bb[pt], acc[pt]);
    }
    const int co = w * 16 + q * 4;
    f32x4 bv = *(const f32x4*)(bias + co);
#pragma unroll
    for (int pt = 0; pt < 8; ++pt) {
        f32x4 v = acc[pt];
        const int p = pt * 16 + lp;
        float r0 = fmaxf(v[0] + bv[0], 0.f), r1 = fmaxf(v[1] + bv[1], 0.f);
        float r2 = fmaxf(v[2] + bv[2], 0.f), r3 = fmaxf(v[3] + bv[3], 0.f);
        *(uint2*)(sOut + p * 136 + co) = make_uint2(pk2(r0, r1), pk2(r2, r3));
        const int sb = sCluSeg[p] * SEGSTR + co;
        atomicMax(&sSeg[sb + 0], __float_as_int(r0));
        atomicMax(&sSeg[sb + 1], __float_as_int(r1));
        atomicMax(&sSeg[sb + 2], __float_as_int(r2));
        atomicMax(&sSeg[sb + 3], __float_as_int(r3));
    }
}

// w1 256->64 concat (both halves in LDS): co-tile (w&3), p-group (w>>2)*4.
__device__ __forceinline__ void convCat128w(const bf16x8 (&wf)[8], const float* __restrict__ bias,
                                            const u16* __restrict__ sLo, const u16* __restrict__ sHi,
                                            u16* __restrict__ sOut) {
    const int t = threadIdx.x, lane = t & 63, w = t >> 6, lp = lane & 15, q = lane >> 4;
    const int ct = w & 3, pp = (w >> 2) * 4;
    f32x4 acc[4] = {};
#pragma unroll
    for (int kb = 0; kb < 8; ++kb) {
        const u16* sIn = (kb < 4) ? sLo : sHi;
        const int col = (kb & 3) * 32 + q * 8;
        bf16x8 bb[4];
#pragma unroll
        for (int i = 0; i < 4; ++i)
            bb[i] = *(const bf16x8*)(sIn + ((pp + i) * 16 + lp) * 136 + col);
#pragma unroll
        for (int i = 0; i < 4; ++i) acc[i] = MFMA(wf[kb], bb[i], acc[i]);
    }
    const int co = ct * 16 + q * 4;
    f32x4 bv = *(const f32x4*)(bias + co);
#pragma unroll
    for (int i = 0; i < 4; ++i) {
        f32x4 v = acc[i];
        storeRow(sOut, (pp + i) * 16 + lp, co,
                 fmaxf(v[0] + bv[0], 0.f), fmaxf(v[1] + bv[1], 0.f),
                 fmaxf(v[2] + bv[2], 0.f), fmaxf(v[3] + bv[3], 0.f));
    }
}

// w1 256->64 concat, upper half gathered per-lane from LDS-staged cf2b (stride 136).
__device__ __forceinline__ void convCatG128s(const bf16x8 (&wf)[8], const float* __restrict__ bias,
                                             const u16* __restrict__ sIn, const u16* __restrict__ sCf,
                                             const int* __restrict__ sClu, u16* __restrict__ sOut) {
    const int t = threadIdx.x, lane = t & 63, w = t >> 6, lp = lane & 15, q = lane >> 4;
    const int ct = w & 3, pp = (w >> 2) * 4;
    f32x4 acc[4] = {};
#pragma unroll
    for (int kb = 0; kb < 8; ++kb) {
        bf16x8 bb[4];
#pragma unroll
        for (int i = 0; i < 4; ++i) {
            const int p = (pp + i) * 16 + lp;
            if (kb < 4) bb[i] = *(const bf16x8*)(sIn + p * 136 + kb * 32 + q * 8);
            else        bb[i] = *(const bf16x8*)(sCf + sClu[p] * CFSTR + (kb - 4) * 32 + q * 8);
        }
#pragma unroll
        for (int i = 0; i < 4; ++i) acc[i] = MFMA(wf[kb], bb[i], acc[i]);
    }
    const int co = ct * 16 + q * 4;
    f32x4 bv = *(const f32x4*)(bias + co);
#pragma unroll
    for (int i = 0; i < 4; ++i) {
        f32x4 v = acc[i];
        storeRow(sOut, (pp + i) * 16 + lp, co,
                 fmaxf(v[0] + bv[0], 0.f), fmaxf(v[1] + bv[1], 0.f),
                 fmaxf(v[2] + bv[2], 0.f), fmaxf(v[3] + bv[3], 0.f));
    }
}

// CIN=128 conv, B direct from global fragment-major f (128-pt group).
__device__ __forceinline__ void convG128w(const bf16x8 (&wf)[4], const float* __restrict__ bias,
                                          const u16* __restrict__ gB, u16* __restrict__ sOut) {
    const int t = threadIdx.x, lane = t & 63, w = t >> 6, lp = lane & 15, q = lane >> 4;
    f32x4 acc[8] = {};
#pragma unroll
    for (int kb = 0; kb < 4; ++kb) {
        bf16x8 bb[8];
#pragma unroll
        for (int pt = 0; pt < 8; ++pt)
            bb[pt] = *(const bf16x8*)(gB + pt * 2048 + kb * 512 + lane * 8);
#pragma unroll
        for (int pt = 0; pt < 8; ++pt) acc[pt] = MFMA(wf[kb], bb[pt], acc[pt]);
    }
    const int co = w * 16 + q * 4;
    f32x4 bv = *(const f32x4*)(bias + co);
#pragma unroll
    for (int pt = 0; pt < 8; ++pt) {
        f32x4 v = acc[pt];
        storeRow(sOut, pt * 16 + lp, co,
                 fmaxf(v[0] + bv[0], 0.f), fmaxf(v[1] + bv[1], 0.f),
                 fmaxf(v[2] + bv[2], 0.f), fmaxf(v[3] + bv[3], 0.f));
    }
}

// wc3 (32x256) + corr seg-max: co-tile (w&1), p-pair (w>>1)*2.
__device__ __forceinline__ void wc3seg128w(const bf16x8 (&wf)[8], const float* __restrict__ bias,
                                           const u16* __restrict__ sLo, const u16* __restrict__ sHi,
                                           const int* __restrict__ sClu, int* __restrict__ sSeg) {
    const int t = threadIdx.x, lane = t & 63, w = t >> 6, lp = lane & 15, q = lane >> 4;
    const int ct = w & 1, pp = (w >> 1) * 2;
    f32x4 acc[2] = {};
#pragma unroll
    for (int kb = 0; kb < 8; ++kb) {
        const u16* sIn = (kb < 4) ? sLo : sHi;
        const int col = (kb & 3) * 32 + q * 8;
        bf16x8 b0 = *(const bf16x8*)(sIn + ((pp + 0) * 16 + lp) * 136 + col);
        bf16x8 b1 = *(const bf16x8*)(sIn + ((pp + 1) * 16 + lp) * 136 + col);
        acc[0] = MFMA(wf[kb], b0, acc[0]);
        acc[1] = MFMA(wf[kb], b1, acc[1]);
    }
    const int col = ct * 16 + q * 4;
    f32x4 bv = *(const f32x4*)(bias + col);
#pragma unroll
    for (int i = 0; i < 2; ++i) {
        const int p = (pp + i) * 16 + lp;
        const int cl = sClu[p];
        f32x4 v = acc[i];
        atomicMax(&sSeg[cl * SEGSTR + 128 + col + 0], __float_as_int(fmaxf(v[0] + bv[0], 0.f)));
        atomicMax(&sSeg[cl * SEGSTR + 128 + col + 1], __float_as_int(fmaxf(v[1] + bv[1], 0.f)));
        atomicMax(&sSeg[cl * SEGSTR + 128 + col + 2], __float_as_int(fmaxf(v[2] + bv[2], 0.f)));
        atomicMax(&sSeg[cl * SEGSTR + 128 + col + 3], __float_as_int(fmaxf(v[3] + bv[3], 0.f)));
    }
}

// ---------- kC building blocks ----------
// wo1 256->128 concat: wave w -> co-tile w, 8 p-tiles; kb<4 from sIn, kb>=4 LDS-staged cf2b.
__device__ __forceinline__ void convCatG128os(const bf16x8 (&wf)[8], const float* __restrict__ bias,
                                              const u16* __restrict__ sIn, const u16* __restrict__ sCf,
                                              const int* __restrict__ sClu, u16* __restrict__ sOut) {
    const int t = threadIdx.x, lane = t & 63, w = t >> 6, lp = lane & 15, q = lane >> 4;
    f32x4 acc[8] = {};
#pragma unroll
    for (int kb = 0; kb < 8; ++kb) {
        bf16x8 bb[8];
#pragma unroll
        for (int pt = 0; pt < 8; ++pt) {
            const int p = pt * 16 + lp;
            if (kb < 4) bb[pt] = *(const bf16x8*)(sIn + p * 136 + kb * 32 + q * 8);
            else        bb[pt] = *(const bf16x8*)(sCf + sClu[p] * CFSTR + (kb - 4) * 32 + q * 8);
        }
#pragma unroll
        for (int pt = 0; pt < 8; ++pt) acc[pt] = MFMA(wf[kb], bb[pt], acc[pt]);
    }
    const int co = w * 16 + q * 4;
    f32x4 bv = *(const f32x4*)(bias + co);
#pragma unroll
    for (int pt = 0; pt < 8; ++pt) {
        f32x4 v = acc[pt];
        storeRow(sOut, pt * 16 + lp, co,
                 fmaxf(v[0] + bv[0], 0.f), fmaxf(v[1] + bv[1], 0.f),
                 fmaxf(v[2] + bv[2], 0.f), fmaxf(v[3] + bv[3], 0.f));
    }
}

// wo2 128->128 + per-channel max: register-max over 8 p-tiles FIRST, then one
// atomicMax per lane-channel.
__device__ __forceinline__ void convNet128w(const bf16x8 (&wf)[4], const float* __restrict__ bias,
                                            const u16* __restrict__ sIn, int* __restrict__ sNet) {
    const int t = threadIdx.x, lane = t & 63, w = t >> 6, lp = lane & 15, q = lane >> 4;
    f32x4 acc[8] = {};
#pragma unroll
    for (int kb = 0; kb < 4; ++kb) {
        bf16x8 bb[8];
#pragma unroll
        for (int pt = 0; pt < 8; ++pt)
            bb[pt] = *(const bf16x8*)(sIn + (pt * 16 + lp) * 136 + kb * 32 + q * 8);
#pragma unroll
        for (int pt = 0; pt < 8; ++pt) acc[pt] = MFMA(wf[kb], bb[pt], acc[pt]);
    }
    const int co = w * 16 + q * 4;
    f32x4 bv = *(const f32x4*)(bias + co);
    f32x4 m = acc[0];
#pragma unroll
    for (int pt = 1; pt < 8; ++pt) {
        m[0] = fmaxf(m[0], acc[pt][0]); m[1] = fmaxf(m[1], acc[pt][1]);
        m[2] = fmaxf(m[2], acc[pt][2]); m[3] = fmaxf(m[3], acc[pt][3]);
    }
    atomicMax(&sNet[co + 0], __float_as_int(fmaxf(m[0] + bv[0], 0.f)));
    atomicMax(&sNet[co + 1], __float_as_int(fmaxf(m[1] + bv[1], 0.f)));
    atomicMax(&sNet[co + 2], __float_as_int(fmaxf(m[2] + bv[2], 0.f)));
    atomicMax(&sNet[co + 3], __float_as_int(fmaxf(m[3] + bv[3], 0.f)));
}

// ---------- iteration-0, part A: w_in -> w1 -> w2 (+f seg, gF store) ----------
__global__ __launch_bounds__(512, 2)
void kA0a(const u16* __restrict__ featc, const int* __restrict__ clu0,
          const u16* __restrict__ WPK, const float* __restrict__ BIAS,
          u16* __restrict__ gF, int* __restrict__ gSeg) {
    __shared__ __attribute__((aligned(16))) u16 sA[128 * 136];
    __shared__ __attribute__((aligned(16))) u16 sB[128 * 136];
    __shared__ __attribute__((aligned(16))) u16 sC[128 * 136];
    __shared__ __attribute__((aligned(16))) u16 sFeat[128 * 40];
    __shared__ int sSeg[SEGTOT];
    __shared__ int sClu[128];
    const int t = threadIdx.x, lane = t & 63, w = t >> 6, lp = lane & 15, q = lane >> 4;
    const int b = blockIdx.y;
    const size_t bN = (size_t)b * N_;
    bf16x8 wf1a[1], wf1b[1], wf2[8], wf3[2];
    loadWF(WPK + PK_WIN + w * 512, lane, wf1a);
    loadWF(WPK + PK_WIN + 4096 + w * 512, lane, wf1b);
    loadWF(WPK + PK_W1 + (w & 3) * 4096, lane, wf2);
    loadWF(WPK + PK_W2 + w * 1024, lane, wf3);
    for (int i = t; i < SEGTOT; i += 512) sSeg[i] = 0;
    {
        const int n0 = blockIdx.x * 1024;
        for (int i = t; i < 5120; i += 512) {
            int p = i / 40, k = i - p * 40;
            sFeat[i] = (k < 22) ? featc[(bN + n0 + p) * 22 + k] : (u16)0;
        }
    }
    __syncthreads();
    for (int s = 0; s < 8; ++s) {
        const int n0 = (blockIdx.x * 8 + s) * 128;
        const size_t ntB = (size_t)b * 2048 + (size_t)(blockIdx.x * 8 + s) * 8;
        if (t < 128) sClu[t] = clu0[bN + n0 + t];
        convP128w<1, 40>(wf1a, BIAS + OBIN,       sFeat, sA);
        convP128w<1, 40>(wf1b, BIAS + OBIN + 128, sFeat, sB);
        __syncthreads();
        convCat128w(wf2, BIAS + OB1, sA, sB, sC);
        __syncthreads();
        convW2_128w(wf3, BIAS + OB2, sC, sA, sClu, sSeg);
        __syncthreads();
        {
#pragma unroll
            for (int r = 0; r < 4; ++r) {
                bf16x8 v = *(const bf16x8*)(sA + (w * 16 + lp) * 136 + r * 32 + q * 8);
                *(bf16x8*)(gF + ((ntB + w) * 4 + r) * 512 + lane * 8) = v;
            }
        }
        if (s < 7) {
            const int n1 = n0 + 128;
            for (int i = t; i < 5120; i += 512) {
                int p = i / 40, k = i - p * 40;
                sFeat[i] = (k < 22) ? featc[(bN + n1 + p) * 22 + k] : (u16)0;
            }
        }
        __syncthreads();
    }
    for (int i = t; i < 4096; i += 512) {
        int cl = i >> 7, ch = i & 127;
        atomicMax(&gSeg[b * 5120 + cl * 160 + ch], sSeg[cl * SEGSTR + ch]);
    }
}

// ---------- part B: wc1 -> wc2 -> wc3 (+corr seg). f consumed from global fragments ----------
template<int PKOFF, int BOFF>
__device__ __forceinline__ void kAbBody(const u16* __restrict__ gFp, const int* __restrict__ clu,
                                        const u16* __restrict__ WPK, const float* __restrict__ BIAS,
                                        int* __restrict__ gSeg) {
    __shared__ __attribute__((aligned(16))) u16 sA[128 * 136];
    __shared__ __attribute__((aligned(16))) u16 sB[128 * 136];
    __shared__ __attribute__((aligned(16))) u16 sC[128 * 136];
    __shared__ int sSeg[SEGTOT];
    __shared__ int sClu[128];
    const int t = threadIdx.x, lane = t & 63, w = t >> 6;
    const int b = blockIdx.y;
    const size_t bN = (size_t)b * N_;
    bf16x8 wf4[4], wf5a[4], wf5b[4], wf6[8];
    loadWF(WPK + PK_WC1 + PKOFF * 16384 + w * 2048, lane, wf4);
    loadWF(WPK + PK_WC2 + PKOFF * 32768 + w * 2048, lane, wf5a);
    loadWF(WPK + PK_WC2 + PKOFF * 32768 + 16384 + w * 2048, lane, wf5b);
    loadWF(WPK + PK_WC3 + PKOFF * 8192 + (w & 1) * 4096, lane, wf6);
    for (int i = t; i < SEGTOT; i += 512) sSeg[i] = 0;
    __syncthreads();
    for (int s = 0; s < 8; ++s) {
        const int n0 = (blockIdx.x * 8 + s) * 128;
        const size_t ntB = (size_t)b * 2048 + (size_t)(blockIdx.x * 8 + s) * 8;
        if (t < 128) sClu[t] = clu[bN + n0 + t];
        const u16* gB = gFp + ntB * 2048;
        convG128w(wf4, BIAS + OBC1 + BOFF * 128, gB, sA);
        __syncthreads();
        convP128w<4, 136>(wf5a, BIAS + OBC2 + BOFF * 256,       sA, sB);
        convP128w<4, 136>(wf5b, BIAS + OBC2 + BOFF * 256 + 128, sA, sC);
        __syncthreads();
        wc3seg128w(wf6, BIAS + OBC3 + BOFF * 32, sB, sC, sClu, sSeg);
        __syncthreads();
    }
    for (int i = t; i < 1024; i += 512) {
        int cl = i >> 5, ch = i & 31;
        atomicMax(&gSeg[b * 5120 + cl * 160 + 128 + ch], sSeg[cl * SEGSTR + 128 + ch]);
    }
}

__global__ __launch_bounds__(512, 2)
void kA0b(const u16* __restrict__ gFp, const int* __restrict__ clu0,
          const u16* __restrict__ WPK, const float* __restrict__ BIAS,
          int* __restrict__ gSeg) {
    kAbBody<0, 0>(gFp, clu0, WPK, BIAS, gSeg);
}

__global__ __launch_bounds__(512, 2)
void kA1b(const u16* __restrict__ gFp, const int* __restrict__ clu1,
          const u16* __restrict__ WPK, const float* __restrict__ BIAS,
          int* __restrict__ gSeg) {
    kAbBody<1, 1>(gFp, clu1, WPK, BIAS, gSeg);
}

// ---------- per-batch cluster math -> bf16 cf2b ----------
__global__ __launch_bounds__(256)
void kB(const int* __restrict__ gSeg, u16* __restrict__ cf2b) {
    __shared__ float sA[5120];
    __shared__ float sR[1024];
    __shared__ float sI[32];
    const int t = threadIdx.x, b = blockIdx.x;
    for (int i = t; i < 5120; i += 256) sA[i] = __int_as_float(gSeg[b * 5120 + i]);
    __syncthreads();
    if (t < 32) {
        float s = 0.f;
        for (int j = 0; j < 32; ++j) { float v = sA[t * 160 + 128 + j]; s = fmaf(v, v, s); }
        sI[t] = 1.f / fmaxf(sqrtf(s), 1e-12f);
    }
    __syncthreads();
    for (int i = t; i < 1024; i += 256) {
        int ca = i >> 5, cb = i & 31;
        float s = 0.f;
        for (int j = 0; j < 32; ++j)
            s = fmaf(sA[ca * 160 + 128 + j], sA[cb * 160 + 128 + j], s);
        sR[i] = s * sI[ca] * sI[cb];
    }
    __syncthreads();
    for (int i = t; i < 4096; i += 256) {
        int c = i >> 7, ch = i & 127;
        float s = 0.f;
        for (int cp = 0; cp < 32; ++cp)
            s = fmaf(sA[cp * 160 + ch], sR[cp * 32 + c], s);
        cf2b[((size_t)b * 32 + c) * 128 + ch] = f2b(s);
    }
}

// ---------- iteration-1, part A: w3 -> w1concat -> w2 (+f seg, gFo store) ----------
// cf2b staged in LDS (R16-verified: kills the per-lane divergent global gather).
__global__ __launch_bounds__(512, 2)
void kA1a(const u16* __restrict__ gFp, const int* __restrict__ clu_g,
          const int* __restrict__ clu_s, const u16* __restrict__ cf2b,
          const u16* __restrict__ WPK, const float* __restrict__ BIAS,
          u16* __restrict__ gFo, int* __restrict__ gSeg) {
    __shared__ __attribute__((aligned(16))) u16 sA[128 * 136];
    __shared__ __attribute__((aligned(16))) u16 sB[128 * 136];
    __shared__ __attribute__((aligned(16))) u16 sC[128 * 136];
    __shared__ __attribute__((aligned(16))) u16 sCf[32 * CFSTR];
    __shared__ int sSeg[SEGTOT];
    __shared__ int sClu0[128];
    __shared__ int sClu1[128];
    const int t = threadIdx.x, lane = t & 63, w = t >> 6, lp = lane & 15, q = lane >> 4;
    const int b = blockIdx.y;
    const size_t bN = (size_t)b * N_;
    bf16x8 wfG[4], wf2[8], wf3[2];
    loadWF(WPK + PK_W3 + w * 2048, lane, wfG);
    loadWF(WPK + PK_W1 + 16384 + (w & 3) * 4096, lane, wf2);
    loadWF(WPK + PK_W2 + 8192 + w * 1024, lane, wf3);
    for (int i = t; i < SEGTOT; i += 512) sSeg[i] = 0;
    const u16* cfb = cf2b + (size_t)b * 4096;
    for (int i = t; i < 4096; i += 512) {
        int cl = i >> 7, ch = i & 127;
        sCf[cl * CFSTR + ch] = cfb[i];
    }
    __syncthreads();
    for (int s = 0; s < 8; ++s) {
        const int n0 = (blockIdx.x * 8 + s) * 128;
        const size_t ntB = (size_t)b * 2048 + (size_t)(blockIdx.x * 8 + s) * 8;
        if (t < 128) sClu0[t] = clu_g[bN + n0 + t];
        else if (t < 256) sClu1[t - 128] = clu_s[bN + n0 + (t - 128)];
        const u16* gB = gFp + ntB * 2048;
        convG128w(wfG, BIAS + OB3, gB, sA);
        __syncthreads();
        convCatG128s(wf2, BIAS + OB1 + 64, sA, sCf, sClu0, sB);
        __syncthreads();
        convW2_128w(wf3, BIAS + OB2 + 128, sB, sC, sClu1, sSeg);
        __syncthreads();
        {
#pragma unroll
            for (int r = 0; r < 4; ++r) {
                bf16x8 v = *(const bf16x8*)(sC + (w * 16 + lp) * 136 + r * 32 + q * 8);
                *(bf16x8*)(gFo + ((ntB + w) * 4 + r) * 512 + lane * 8) = v;
            }
        }
        __syncthreads();
    }
    for (int i = t; i < 4096; i += 512) {
        int cl = i >> 7, ch = i & 127;
        atomicMax(&gSeg[b * 5120 + cl * 160 + ch], sSeg[cl * SEGSTR + ch]);
    }
}

// ---------- final conv head: 512 thr, 128-pt subtiles, LDS-staged cf2b (R16-verified) ----------
__global__ __launch_bounds__(512, 2)
void kC(const u16* __restrict__ gFp, const int* __restrict__ clu_g,
        const u16* __restrict__ cf2b,
        const u16* __restrict__ WPK, const float* __restrict__ BIAS,
        int* __restrict__ gNet) {
    __shared__ __attribute__((aligned(16))) u16 sA[128 * 136];
    __shared__ __attribute__((aligned(16))) u16 sB[128 * 136];
    __shared__ __attribute__((aligned(16))) u16 sCf[32 * CFSTR];
    __shared__ int sNet[128];
    __shared__ int sClu[128];
    const int t = threadIdx.x, lane = t & 63, w = t >> 6;
    const int b = blockIdx.y;
    const size_t bN = (size_t)b * N_;
    bf16x8 wfG[4], wfO1[8], wfO2[4];
    loadWF(WPK + PK_W3 + 16384 + w * 2048, lane, wfG);
    loadWF(WPK + PK_WO1 + w * 4096, lane, wfO1);
    loadWF(WPK + PK_WO2 + w * 2048, lane, wfO2);
    if (t < 128) sNet[t] = 0;
    const u16* cfb = cf2b + (size_t)b * 4096;
    for (int i = t; i < 4096; i += 512) {
        int cl = i >> 7, ch = i & 127;
        sCf[cl * CFSTR + ch] = cfb[i];
    }
    __syncthreads();
    for (int s = 0; s < 4; ++s) {
        const int n0 = (blockIdx.x * 4 + s) * 128;
        if (t < 128) sClu[t] = clu_g[bN + n0 + t];
        const u16* gB = gFp + ((size_t)b * 2048 + (size_t)(blockIdx.x * 4 + s) * 8) * 2048;
        convG128w(wfG, BIAS + OB3 + 128, gB, sA);
        __syncthreads();
        convCatG128os(wfO1, BIAS + OBO1, sA, sCf, sClu, sB);
        __syncthreads();
        convNet128w(wfO2, BIAS + OBO2, sB, sNet);
        __syncthreads();
    }
    if (t < 128) atomicMax(&gNet[b * 128 + t], sNet[t]);
}

// ---------- tiny MLP head: one block per batch (R17 — was grid(1), 88us serial) ----------
__global__ __launch_bounds__(256)
void kD(const int* __restrict__ gNet, const u16* __restrict__ DWC,
        const float* __restrict__ BIAS, void* __restrict__ outv,
        const int* __restrict__ modep) {
    __shared__ float sN[128];
    __shared__ float sD1[256];
    __shared__ float sD2[256];
    const int mode = *modep;
    const int t = threadIdx.x, bb = blockIdx.x;
    if (t < 128) sN[t] = __int_as_float(gNet[bb * 128 + t]);
    __syncthreads();
    {   // layer 1: 256 outputs, one per thread (k ascending — same order as before)
        float s = BIAS[ODB1 + t];
        for (int k = 0; k < 128; ++k)
            s = fmaf(sN[k], b2f(DWC[ODW1 + k * 256 + t]), s);
        sD1[t] = (s >= 0.f) ? s : 0.2f * s;
    }
    __syncthreads();
    {   // layer 2: 256 outputs, one per thread
        float s = BIAS[ODB2 + t];
        for (int k = 0; k < 256; ++k)
            s = fmaf(sD1[k], b2f(DWC[ODW2 + k * 256 + t]), s);
        sD2[t] = (s >= 0.f) ? s : 0.2f * s;
    }
    __syncthreads();
    if (t < 40) {   // layer 3: 40 outputs
        float s = BIAS[ODB3 + t];
        for (int k = 0; k < 256; ++k)
            s = fmaf(sD2[k], b2f(DWC[ODW3 + k * 40 + t]), s);
        if (mode) ((float*)outv)[bb * 40 + t] = s;
        else      ((u16*)outv)[bb * 40 + t]   = f2b(s);
    }
}

extern "C" void kernel_launch(void* const* d_in, const int* in_sizes, int n_in,
                              void* d_out, int out_size, void* d_ws, size_t ws_size,
                              hipStream_t stream) {
    const void* feat = d_in[0];
    const int* clus = (const int*)d_in[1];

    char* ws = (char*)d_ws;
    u16*   WPK   = (u16*)(ws + OFS_WPK);
    float* BIAS  = (float*)(ws + OFS_BIAS);
    u16*   DWC   = (u16*)(ws + OFS_DWC);
    int*   modep = (int*)(ws + OFS_MODE);
    u16*   FEATC = (u16*)(ws + OFS_FEATC);
    int*   seg0  = (int*)(ws + OFS_GACC0);
    int*   seg1  = (int*)(ws + OFS_GACC1);
    int*   gNet  = (int*)(ws + OFS_GNET);
    u16*   cf2b0 = (u16*)(ws + OFS_CF2B0);
    u16*   cf2b1 = (u16*)(ws + OFS_CF2B1);
    u16*   f0    = (u16*)(ws + OFS_F0);
    u16*   f1    = (u16*)(ws + OFS_F1);

    hipMemsetAsync(ws + OFS_GACC0, 0, GACC_ZERO_BYTES, stream);
    hipLaunchKernelGGL(kSniff, dim3(1), dim3(256), 0, stream, (const u16*)feat, modep);
    hipLaunchKernelGGL(kPrep, dim3(256), dim3(256), 0, stream,
                       feat, d_in[2], d_in[3], d_in[4], d_in[5], d_in[6], d_in[7],
                       d_in[8], d_in[9], d_in[10], d_in[11], d_in[12], d_in[13],
                       d_in[14], d_in[15], d_in[16], d_in[17], d_in[18], d_in[19],
                       d_in[20], d_in[21], d_in[22], d_in[23], d_in[24], d_in[25],
                       WPK, BIAS, DWC, FEATC, modep);

    const int* clu0 = clus;
    const int* clu1 = clus + (size_t)B_ * N_;

    hipLaunchKernelGGL(kA0a, dim3(32, 8), dim3(512), 0, stream,
                       FEATC, clu0, WPK, BIAS, f0, seg0);
    hipLaunchKernelGGL(kA0b, dim3(32, 8), dim3(512), 0, stream,
                       f0, clu0, WPK, BIAS, seg0);
    hipLaunchKernelGGL(kB, dim3(8), dim3(256), 0, stream, seg0, cf2b0);
    hipLaunchKernelGGL(kA1a, dim3(32, 8), dim3(512), 0, stream,
                       f0, clu0, clu1, cf2b0, WPK, BIAS, f1, seg1);
    hipLaunchKernelGGL(kA1b, dim3(32, 8), dim3(512), 0, stream,
                       f1, clu1, WPK, BIAS, seg1);
    hipLaunchKernelGGL(kB, dim3(8), dim3(256), 0, stream, seg1, cf2b1);
    hipLaunchKernelGGL(kC, dim3(64, 8), dim3(512), 0, stream,
                       f1, clu1, cf2b1, WPK, BIAS, gNet);
    hipLaunchKernelGGL(kD, dim3(8), dim3(256), 0, stream,
                       gNet, DWC, BIAS, d_out, modep);
}

// Round 18
// 476.773 us; speedup vs baseline: 1.5360x; 1.0094x over previous
//
#include <hip/hip_runtime.h>
#include <stdint.h>

// Problem constants
#define B_   8
#define N_   32768
#define C_   32
#define K_   22
#define CAT_ 40

typedef unsigned short u16;
typedef unsigned int   u32;

typedef __attribute__((ext_vector_type(8))) short bf16x8;
typedef __attribute__((ext_vector_type(4))) float f32x4;

#define MFMA(a, b, c) __builtin_amdgcn_mfma_f32_16x16x32_bf16(a, b, c, 0, 0, 0)

// ---------- bf16 helpers (raw bits) ----------
__device__ __forceinline__ float b2f(u16 v) { return __uint_as_float(((u32)v) << 16); }
__device__ __forceinline__ u16 f2b(float f) {
    u32 x = __float_as_uint(f);
    return (u16)((x + 0x7fffu + ((x >> 16) & 1u)) >> 16);   // RNE
}
__device__ __forceinline__ u32 pk2(float a, float b) {
    return (u32)f2b(a) | ((u32)f2b(b) << 16);
}

// ---------- packed MFMA A-fragment weight offsets (u16 units) ----------
#define PK_WIN 0         // 256x32(pad), KB=1 : 8192
#define PK_W1  8192      // 2 x 64x256, KB=8  : 16384 each
#define PK_W2  40960     // 2 x 128x64, KB=2  : 8192 each
#define PK_W3  57344     // 2 x 128x128, KB=4 : 16384 each
#define PK_WC1 90112     // 2 x 128x128       : 16384 each
#define PK_WC2 122880    // 2 x 256x128, KB=4 : 32768 each
#define PK_WC3 188416    // 2 x 32x256, KB=8  : 8192 each
#define PK_WO1 204800    // 128x256, KB=8     : 32768
#define PK_WO2 237568    // 128x128, KB=4     : 16384

// ---------- fp32 bias block offsets (floats) ----------
#define OBIN 0
#define OB1  256
#define OB2  384
#define OB3  640
#define OBC1 896
#define OBC2 1152
#define OBC3 1664
#define OBO1 1728
#define OBO2 1856
#define ODB1 1984
#define ODB2 2240
#define ODB3 2496

// ---------- canonical bf16 dense-head weights (u16 offsets) ----------
#define ODW1 0
#define ODW2 32768
#define ODW3 98304

// ---------- workspace byte offsets ----------
#define OFS_WPK   0u
#define OFS_BIAS  524288u
#define OFS_DWC   540672u
#define OFS_MODE  786432u
#define OFS_FEATC 1048576u
#define OFS_GACC0 12582912u
#define OFS_GACC1 12746752u
#define OFS_GNET  12910592u
#define GACC_ZERO_BYTES 331776u
#define OFS_CF2B0 12914688u
#define OFS_CF2B1 12980224u
#define OFS_F0    16777216u     // fragment-major f: [b][nt(2048 of 16 pts)][kb(4)][lane(64)][8] bf16
#define OFS_F1    83886080u

// sSeg LDS layout (full, 128f+32corr): stride 161 dwords (160%32==0 caused 16-way
// bank conflicts on every seg-max atomic — round-6 lesson). bank=(cl+co)%32.
#define SEGSTR 161
#define SEGTOT (32 * SEGSTR)
// f-seg-only sSeg (kA0a, R18): stride 129 (odd -> bank=(cl+co)%32 spread).
#define SEGFSTR 129
#define SEGFTOT (32 * SEGFSTR)
// cf2b LDS staging stride: 136 u16 (cluster base -> 8 bank groups, 16B aligned).
#define CFSTR 136

// ---------- dtype sniffer ----------
__global__ void kSniff(const u16* __restrict__ featAny, int* __restrict__ mode) {
    __shared__ int cnt;
    if (threadIdx.x == 0) cnt = 0;
    __syncthreads();
    int weird = 0;
    for (int j = 0; j < 4; ++j) {
        u16 v = featAny[threadIdx.x * 4 + j];
        float f = b2f(v);
        if (v == 0 || !(fabsf(f) < 1e10f)) weird++;
    }
    if (weird) atomicAdd(&cnt, weird);
    __syncthreads();
    if (threadIdx.x == 0) *mode = (cnt > 64) ? 1 : 0;
}

__device__ __forceinline__ float fetchF(const void* src, size_t i, int mode) {
    return mode ? ((const float*)src)[i] : b2f(((const u16*)src)[i]);
}

// ---------- weight pack: (COUT,CIN) -> MFMA A-fragment bf16 order ----------
__device__ void packA(const void* __restrict__ src, u16* __restrict__ dst,
                      int COUT, int CIN, int mode, int tid, int np) {
    int KB = (CIN + 31) / 32;
    int tiles = COUT / 16;
    int tot = tiles * KB * 64 * 8;
    for (int i = tid; i < tot; i += np) {
        int j = i & 7;
        int L = (i >> 3) & 63;
        int rest = i >> 9;
        int kb = rest % KB, tile = rest / KB;
        int co = tile * 16 + (L & 15);
        int ci = kb * 32 + (L >> 4) * 8 + j;
        float v = (ci < CIN) ? fetchF(src, (size_t)co * CIN + ci, mode) : 0.f;
        dst[i] = f2b(v);
    }
}

__device__ void cvtF(const void* __restrict__ src, float* __restrict__ dst,
                     int n, int mode, int tid, int np) {
    for (int i = tid; i < n; i += np) dst[i] = fetchF(src, i, mode);
}

__device__ void cvtB(const void* __restrict__ src, u16* __restrict__ dst,
                     int n, int mode, int tid, int np) {
    for (int i = tid; i < n; i += np)
        dst[i] = mode ? f2b(((const float*)src)[i]) : ((const u16*)src)[i];
}

__global__ void kPrep(const void* feat, const void* w_in, const void* b_in,
                      const void* w1, const void* b1, const void* w2, const void* b2,
                      const void* w3, const void* b3,
                      const void* wc1, const void* bc1, const void* wc2, const void* bc2,
                      const void* wc3, const void* bc3,
                      const void* wo1, const void* bo1, const void* wo2, const void* bo2,
                      const void* dw1, const void* db1, const void* dw2, const void* db2,
                      const void* dw3, const void* db3,
                      u16* WPK, float* BIAS, u16* DWC, u16* FEATC,
                      const int* __restrict__ modep) {
    const int mode = *modep;
    int tid = blockIdx.x * blockDim.x + threadIdx.x;
    int np  = gridDim.x * blockDim.x;
    cvtB(feat, FEATC, B_ * N_ * K_, mode, tid, np);
    packA(w_in, WPK + PK_WIN, 256, 22, mode, tid, np);
    packA(w1,                                 WPK + PK_W1,          64, 256, mode, tid, np);
    packA((const u16*)w1 + (mode?32768:16384), WPK + PK_W1 + 16384,  64, 256, mode, tid, np);
    packA(w2,                                 WPK + PK_W2,          128, 64, mode, tid, np);
    packA((const u16*)w2 + (mode?16384:8192),  WPK + PK_W2 + 8192,   128, 64, mode, tid, np);
    packA(w3,                                 WPK + PK_W3,          128, 128, mode, tid, np);
    packA((const u16*)w3 + (mode?32768:16384), WPK + PK_W3 + 16384,  128, 128, mode, tid, np);
    packA(wc1,                                WPK + PK_WC1,         128, 128, mode, tid, np);
    packA((const u16*)wc1 + (mode?32768:16384),WPK + PK_WC1 + 16384, 128, 128, mode, tid, np);
    packA(wc2,                                WPK + PK_WC2,         256, 128, mode, tid, np);
    packA((const u16*)wc2 + (mode?65536:32768),WPK + PK_WC2 + 32768, 256, 128, mode, tid, np);
    packA(wc3,                                WPK + PK_WC3,         32, 256, mode, tid, np);
    packA((const u16*)wc3 + (mode?16384:8192), WPK + PK_WC3 + 8192,  32, 256, mode, tid, np);
    packA(wo1, WPK + PK_WO1, 128, 256, mode, tid, np);
    packA(wo2, WPK + PK_WO2, 128, 128, mode, tid, np);
    cvtF(b_in, BIAS + OBIN, 256, mode, tid, np);
    cvtF(b1,   BIAS + OB1,  128, mode, tid, np);
    cvtF(b2,   BIAS + OB2,  256, mode, tid, np);
    cvtF(b3,   BIAS + OB3,  256, mode, tid, np);
    cvtF(bc1,  BIAS + OBC1, 256, mode, tid, np);
    cvtF(bc2,  BIAS + OBC2, 512, mode, tid, np);
    cvtF(bc3,  BIAS + OBC3, 64,  mode, tid, np);
    cvtF(bo1,  BIAS + OBO1, 128, mode, tid, np);
    cvtF(bo2,  BIAS + OBO2, 128, mode, tid, np);
    cvtF(db1,  BIAS + ODB1, 256, mode, tid, np);
    cvtF(db2,  BIAS + ODB2, 256, mode, tid, np);
    cvtF(db3,  BIAS + ODB3, 40,  mode, tid, np);
    cvtB(dw1, DWC + ODW1, 128 * 256, mode, tid, np);
    cvtB(dw2, DWC + ODW2, 256 * 256, mode, tid, np);
    cvtB(dw3, DWC + ODW3, 256 * 40,  mode, tid, np);
}

__device__ __forceinline__ void storeRow(u16* __restrict__ buf, int p, int col,
                                         float r0, float r1, float r2, float r3) {
    *(uint2*)(buf + p * 136 + col) = make_uint2(pk2(r0, r1), pk2(r2, r3));
}

// Load a wave's weight fragments for one phase into registers.
template<int NF>
__device__ __forceinline__ void loadWF(const u16* __restrict__ wA, int lane, bf16x8 (&wf)[NF]) {
#pragma unroll
    for (int i = 0; i < NF; ++i)
        wf[i] = *(const bf16x8*)(wA + ((size_t)(i * 64 + lane)) * 8);
}

// ================= 4-wave / 64-pt building blocks (kA0a, R18; R4-verified patterns) ====
// Generic LDS-in conv: wave w -> co-tiles w*CT..w*CT+CT-1, 4 p-tiles. wf[ct*KB+kb].
template<int CT, int KB, int INS>
__device__ __forceinline__ void convL64w(const bf16x8 (&wf)[CT * KB], const float* __restrict__ bias,
                                         const u16* __restrict__ sIn, u16* __restrict__ sOut) {
    const int t = threadIdx.x, lane = t & 63, w = t >> 6, lp = lane & 15, q = lane >> 4;
    f32x4 acc[CT][4] = {};
#pragma unroll
    for (int kb = 0; kb < KB; ++kb) {
        bf16x8 bb[4];
#pragma unroll
        for (int pt = 0; pt < 4; ++pt)
            bb[pt] = *(const bf16x8*)(sIn + (pt * 16 + lp) * INS + kb * 32 + q * 8);
#pragma unroll
        for (int ct = 0; ct < CT; ++ct)
#pragma unroll
            for (int pt = 0; pt < 4; ++pt)
                acc[ct][pt] = MFMA(wf[ct * KB + kb], bb[pt], acc[ct][pt]);
    }
#pragma unroll
    for (int ct = 0; ct < CT; ++ct) {
        const int co = (w * CT + ct) * 16 + q * 4;
        f32x4 bv = *(const f32x4*)(bias + co);
        const int col = co & 127;
#pragma unroll
        for (int pt = 0; pt < 4; ++pt) {
            f32x4 v = acc[ct][pt];
            storeRow(sOut, pt * 16 + lp, col,
                     fmaxf(v[0] + bv[0], 0.f), fmaxf(v[1] + bv[1], 0.f),
                     fmaxf(v[2] + bv[2], 0.f), fmaxf(v[3] + bv[3], 0.f));
        }
    }
}

// w1 256->64 concat: wave w -> co-tile w, 4 p-tiles, kb<4 lo / kb>=4 hi.
__device__ __forceinline__ void convCat64w(const bf16x8 (&wf)[8], const float* __restrict__ bias,
                                           const u16* __restrict__ sLo, const u16* __restrict__ sHi,
                                           u16* __restrict__ sOut) {
    const int t = threadIdx.x, lane = t & 63, w = t >> 6, lp = lane & 15, q = lane >> 4;
    f32x4 acc[4] = {};
#pragma unroll
    for (int kb = 0; kb < 8; ++kb) {
        const u16* sIn = (kb < 4) ? sLo : sHi;
        const int col = (kb & 3) * 32 + q * 8;
        bf16x8 bb[4];
#pragma unroll
        for (int pt = 0; pt < 4; ++pt)
            bb[pt] = *(const bf16x8*)(sIn + (pt * 16 + lp) * 136 + col);
#pragma unroll
        for (int pt = 0; pt < 4; ++pt) acc[pt] = MFMA(wf[kb], bb[pt], acc[pt]);
    }
    const int co = w * 16 + q * 4;
    f32x4 bv = *(const f32x4*)(bias + co);
#pragma unroll
    for (int pt = 0; pt < 4; ++pt) {
        f32x4 v = acc[pt];
        storeRow(sOut, pt * 16 + lp, co,
                 fmaxf(v[0] + bv[0], 0.f), fmaxf(v[1] + bv[1], 0.f),
                 fmaxf(v[2] + bv[2], 0.f), fmaxf(v[3] + bv[3], 0.f));
    }
}

// w2 64->128 fused: LDS store + f32 seg-max atomics (f-only sSeg, stride 129).
__device__ __forceinline__ void convW2_64w(const bf16x8 (&wf)[4], const float* __restrict__ bias,
                                           const u16* __restrict__ sIn, u16* __restrict__ sOut,
                                           const int* __restrict__ sClu, int* __restrict__ sSegF) {
    const int t = threadIdx.x, lane = t & 63, w = t >> 6, lp = lane & 15, q = lane >> 4;
    f32x4 acc[2][4] = {};
#pragma unroll
    for (int kb = 0; kb < 2; ++kb) {
        bf16x8 bb[4];
#pragma unroll
        for (int pt = 0; pt < 4; ++pt)
            bb[pt] = *(const bf16x8*)(sIn + (pt * 16 + lp) * 136 + kb * 32 + q * 8);
#pragma unroll
        for (int ct = 0; ct < 2; ++ct)
#pragma unroll
            for (int pt = 0; pt < 4; ++pt)
                acc[ct][pt] = MFMA(wf[ct * 2 + kb], bb[pt], acc[ct][pt]);
    }
#pragma unroll
    for (int ct = 0; ct < 2; ++ct) {
        const int co = (w * 2 + ct) * 16 + q * 4;
        f32x4 bv = *(const f32x4*)(bias + co);
#pragma unroll
        for (int pt = 0; pt < 4; ++pt) {
            f32x4 v = acc[ct][pt];
            const int p = pt * 16 + lp;
            float r0 = fmaxf(v[0] + bv[0], 0.f), r1 = fmaxf(v[1] + bv[1], 0.f);
            float r2 = fmaxf(v[2] + bv[2], 0.f), r3 = fmaxf(v[3] + bv[3], 0.f);
            *(uint2*)(sOut + p * 136 + co) = make_uint2(pk2(r0, r1), pk2(r2, r3));
            const int sb = sClu[p] * SEGFSTR + co;
            atomicMax(&sSegF[sb + 0], __float_as_int(r0));
            atomicMax(&sSegF[sb + 1], __float_as_int(r1));
            atomicMax(&sSegF[sb + 2], __float_as_int(r2));
            atomicMax(&sSegF[sb + 3], __float_as_int(r3));
        }
    }
}

// ================= 8-wave / 128-pt building blocks (R12-verified) ==========
template<int KB, int INS>
__device__ __forceinline__ void convP128w(const bf16x8 (&wf)[KB], const float* __restrict__ bias,
                                          const u16* __restrict__ sIn, u16* __restrict__ sOut) {
    const int t = threadIdx.x, lane = t & 63, w = t >> 6, lp = lane & 15, q = lane >> 4;
    f32x4 acc[8] = {};
#pragma unroll
    for (int kb = 0; kb < KB; ++kb) {
        bf16x8 bb[8];
#pragma unroll
        for (int pt = 0; pt < 8; ++pt)
            bb[pt] = *(const bf16x8*)(sIn + (pt * 16 + lp) * INS + kb * 32 + q * 8);
#pragma unroll
        for (int pt = 0; pt < 8; ++pt) acc[pt] = MFMA(wf[kb], bb[pt], acc[pt]);
    }
    const int co = w * 16 + q * 4;
    f32x4 bv = *(const f32x4*)(bias + co);
#pragma unroll
    for (int pt = 0; pt < 8; ++pt) {
        f32x4 v = acc[pt];
        storeRow(sOut, pt * 16 + lp, co,
                 fmaxf(v[0] + bv[0], 0.f), fmaxf(v[1] + bv[1], 0.f),
                 fmaxf(v[2] + bv[2], 0.f), fmaxf(v[3] + bv[3], 0.f));
    }
}

// w2 64->128 fused (128-pt, kA1a): LDS store + f32 seg-max atomics, full sSeg.
__device__ __forceinline__ void convW2_128w(const bf16x8 (&wf)[2], const float* __restrict__ bias,
                                            const u16* __restrict__ sIn, u16* __restrict__ sOut,
                                            const int* __restrict__ sCluSeg, int* __restrict__ sSeg) {
    const int t = threadIdx.x, lane = t & 63, w = t >> 6, lp = lane & 15, q = lane >> 4;
    f32x4 acc[8] = {};
#pragma unroll
    for (int kb = 0; kb < 2; ++kb) {
        bf16x8 bb[8];
#pragma unroll
        for (int pt = 0; pt < 8; ++pt)
            bb[pt] = *(const bf16x8*)(sIn + (pt * 16 + lp) * 136 + kb * 32 + q * 8);
#pragma unroll
        for (int pt = 0; pt < 8; ++pt) acc[pt] = MFMA(wf[kb], bb[pt], acc[pt]);
    }
    const int co = w * 16 + q * 4;
    f32x4 bv = *(const f32x4*)(bias + co);
#pragma unroll
    for (int pt = 0; pt < 8; ++pt) {
        f32x4 v = acc[pt];
        const int p = pt * 16 + lp;
        float r0 = fmaxf(v[0] + bv[0], 0.f), r1 = fmaxf(v[1] + bv[1], 0.f);
        float r2 = fmaxf(v[2] + bv[2], 0.f), r3 = fmaxf(v[3] + bv[3], 0.f);
        *(uint2*)(sOut + p * 136 + co) = make_uint2(pk2(r0, r1), pk2(r2, r3));
        const int sb = sCluSeg[p] * SEGSTR + co;
        atomicMax(&sSeg[sb + 0], __float_as_int(r0));
        atomicMax(&sSeg[sb + 1], __float_as_int(r1));
        atomicMax(&sSeg[sb + 2], __float_as_int(r2));
        atomicMax(&sSeg[sb + 3], __float_as_int(r3));
    }
}

// w1 256->64 concat, upper half gathered per-lane from LDS-staged cf2b (stride 136).
__device__ __forceinline__ void convCatG128s(const bf16x8 (&wf)[8], const float* __restrict__ bias,
                                             const u16* __restrict__ sIn, const u16* __restrict__ sCf,
                                             const int* __restrict__ sClu, u16* __restrict__ sOut) {
    const int t = threadIdx.x, lane = t & 63, w = t >> 6, lp = lane & 15, q = lane >> 4;
    const int ct = w & 3, pp = (w >> 2) * 4;
    f32x4 acc[4] = {};
#pragma unroll
    for (int kb = 0; kb < 8; ++kb) {
        bf16x8 bb[4];
#pragma unroll
        for (int i = 0; i < 4; ++i) {
            const int p = (pp + i) * 16 + lp;
            if (kb < 4) bb[i] = *(const bf16x8*)(sIn + p * 136 + kb * 32 + q * 8);
            else        bb[i] = *(const bf16x8*)(sCf + sClu[p] * CFSTR + (kb - 4) * 32 + q * 8);
        }
#pragma unroll
        for (int i = 0; i < 4; ++i) acc[i] = MFMA(wf[kb], bb[i], acc[i]);
    }
    const int co = ct * 16 + q * 4;
    f32x4 bv = *(const f32x4*)(bias + co);
#pragma unroll
    for (int i = 0; i < 4; ++i) {
        f32x4 v = acc[i];
        storeRow(sOut, (pp + i) * 16 + lp, co,
                 fmaxf(v[0] + bv[0], 0.f), fmaxf(v[1] + bv[1], 0.f),
                 fmaxf(v[2] + bv[2], 0.f), fmaxf(v[3] + bv[3], 0.f));
    }
}

// CIN=128 conv, B direct from global fragment-major f (128-pt group).
__device__ __forceinline__ void convG128w(const bf16x8 (&wf)[4], const float* __restrict__ bias,
                                          const u16* __restrict__ gB, u16* __restrict__ sOut) {
    const int t = threadIdx.x, lane = t & 63, w = t >> 6, lp = lane & 15, q = lane >> 4;
    f32x4 acc[8] = {};
#pragma unroll
    for (int kb = 0; kb < 4; ++kb) {
        bf16x8 bb[8];
#pragma unroll
        for (int pt = 0; pt < 8; ++pt)
            bb[pt] = *(const bf16x8*)(gB + pt * 2048 + kb * 512 + lane * 8);
#pragma unroll
        for (int pt = 0; pt < 8; ++pt) acc[pt] = MFMA(wf[kb], bb[pt], acc[pt]);
    }
    const int co = w * 16 + q * 4;
    f32x4 bv = *(const f32x4*)(bias + co);
#pragma unroll
    for (int pt = 0; pt < 8; ++pt) {
        f32x4 v = acc[pt];
        storeRow(sOut, pt * 16 + lp, co,
                 fmaxf(v[0] + bv[0], 0.f), fmaxf(v[1] + bv[1], 0.f),
                 fmaxf(v[2] + bv[2], 0.f), fmaxf(v[3] + bv[3], 0.f));
    }
}

// wc3 (32x256) + corr seg-max: co-tile (w&1), p-pair (w>>1)*2.
__device__ __forceinline__ void wc3seg128w(const bf16x8 (&wf)[8], const float* __restrict__ bias,
                                           const u16* __restrict__ sLo, const u16* __restrict__ sHi,
                                           const int* __restrict__ sClu, int* __restrict__ sSeg) {
    const int t = threadIdx.x, lane = t & 63, w = t >> 6, lp = lane & 15, q = lane >> 4;
    const int ct = w & 1, pp = (w >> 1) * 2;
    f32x4 acc[2] = {};
#pragma unroll
    for (int kb = 0; kb < 8; ++kb) {
        const u16* sIn = (kb < 4) ? sLo : sHi;
        const int col = (kb & 3) * 32 + q * 8;
        bf16x8 b0 = *(const bf16x8*)(sIn + ((pp + 0) * 16 + lp) * 136 + col);
        bf16x8 b1 = *(const bf16x8*)(sIn + ((pp + 1) * 16 + lp) * 136 + col);
        acc[0] = MFMA(wf[kb], b0, acc[0]);
        acc[1] = MFMA(wf[kb], b1, acc[1]);
    }
    const int col = ct * 16 + q * 4;
    f32x4 bv = *(const f32x4*)(bias + col);
#pragma unroll
    for (int i = 0; i < 2; ++i) {
        const int p = (pp + i) * 16 + lp;
        const int cl = sClu[p];
        f32x4 v = acc[i];
        atomicMax(&sSeg[cl * SEGSTR + 128 + col + 0], __float_as_int(fmaxf(v[0] + bv[0], 0.f)));
        atomicMax(&sSeg[cl * SEGSTR + 128 + col + 1], __float_as_int(fmaxf(v[1] + bv[1], 0.f)));
        atomicMax(&sSeg[cl * SEGSTR + 128 + col + 2], __float_as_int(fmaxf(v[2] + bv[2], 0.f)));
        atomicMax(&sSeg[cl * SEGSTR + 128 + col + 3], __float_as_int(fmaxf(v[3] + bv[3], 0.f)));
    }
}

// ---------- kC building blocks ----------
__device__ __forceinline__ void convCatG128os(const bf16x8 (&wf)[8], const float* __restrict__ bias,
                                              const u16* __restrict__ sIn, const u16* __restrict__ sCf,
                                              const int* __restrict__ sClu, u16* __restrict__ sOut) {
    const int t = threadIdx.x, lane = t & 63, w = t >> 6, lp = lane & 15, q = lane >> 4;
    f32x4 acc[8] = {};
#pragma unroll
    for (int kb = 0; kb < 8; ++kb) {
        bf16x8 bb[8];
#pragma unroll
        for (int pt = 0; pt < 8; ++pt) {
            const int p = pt * 16 + lp;
            if (kb < 4) bb[pt] = *(const bf16x8*)(sIn + p * 136 + kb * 32 + q * 8);
            else        bb[pt] = *(const bf16x8*)(sCf + sClu[p] * CFSTR + (kb - 4) * 32 + q * 8);
        }
#pragma unroll
        for (int pt = 0; pt < 8; ++pt) acc[pt] = MFMA(wf[kb], bb[pt], acc[pt]);
    }
    const int co = w * 16 + q * 4;
    f32x4 bv = *(const f32x4*)(bias + co);
#pragma unroll
    for (int pt = 0; pt < 8; ++pt) {
        f32x4 v = acc[pt];
        storeRow(sOut, pt * 16 + lp, co,
                 fmaxf(v[0] + bv[0], 0.f), fmaxf(v[1] + bv[1], 0.f),
                 fmaxf(v[2] + bv[2], 0.f), fmaxf(v[3] + bv[3], 0.f));
    }
}

__device__ __forceinline__ void convNet128w(const bf16x8 (&wf)[4], const float* __restrict__ bias,
                                            const u16* __restrict__ sIn, int* __restrict__ sNet) {
    const int t = threadIdx.x, lane = t & 63, w = t >> 6, lp = lane & 15, q = lane >> 4;
    f32x4 acc[8] = {};
#pragma unroll
    for (int kb = 0; kb < 4; ++kb) {
        bf16x8 bb[8];
#pragma unroll
        for (int pt = 0; pt < 8; ++pt)
            bb[pt] = *(const bf16x8*)(sIn + (pt * 16 + lp) * 136 + kb * 32 + q * 8);
#pragma unroll
        for (int pt = 0; pt < 8; ++pt) acc[pt] = MFMA(wf[kb], bb[pt], acc[pt]);
    }
    const int co = w * 16 + q * 4;
    f32x4 bv = *(const f32x4*)(bias + co);
    f32x4 m = acc[0];
#pragma unroll
    for (int pt = 1; pt < 8; ++pt) {
        m[0] = fmaxf(m[0], acc[pt][0]); m[1] = fmaxf(m[1], acc[pt][1]);
        m[2] = fmaxf(m[2], acc[pt][2]); m[3] = fmaxf(m[3], acc[pt][3]);
    }
    atomicMax(&sNet[co + 0], __float_as_int(fmaxf(m[0] + bv[0], 0.f)));
    atomicMax(&sNet[co + 1], __float_as_int(fmaxf(m[1] + bv[1], 0.f)));
    atomicMax(&sNet[co + 2], __float_as_int(fmaxf(m[2] + bv[2], 0.f)));
    atomicMax(&sNet[co + 3], __float_as_int(fmaxf(m[3] + bv[3], 0.f)));
}

// ---------- iteration-0, part A (R18): 64-pt subtiles, 256 thr, 2 blocks/CU ----------
__global__ __launch_bounds__(256, 2)
void kA0a(const u16* __restrict__ featc, const int* __restrict__ clu0,
          const u16* __restrict__ WPK, const float* __restrict__ BIAS,
          u16* __restrict__ gF, int* __restrict__ gSeg) {
    __shared__ __attribute__((aligned(16))) u16 sA[64 * 136];
    __shared__ __attribute__((aligned(16))) u16 sB[64 * 136];
    __shared__ __attribute__((aligned(16))) u16 sC[64 * 136];
    __shared__ __attribute__((aligned(16))) u16 sFeat[64 * 40];
    __shared__ int sSegF[SEGFTOT];
    __shared__ int sClu[64];
    const int t = threadIdx.x, lane = t & 63, w = t >> 6, lp = lane & 15, q = lane >> 4;
    const int b = blockIdx.y;
    const size_t bN = (size_t)b * N_;
    // Per-wave weight fragments (all L2-resident: kA0a weight set = 64 KB).
    bf16x8 wfL[2], wfH[2], wf1[8], wf2[4];
    loadWF(WPK + PK_WIN + (2 * w) * 512, lane, wfL);            // w_in lo tiles 2w,2w+1
    loadWF(WPK + PK_WIN + 4096 + (2 * w) * 512, lane, wfH);     // w_in hi tiles
    loadWF(WPK + PK_W1 + w * 4096, lane, wf1);                  // w1 co-tile w, 8 kb
    loadWF(WPK + PK_W2 + w * 2048, lane, wf2);                  // w2 tiles 2w,2w+1 x 2 kb
    for (int i = t; i < SEGFTOT; i += 256) sSegF[i] = 0;
    {   // prime subtile 0 features
        const int n0 = blockIdx.x * 512;
        for (int i = t; i < 2560; i += 256) {
            int p = i / 40, k = i - p * 40;
            sFeat[i] = (k < 22) ? featc[(bN + n0 + p) * 22 + k] : (u16)0;
        }
    }
    __syncthreads();
    for (int s = 0; s < 8; ++s) {
        const int n0 = (blockIdx.x * 8 + s) * 64;
        const size_t ntB = (size_t)b * 2048 + (size_t)(blockIdx.x * 8 + s) * 4;
        if (t < 64) sClu[t] = clu0[bN + n0 + t];
        // P1: w_in 22->256 (lo->sA, hi->sB)
        convL64w<2, 1, 40>(wfL, BIAS + OBIN,       sFeat, sA);
        convL64w<2, 1, 40>(wfH, BIAS + OBIN + 128, sFeat, sB);
        __syncthreads();
        // P2: w1 256->64 (h -> sC)
        convCat64w(wf1, BIAS + OB1, sA, sB, sC);
        __syncthreads();
        // P3: w2 64->128 fused (f -> sA + f32 seg-max, stride-129 f-only sSeg)
        convW2_64w(wf2, BIAS + OB2, sC, sA, sClu, sSegF);
        __syncthreads();
        // P4: fragment-major gF store + next-feat stage
        {
#pragma unroll
            for (int r = 0; r < 4; ++r) {
                bf16x8 v = *(const bf16x8*)(sA + (w * 16 + lp) * 136 + r * 32 + q * 8);
                *(bf16x8*)(gF + ((ntB + w) * 4 + r) * 512 + lane * 8) = v;
            }
        }
        if (s < 7) {
            const int n1 = n0 + 64;
            for (int i = t; i < 2560; i += 256) {
                int p = i / 40, k = i - p * 40;
                sFeat[i] = (k < 22) ? featc[(bN + n1 + p) * 22 + k] : (u16)0;
            }
        }
        __syncthreads();
    }
    for (int i = t; i < 4096; i += 256) {
        int cl = i >> 7, ch = i & 127;
        atomicMax(&gSeg[b * 5120 + cl * 160 + ch], sSegF[cl * SEGFSTR + ch]);
    }
}

// ---------- part B: wc1 -> wc2 -> wc3 (+corr seg). R12-verified, unchanged ----------
template<int PKOFF, int BOFF>
__device__ __forceinline__ void kAbBody(const u16* __restrict__ gFp, const int* __restrict__ clu,
                                        const u16* __restrict__ WPK, const float* __restrict__ BIAS,
                                        int* __restrict__ gSeg) {
    __shared__ __attribute__((aligned(16))) u16 sA[128 * 136];
    __shared__ __attribute__((aligned(16))) u16 sB[128 * 136];
    __shared__ __attribute__((aligned(16))) u16 sC[128 * 136];
    __shared__ int sSeg[SEGTOT];
    __shared__ int sClu[128];
    const int t = threadIdx.x, lane = t & 63, w = t >> 6;
    const int b = blockIdx.y;
    const size_t bN = (size_t)b * N_;
    bf16x8 wf4[4], wf5a[4], wf5b[4], wf6[8];
    loadWF(WPK + PK_WC1 + PKOFF * 16384 + w * 2048, lane, wf4);
    loadWF(WPK + PK_WC2 + PKOFF * 32768 + w * 2048, lane, wf5a);
    loadWF(WPK + PK_WC2 + PKOFF * 32768 + 16384 + w * 2048, lane, wf5b);
    loadWF(WPK + PK_WC3 + PKOFF * 8192 + (w & 1) * 4096, lane, wf6);
    for (int i = t; i < SEGTOT; i += 512) sSeg[i] = 0;
    __syncthreads();
    for (int s = 0; s < 8; ++s) {
        const int n0 = (blockIdx.x * 8 + s) * 128;
        const size_t ntB = (size_t)b * 2048 + (size_t)(blockIdx.x * 8 + s) * 8;
        if (t < 128) sClu[t] = clu[bN + n0 + t];
        const u16* gB = gFp + ntB * 2048;
        convG128w(wf4, BIAS + OBC1 + BOFF * 128, gB, sA);
        __syncthreads();
        convP128w<4, 136>(wf5a, BIAS + OBC2 + BOFF * 256,       sA, sB);
        convP128w<4, 136>(wf5b, BIAS + OBC2 + BOFF * 256 + 128, sA, sC);
        __syncthreads();
        wc3seg128w(wf6, BIAS + OBC3 + BOFF * 32, sB, sC, sClu, sSeg);
        __syncthreads();
    }
    for (int i = t; i < 1024; i += 512) {
        int cl = i >> 5, ch = i & 31;
        atomicMax(&gSeg[b * 5120 + cl * 160 + 128 + ch], sSeg[cl * SEGSTR + 128 + ch]);
    }
}

__global__ __launch_bounds__(512, 2)
void kA0b(const u16* __restrict__ gFp, const int* __restrict__ clu0,
          const u16* __restrict__ WPK, const float* __restrict__ BIAS,
          int* __restrict__ gSeg) {
    kAbBody<0, 0>(gFp, clu0, WPK, BIAS, gSeg);
}

__global__ __launch_bounds__(512, 2)
void kA1b(const u16* __restrict__ gFp, const int* __restrict__ clu1,
          const u16* __restrict__ WPK, const float* __restrict__ BIAS,
          int* __restrict__ gSeg) {
    kAbBody<1, 1>(gFp, clu1, WPK, BIAS, gSeg);
}

// ---------- per-batch cluster math -> bf16 cf2b ----------
__global__ __launch_bounds__(256)
void kB(const int* __restrict__ gSeg, u16* __restrict__ cf2b) {
    __shared__ float sA[5120];
    __shared__ float sR[1024];
    __shared__ float sI[32];
    const int t = threadIdx.x, b = blockIdx.x;
    for (int i = t; i < 5120; i += 256) sA[i] = __int_as_float(gSeg[b * 5120 + i]);
    __syncthreads();
    if (t < 32) {
        float s = 0.f;
        for (int j = 0; j < 32; ++j) { float v = sA[t * 160 + 128 + j]; s = fmaf(v, v, s); }
        sI[t] = 1.f / fmaxf(sqrtf(s), 1e-12f);
    }
    __syncthreads();
    for (int i = t; i < 1024; i += 256) {
        int ca = i >> 5, cb = i & 31;
        float s = 0.f;
        for (int j = 0; j < 32; ++j)
            s = fmaf(sA[ca * 160 + 128 + j], sA[cb * 160 + 128 + j], s);
        sR[i] = s * sI[ca] * sI[cb];
    }
    __syncthreads();
    for (int i = t; i < 4096; i += 256) {
        int c = i >> 7, ch = i & 127;
        float s = 0.f;
        for (int cp = 0; cp < 32; ++cp)
            s = fmaf(sA[cp * 160 + ch], sR[cp * 32 + c], s);
        cf2b[((size_t)b * 32 + c) * 128 + ch] = f2b(s);
    }
}

// ---------- iteration-1, part A (R16-verified, unchanged) ----------
__global__ __launch_bounds__(512, 2)
void kA1a(const u16* __restrict__ gFp, const int* __restrict__ clu_g,
          const int* __restrict__ clu_s, const u16* __restrict__ cf2b,
          const u16* __restrict__ WPK, const float* __restrict__ BIAS,
          u16* __restrict__ gFo, int* __restrict__ gSeg) {
    __shared__ __attribute__((aligned(16))) u16 sA[128 * 136];
    __shared__ __attribute__((aligned(16))) u16 sB[128 * 136];
    __shared__ __attribute__((aligned(16))) u16 sC[128 * 136];
    __shared__ __attribute__((aligned(16))) u16 sCf[32 * CFSTR];
    __shared__ int sSeg[SEGTOT];
    __shared__ int sClu0[128];
    __shared__ int sClu1[128];
    const int t = threadIdx.x, lane = t & 63, w = t >> 6, lp = lane & 15, q = lane >> 4;
    const int b = blockIdx.y;
    const size_t bN = (size_t)b * N_;
    bf16x8 wfG[4], wf2[8], wf3[2];
    loadWF(WPK + PK_W3 + w * 2048, lane, wfG);
    loadWF(WPK + PK_W1 + 16384 + (w & 3) * 4096, lane, wf2);
    loadWF(WPK + PK_W2 + 8192 + w * 1024, lane, wf3);
    for (int i = t; i < SEGTOT; i += 512) sSeg[i] = 0;
    const u16* cfb = cf2b + (size_t)b * 4096;
    for (int i = t; i < 4096; i += 512) {
        int cl = i >> 7, ch = i & 127;
        sCf[cl * CFSTR + ch] = cfb[i];
    }
    __syncthreads();
    for (int s = 0; s < 8; ++s) {
        const int n0 = (blockIdx.x * 8 + s) * 128;
        const size_t ntB = (size_t)b * 2048 + (size_t)(blockIdx.x * 8 + s) * 8;
        if (t < 128) sClu0[t] = clu_g[bN + n0 + t];
        else if (t < 256) sClu1[t - 128] = clu_s[bN + n0 + (t - 128)];
        const u16* gB = gFp + ntB * 2048;
        convG128w(wfG, BIAS + OB3, gB, sA);
        __syncthreads();
        convCatG128s(wf2, BIAS + OB1 + 64, sA, sCf, sClu0, sB);
        __syncthreads();
        convW2_128w(wf3, BIAS + OB2 + 128, sB, sC, sClu1, sSeg);
        __syncthreads();
        {
#pragma unroll
            for (int r = 0; r < 4; ++r) {
                bf16x8 v = *(const bf16x8*)(sC + (w * 16 + lp) * 136 + r * 32 + q * 8);
                *(bf16x8*)(gFo + ((ntB + w) * 4 + r) * 512 + lane * 8) = v;
            }
        }
        __syncthreads();
    }
    for (int i = t; i < 4096; i += 512) {
        int cl = i >> 7, ch = i & 127;
        atomicMax(&gSeg[b * 5120 + cl * 160 + ch], sSeg[cl * SEGSTR + ch]);
    }
}

// ---------- final conv head (R16-verified, unchanged) ----------
__global__ __launch_bounds__(512, 2)
void kC(const u16* __restrict__ gFp, const int* __restrict__ clu_g,
        const u16* __restrict__ cf2b,
        const u16* __restrict__ WPK, const float* __restrict__ BIAS,
        int* __restrict__ gNet) {
    __shared__ __attribute__((aligned(16))) u16 sA[128 * 136];
    __shared__ __attribute__((aligned(16))) u16 sB[128 * 136];
    __shared__ __attribute__((aligned(16))) u16 sCf[32 * CFSTR];
    __shared__ int sNet[128];
    __shared__ int sClu[128];
    const int t = threadIdx.x, lane = t & 63, w = t >> 6;
    const int b = blockIdx.y;
    const size_t bN = (size_t)b * N_;
    bf16x8 wfG[4], wfO1[8], wfO2[4];
    loadWF(WPK + PK_W3 + 16384 + w * 2048, lane, wfG);
    loadWF(WPK + PK_WO1 + w * 4096, lane, wfO1);
    loadWF(WPK + PK_WO2 + w * 2048, lane, wfO2);
    if (t < 128) sNet[t] = 0;
    const u16* cfb = cf2b + (size_t)b * 4096;
    for (int i = t; i < 4096; i += 512) {
        int cl = i >> 7, ch = i & 127;
        sCf[cl * CFSTR + ch] = cfb[i];
    }
    __syncthreads();
    for (int s = 0; s < 4; ++s) {
        const int n0 = (blockIdx.x * 4 + s) * 128;
        if (t < 128) sClu[t] = clu_g[bN + n0 + t];
        const u16* gB = gFp + ((size_t)b * 2048 + (size_t)(blockIdx.x * 4 + s) * 8) * 2048;
        convG128w(wfG, BIAS + OB3 + 128, gB, sA);
        __syncthreads();
        convCatG128os(wfO1, BIAS + OBO1, sA, sCf, sClu, sB);
        __syncthreads();
        convNet128w(wfO2, BIAS + OBO2, sB, sNet);
        __syncthreads();
    }
    if (t < 128) atomicMax(&gNet[b * 128 + t], sNet[t]);
}

// ---------- tiny MLP head: one block per batch (R17-verified) ----------
__global__ __launch_bounds__(256)
void kD(const int* __restrict__ gNet, const u16* __restrict__ DWC,
        const float* __restrict__ BIAS, void* __restrict__ outv,
        const int* __restrict__ modep) {
    __shared__ float sN[128];
    __shared__ float sD1[256];
    __shared__ float sD2[256];
    const int mode = *modep;
    const int t = threadIdx.x, bb = blockIdx.x;
    if (t < 128) sN[t] = __int_as_float(gNet[bb * 128 + t]);
    __syncthreads();
    {
        float s = BIAS[ODB1 + t];
        for (int k = 0; k < 128; ++k)
            s = fmaf(sN[k], b2f(DWC[ODW1 + k * 256 + t]), s);
        sD1[t] = (s >= 0.f) ? s : 0.2f * s;
    }
    __syncthreads();
    {
        float s = BIAS[ODB2 + t];
        for (int k = 0; k < 256; ++k)
            s = fmaf(sD1[k], b2f(DWC[ODW2 + k * 256 + t]), s);
        sD2[t] = (s >= 0.f) ? s : 0.2f * s;
    }
    __syncthreads();
    if (t < 40) {
        float s = BIAS[ODB3 + t];
        for (int k = 0; k < 256; ++k)
            s = fmaf(sD2[k], b2f(DWC[ODW3 + k * 40 + t]), s);
        if (mode) ((float*)outv)[bb * 40 + t] = s;
        else      ((u16*)outv)[bb * 40 + t]   = f2b(s);
    }
}

extern "C" void kernel_launch(void* const* d_in, const int* in_sizes, int n_in,
                              void* d_out, int out_size, void* d_ws, size_t ws_size,
                              hipStream_t stream) {
    const void* feat = d_in[0];
    const int* clus = (const int*)d_in[1];

    char* ws = (char*)d_ws;
    u16*   WPK   = (u16*)(ws + OFS_WPK);
    float* BIAS  = (float*)(ws + OFS_BIAS);
    u16*   DWC   = (u16*)(ws + OFS_DWC);
    int*   modep = (int*)(ws + OFS_MODE);
    u16*   FEATC = (u16*)(ws + OFS_FEATC);
    int*   seg0  = (int*)(ws + OFS_GACC0);
    int*   seg1  = (int*)(ws + OFS_GACC1);
    int*   gNet  = (int*)(ws + OFS_GNET);
    u16*   cf2b0 = (u16*)(ws + OFS_CF2B0);
    u16*   cf2b1 = (u16*)(ws + OFS_CF2B1);
    u16*   f0    = (u16*)(ws + OFS_F0);
    u16*   f1    = (u16*)(ws + OFS_F1);

    hipMemsetAsync(ws + OFS_GACC0, 0, GACC_ZERO_BYTES, stream);
    hipLaunchKernelGGL(kSniff, dim3(1), dim3(256), 0, stream, (const u16*)feat, modep);
    hipLaunchKernelGGL(kPrep, dim3(256), dim3(256), 0, stream,
                       feat, d_in[2], d_in[3], d_in[4], d_in[5], d_in[6], d_in[7],
                       d_in[8], d_in[9], d_in[10], d_in[11], d_in[12], d_in[13],
                       d_in[14], d_in[15], d_in[16], d_in[17], d_in[18], d_in[19],
                       d_in[20], d_in[21], d_in[22], d_in[23], d_in[24], d_in[25],
                       WPK, BIAS, DWC, FEATC, modep);

    const int* clu0 = clus;
    const int* clu1 = clus + (size_t)B_ * N_;

    hipLaunchKernelGGL(kA0a, dim3(64, 8), dim3(256), 0, stream,
                       FEATC, clu0, WPK, BIAS, f0, seg0);
    hipLaunchKernelGGL(kA0b, dim3(32, 8), dim3(512), 0, stream,
                       f0, clu0, WPK, BIAS, seg0);
    hipLaunchKernelGGL(kB, dim3(8), dim3(256), 0, stream, seg0, cf2b0);
    hipLaunchKernelGGL(kA1a, dim3(32, 8), dim3(512), 0, stream,
                       f0, clu0, clu1, cf2b0, WPK, BIAS, f1, seg1);
    hipLaunchKernelGGL(kA1b, dim3(32, 8), dim3(512), 0, stream,
                       f1, clu1, WPK, BIAS, seg1);
    hipLaunchKernelGGL(kB, dim3(8), dim3(256), 0, stream, seg1, cf2b1);
    hipLaunchKernelGGL(kC, dim3(64, 8), dim3(512), 0, stream,
                       f1, clu1, cf2b1, WPK, BIAS, gNet);
    hipLaunchKernelGGL(kD, dim3(8), dim3(256), 0, stream,
                       gNet, DWC, BIAS, d_out, modep);
}